// Round 11
// baseline (1048.181 us; speedup 1.0000x reference)
//
#include <hip/hip_runtime.h>
#include <cstdint>
#include <cstddef>

typedef __attribute__((ext_vector_type(8))) short short8;    // 8 bf16 (4 VGPR)
typedef __attribute__((ext_vector_type(4))) float f32x4;     // MFMA acc

// ============================================================================
// Threefry2x32 (matches jax._src.prng.threefry2x32).
// ============================================================================
__host__ __device__ inline void threefry2x32(uint32_t k0, uint32_t k1,
                                             uint32_t x0, uint32_t x1,
                                             uint32_t& o0, uint32_t& o1) {
  uint32_t ks2 = k0 ^ k1 ^ 0x1BD11BDAu;
  uint32_t v0 = x0 + k0, v1 = x1 + k1;
#define TF_R(r) { v0 += v1; v1 = (v1 << (r)) | (v1 >> (32 - (r))); v1 ^= v0; }
  TF_R(13) TF_R(15) TF_R(26) TF_R(6)
  v0 += k1; v1 += ks2 + 1u;
  TF_R(17) TF_R(29) TF_R(16) TF_R(24)
  v0 += ks2; v1 += k0 + 2u;
  TF_R(13) TF_R(15) TF_R(26) TF_R(6)
  v0 += k0; v1 += k1 + 3u;
  TF_R(17) TF_R(29) TF_R(16) TF_R(24)
  v0 += k1; v1 += ks2 + 4u;
  TF_R(13) TF_R(15) TF_R(26) TF_R(6)
  v0 += ks2; v1 += k0 + 5u;
#undef TF_R
  o0 = v0; o1 = v1;
}

__device__ __forceinline__ uint32_t tf_bits32(uint32_t k0, uint32_t k1, uint32_t j) {
  uint32_t o0, o1;
  threefry2x32(k0, k1, 0u, j, o0, o1);
  return o0 ^ o1;
}

__device__ __forceinline__ float u01_from_bits(uint32_t bits) {
  return __uint_as_float((bits >> 9) | 0x3f800000u) - 1.0f;  // [0,1)
}

__device__ __forceinline__ float waveSum(float v) {
#pragma unroll
  for (int off = 32; off > 0; off >>= 1) v += __shfl_down(v, off, 64);
  return v;
}

// ============================================================================
// conv1 fused: conv(3->32) + BN partials (unpooled) + RAW 2x2 maxpool store.
// ============================================================================
__global__ __launch_bounds__(256) void conv1_fused_kernel(
    const float* __restrict__ in, const float* __restrict__ w,
    float* __restrict__ outraw, float* __restrict__ partials) {
  __shared__ float ins[3 * 34 * 34];
  __shared__ float red[4][64];
  const int b = blockIdx.x, t = threadIdx.x;
  for (int i = t; i < 3 * 34 * 34; i += 256) {
    int ci = i / 1156, r = i % 1156, iy = r / 34, ix = r % 34;
    int y = iy - 1, x = ix - 1;
    float v = 0.f;
    if ((unsigned)y < 32u && (unsigned)x < 32u)
      v = in[(((size_t)b * 3 + ci) * 32 + y) * 32 + x];
    ins[i] = v;
  }
  __syncthreads();
  const int py = t >> 4, px = t & 15, wv = t >> 6, ln = t & 63;
  float win[3][4][4];
#pragma unroll
  for (int ci = 0; ci < 3; ci++)
#pragma unroll
    for (int r = 0; r < 4; r++)
#pragma unroll
      for (int c = 0; c < 4; c++)
        win[ci][r][c] = ins[ci * 1156 + (2 * py + r) * 34 + (2 * px + c)];
#pragma unroll 1
  for (int co = 0; co < 32; co++) {
    float acc00 = 0.f, acc01 = 0.f, acc10 = 0.f, acc11 = 0.f;
#pragma unroll
    for (int ci = 0; ci < 3; ci++) {
      const float* wp = w + (co * 3 + ci) * 9;  // wave-uniform -> s_load
#pragma unroll
      for (int dy = 0; dy < 3; dy++)
#pragma unroll
        for (int dx = 0; dx < 3; dx++) {
          float wvv = wp[dy * 3 + dx];
          acc00 += win[ci][dy][dx] * wvv;
          acc01 += win[ci][dy][dx + 1] * wvv;
          acc10 += win[ci][dy + 1][dx] * wvv;
          acc11 += win[ci][dy + 1][dx + 1] * wvv;
        }
    }
    float sm = acc00 + acc01 + acc10 + acc11;
    float sq = acc00 * acc00 + acc01 * acc01 + acc10 * acc10 + acc11 * acc11;
    float s = waveSum(sm), q = waveSum(sq);
    if (ln == 0) { red[wv][2 * co] = s; red[wv][2 * co + 1] = q; }
    float m = fmaxf(fmaxf(acc00, acc01), fmaxf(acc10, acc11));  // RAW max
    outraw[(((size_t)b * 32 + co) * 16 + py) * 16 + px] = m;
  }
  __syncthreads();
  for (int i = t; i < 64; i += 256)
    partials[(size_t)b * 64 + i] = red[0][i] + red[1][i] + red[2][i] + red[3][i];
}

// ============================================================================
// bf16-split helpers
// ============================================================================
__device__ __forceinline__ uint32_t pack_bf16q(float x) {
  uint32_t u = __float_as_uint(x);
  uint32_t hi = (u + 0x7fffu + ((u >> 16) & 1u)) & 0xffff0000u;
  float r = x - __uint_as_float(hi);
  uint32_t v = __float_as_uint(r);
  uint32_t lo = (v + 0x7fffu + ((v >> 16) & 1u)) >> 16;
  return hi | lo;
}

__global__ void cvt_bf16q_kernel(const float* X, uint32_t* Y, int n4) {
  int i = blockIdx.x * blockDim.x + threadIdx.x;
  if (i >= n4) return;
  float4 x = ((const float4*)X)[i];
  uint4 o;
  o.x = pack_bf16q(x.x); o.y = pack_bf16q(x.y);
  o.z = pack_bf16q(x.z); o.w = pack_bf16q(x.w);
  ((uint4*)Y)[i] = o;
}

// conv2 weight prepack: w [64][32][9] fp32 -> wh/wl [9][64][32] bf16 planes.
__global__ void prep_w2_kernel(const float* __restrict__ w, short* __restrict__ wh,
                               short* __restrict__ wl) {
  int idx = blockIdx.x * 256 + threadIdx.x;
  if (idx >= 64 * 32 * 9) return;
  int tp = idx % 9, rem = idx / 9;
  int ci = rem % 32, co = rem / 32;
  uint32_t pq = pack_bf16q(w[idx]);
  size_t o = ((size_t)tp * 64 + co) * 32 + ci;
  wh[o] = (short)(pq >> 16);
  wl[o] = (short)(pq & 0xffffu);
}

// conv3 weight prepack: w [128][64][9] fp32 -> wh/wl [9][128][64] bf16 planes.
__global__ void prep_w3_kernel(const float* __restrict__ w, short* __restrict__ wh,
                               short* __restrict__ wl) {
  int idx = blockIdx.x * 256 + threadIdx.x;
  if (idx >= 128 * 64 * 9) return;
  int tp = idx % 9, rem = idx / 9;
  int ci = rem % 64, co = rem / 64;
  uint32_t pq = pack_bf16q(w[idx]);
  size_t o = ((size_t)tp * 128 + co) * 64 + ci;
  wh[o] = (short)(pq >> 16);
  wl[o] = (short)(pq & 0xffffu);
}

// ============================================================================
// conv2 via MFMA implicit GEMM (bf16-split, 3 terms).
// ============================================================================
__global__ __launch_bounds__(256) void conv2_mfma_kernel(
    const uint32_t* __restrict__ inq, const short* __restrict__ wh,
    const short* __restrict__ wl, float* __restrict__ outpool,
    float* __restrict__ partials) {
  __shared__ short Xh[324 * 32], Xl[324 * 32];
  __shared__ float red[4][128];
  const int b = blockIdx.x, t = threadIdx.x;
  for (int i = t; i < 324 * 16; i += 256) {
    int row = i >> 4;
    int py = row / 18, pxx = row % 18;
    if (py == 0 || py == 17 || pxx == 0 || pxx == 17) {
      ((uint32_t*)Xh)[i] = 0u;
      ((uint32_t*)Xl)[i] = 0u;
    }
  }
  for (int i = t; i < 4096; i += 256) {
    int p = i >> 8, px = i & 255;
    int y = px >> 4, x = px & 15;
    uint32_t ua = inq[((size_t)b * 32 + 2 * p) * 256 + px];
    uint32_t ub = inq[((size_t)b * 32 + 2 * p + 1) * 256 + px];
    uint32_t h = (ua >> 16) | (ub & 0xffff0000u);
    uint32_t l = (ua & 0xffffu) | (ub << 16);
    int row = (y + 1) * 18 + (x + 1);
    int ci2 = (2 * p) ^ ((row & 3) << 3);  // swizzled, stays even
    ((uint32_t*)Xh)[(row * 32 + ci2) >> 1] = h;
    ((uint32_t*)Xl)[(row * 32 + ci2) >> 1] = l;
  }
  __syncthreads();
  const int w = t >> 6, l = t & 63;
  const int lr = l & 15, lg = l >> 4;
  f32x4 acc[4][4];  // [co block][px block]
#pragma unroll
  for (int i = 0; i < 4; i++)
#pragma unroll
    for (int j = 0; j < 4; j++) acc[i][j] = (f32x4){0.f, 0.f, 0.f, 0.f};
#pragma unroll 1
  for (int tap = 0; tap < 9; tap++) {
    const int dy = tap / 3, dx = tap % 3;
    short8 awh[4], awl[4];
#pragma unroll
    for (int i = 0; i < 4; i++) {
      size_t off = ((size_t)tap * 64 + i * 16 + lr) * 32 + lg * 8;
      awh[i] = *(const short8*)(wh + off);
      awl[i] = *(const short8*)(wl + off);
    }
    short8 bxh[4], bxl[4];
#pragma unroll
    for (int j = 0; j < 4; j++) {
      int y = w * 4 + j, x = lr;
      int row = (y + dy) * 18 + (x + dx);
      int ci = (lg * 8) ^ ((row & 3) << 3);
      bxh[j] = *(const short8*)&Xh[row * 32 + ci];
      bxl[j] = *(const short8*)&Xl[row * 32 + ci];
    }
#pragma unroll
    for (int i = 0; i < 4; i++)
#pragma unroll
      for (int j = 0; j < 4; j++) {
        acc[i][j] = __builtin_amdgcn_mfma_f32_16x16x32_bf16(awh[i], bxh[j], acc[i][j], 0, 0, 0);
        acc[i][j] = __builtin_amdgcn_mfma_f32_16x16x32_bf16(awh[i], bxl[j], acc[i][j], 0, 0, 0);
        acc[i][j] = __builtin_amdgcn_mfma_f32_16x16x32_bf16(awl[i], bxh[j], acc[i][j], 0, 0, 0);
      }
  }
#pragma unroll
  for (int i = 0; i < 4; i++)
#pragma unroll
    for (int r = 0; r < 4; r++) {
      int co = i * 16 + lg * 4 + r;
      float v0 = acc[i][0][r], v1 = acc[i][1][r], v2 = acc[i][2][r], v3 = acc[i][3][r];
      float s = v0 + v1 + v2 + v3;
      float q = v0 * v0 + v1 * v1 + v2 * v2 + v3 * v3;
#pragma unroll
      for (int off = 1; off <= 8; off <<= 1) {
        s += __shfl_xor(s, off, 64);
        q += __shfl_xor(q, off, 64);
      }
      if (lr == 0) { red[w][2 * co] = s; red[w][2 * co + 1] = q; }
      float h0 = fmaxf(v0, __shfl_xor(v0, 1, 64));
      float h1 = fmaxf(v1, __shfl_xor(v1, 1, 64));
      float h2 = fmaxf(v2, __shfl_xor(v2, 1, 64));
      float h3 = fmaxf(v3, __shfl_xor(v3, 1, 64));
      float pm0 = fmaxf(h0, h1);
      float pm1 = fmaxf(h2, h3);
      if ((lr & 1) == 0) {
        size_t base = ((size_t)b * 64 + co) * 64 + (w * 2) * 8 + (lr >> 1);
        outpool[base] = pm0;
        outpool[base + 8] = pm1;
      }
    }
  __syncthreads();
  for (int i = t; i < 128; i += 256)
    partials[(size_t)b * 128 + i] = red[0][i] + red[1][i] + red[2][i] + red[3][i];
}

// ============================================================================
// conv3 via MFMA implicit GEMM (bf16-split, 3 terms).
// ============================================================================
__global__ __launch_bounds__(256) void conv3_mfma_kernel(
    const uint32_t* __restrict__ inq, const short* __restrict__ wh,
    const short* __restrict__ wl, float* __restrict__ outraw,
    float* __restrict__ partials) {
  __shared__ short Xh[100 * 64], Xl[100 * 64];
  __shared__ float red[256];
  const int b = blockIdx.x, t = threadIdx.x;
  for (int i = t; i < 100 * 32; i += 256) {
    int row = i >> 5;
    int py = row / 10, pxx = row % 10;
    if (py == 0 || py == 9 || pxx == 0 || pxx == 9) {
      ((uint32_t*)Xh)[i] = 0u;
      ((uint32_t*)Xl)[i] = 0u;
    }
  }
  for (int i = t; i < 2048; i += 256) {
    int p = i >> 6, px = i & 63;
    int y = px >> 3, x = px & 7;
    uint32_t ua = inq[((size_t)b * 64 + 2 * p) * 64 + px];
    uint32_t ub = inq[((size_t)b * 64 + 2 * p + 1) * 64 + px];
    uint32_t h = (ua >> 16) | (ub & 0xffff0000u);
    uint32_t l = (ua & 0xffffu) | (ub << 16);
    int row = (y + 1) * 10 + (x + 1);
    int ci2 = (2 * p) ^ ((row & 7) << 3);
    ((uint32_t*)Xh)[(row * 64 + ci2) >> 1] = h;
    ((uint32_t*)Xl)[(row * 64 + ci2) >> 1] = l;
  }
  __syncthreads();
  const int w = t >> 6, l = t & 63;
  const int lr = l & 15, lg = l >> 4;
  const int co_base = w * 32;
  f32x4 acc[2][4];
#pragma unroll
  for (int i = 0; i < 2; i++)
#pragma unroll
    for (int j = 0; j < 4; j++) acc[i][j] = (f32x4){0.f, 0.f, 0.f, 0.f};
#pragma unroll 1
  for (int tap = 0; tap < 9; tap++) {
    const int dy = tap / 3, dx = tap % 3;
#pragma unroll
    for (int sl = 0; sl < 2; sl++) {
      short8 awh[2], awl[2];
#pragma unroll
      for (int i = 0; i < 2; i++) {
        size_t off = ((size_t)tap * 128 + co_base + i * 16 + lr) * 64 + sl * 32 + lg * 8;
        awh[i] = *(const short8*)(wh + off);
        awl[i] = *(const short8*)(wl + off);
      }
      short8 bxh[4], bxl[4];
#pragma unroll
      for (int j = 0; j < 4; j++) {
        int px = j * 16 + lr;
        int row = ((px >> 3) + dy) * 10 + (px & 7) + dx;
        int ci = (sl * 32 + lg * 8) ^ ((row & 7) << 3);
        bxh[j] = *(const short8*)&Xh[row * 64 + ci];
        bxl[j] = *(const short8*)&Xl[row * 64 + ci];
      }
#pragma unroll
      for (int i = 0; i < 2; i++)
#pragma unroll
        for (int j = 0; j < 4; j++) {
          acc[i][j] = __builtin_amdgcn_mfma_f32_16x16x32_bf16(awh[i], bxh[j], acc[i][j], 0, 0, 0);
          acc[i][j] = __builtin_amdgcn_mfma_f32_16x16x32_bf16(awh[i], bxl[j], acc[i][j], 0, 0, 0);
          acc[i][j] = __builtin_amdgcn_mfma_f32_16x16x32_bf16(awl[i], bxh[j], acc[i][j], 0, 0, 0);
        }
    }
  }
#pragma unroll
  for (int i = 0; i < 2; i++)
#pragma unroll
    for (int r = 0; r < 4; r++) {
      int co = co_base + i * 16 + lg * 4 + r;
      float s = 0.f, q = 0.f;
#pragma unroll
      for (int j = 0; j < 4; j++) {
        float v = acc[i][j][r];
        outraw[((size_t)b * 128 + co) * 64 + j * 16 + lr] = v;
        s += v; q += v * v;
      }
#pragma unroll
      for (int off = 1; off <= 8; off <<= 1) {
        s += __shfl_xor(s, off, 64);
        q += __shfl_xor(q, off, 64);
      }
      if (lr == 0) { red[2 * co] = s; red[2 * co + 1] = q; }
    }
  __syncthreads();
  for (int i = t; i < 256; i += 256) partials[(size_t)b * 256 + i] = red[i];
}

// ============================================================================
// BN helpers
// ============================================================================
__global__ __launch_bounds__(256) void reduce_partials_kernel(
    const float* __restrict__ partials, int nblk, int Q, double* __restrict__ sums) {
  int q = blockIdx.x;
  double acc = 0.0;
  for (int i = threadIdx.x; i < nblk; i += 256) acc += (double)partials[(size_t)i * Q + q];
  __shared__ double red[256];
  red[threadIdx.x] = acc;
  __syncthreads();
  for (int s = 128; s > 0; s >>= 1) {
    if (threadIdx.x < s) red[threadIdx.x] += red[threadIdx.x + s];
    __syncthreads();
  }
  if (threadIdx.x == 0) sums[q] = red[0];
}

__global__ __launch_bounds__(1024) void col_stats_kernel(
    const float* __restrict__ X, int R, int C, int nch, double* __restrict__ sums) {
  int c0 = blockIdx.x * 64, chunk = blockIdx.y;
  int cl = threadIdx.x & 63, rg = threadIdx.x >> 6;
  int rows = R / nch, rbeg = chunk * rows, rend = rbeg + rows;
  double s = 0.0, sq = 0.0;
  for (int r = rbeg + rg; r < rend; r += 16) {
    float v = X[(size_t)r * C + c0 + cl];
    s += v; sq += (double)v * (double)v;
  }
  __shared__ double red[16][64][2];
  red[rg][cl][0] = s; red[rg][cl][1] = sq;
  __syncthreads();
  if (rg == 0) {
    for (int i = 1; i < 16; i++) { s += red[i][cl][0]; sq += red[i][cl][1]; }
    sums[(size_t)chunk * 2 * C + 2 * (c0 + cl)] = s;
    sums[(size_t)chunk * 2 * C + 2 * (c0 + cl) + 1] = sq;
  }
}

__global__ void bn_finalize_kernel(const double* __restrict__ sums, int nch, int cst2,
                                   const float* __restrict__ g, const float* __restrict__ b,
                                   float* __restrict__ scale, float* __restrict__ shift,
                                   int C, double invN) {
  int c = blockIdx.x * blockDim.x + threadIdx.x;
  if (c >= C) return;
  double s = 0.0, sq = 0.0;
  for (int ch = 0; ch < nch; ch++) {
    s += sums[(size_t)ch * cst2 + 2 * c];
    sq += sums[(size_t)ch * cst2 + 2 * c + 1];
  }
  double m = s * invN;
  double v = sq * invN - m * m;
  double sc = (double)g[c] / sqrt(v + 1e-5);
  scale[c] = (float)sc;
  shift[c] = (float)((double)b[c] - m * sc);
}

// BN+ReLU+bf16q-pack fused, NCHW layout, in place (fp32 -> packed u32).
template <int LOGHW, int CMASK>
__global__ void bn_relu_pack_vec4_kernel(float* __restrict__ X,
                                         const float* __restrict__ scale,
                                         const float* __restrict__ shift, int n4) {
  int i = blockIdx.x * blockDim.x + threadIdx.x;
  if (i >= n4) return;
  int c = ((i << 2) >> LOGHW) & CMASK;
  float4 v = ((float4*)X)[i];
  float sc = scale[c], sh = shift[c];
  uint4 o;
  o.x = pack_bf16q(fmaxf(v.x * sc + sh, 0.f));
  o.y = pack_bf16q(fmaxf(v.y * sc + sh, 0.f));
  o.z = pack_bf16q(fmaxf(v.z * sc + sh, 0.f));
  o.w = pack_bf16q(fmaxf(v.w * sc + sh, 0.f));
  ((uint4*)X)[i] = o;
}

// BN+ReLU+pack for [R][C] row-major, in place. C4 = C/4.
__global__ void bn_relu_pack_cols4_kernel(float* __restrict__ X,
                                          const float* __restrict__ scale,
                                          const float* __restrict__ shift,
                                          int n4, int C4) {
  int i = blockIdx.x * blockDim.x + threadIdx.x;
  if (i >= n4) return;
  int c4 = i % C4;
  float4 v = ((float4*)X)[i];
  float4 sc = ((const float4*)scale)[c4];
  float4 sh = ((const float4*)shift)[c4];
  uint4 o;
  o.x = pack_bf16q(fmaxf(v.x * sc.x + sh.x, 0.f));
  o.y = pack_bf16q(fmaxf(v.y * sc.y + sh.y, 0.f));
  o.z = pack_bf16q(fmaxf(v.z * sc.z + sh.z, 0.f));
  o.w = pack_bf16q(fmaxf(v.w * sc.w + sh.w, 0.f));
  ((uint4*)X)[i] = o;
}

// BN+ReLU (fp32 out) for [R][C] row-major, in place. C4 = C/4.
__global__ void bn_relu_cols4_kernel(float* __restrict__ X, const float* __restrict__ scale,
                                     const float* __restrict__ shift, int n4, int C4) {
  int i = blockIdx.x * blockDim.x + threadIdx.x;
  if (i >= n4) return;
  int c4 = i % C4;
  float4 v = ((float4*)X)[i];
  float4 sc = ((const float4*)scale)[c4];
  float4 sh = ((const float4*)shift)[c4];
  v.x = fmaxf(v.x * sc.x + sh.x, 0.f);
  v.y = fmaxf(v.y * sc.y + sh.y, 0.f);
  v.z = fmaxf(v.z * sc.z + sh.z, 0.f);
  v.w = fmaxf(v.w * sc.w + sh.w, 0.f);
  ((float4*)X)[i] = v;
}

// ============================================================================
// bf16-split MFMA GEMM (3 terms), 128x64 tile, BK=32. For N%64 shapes.
// ============================================================================
template <int BIASRELU>
__global__ __launch_bounds__(256) void gemm_bf16q_kernel(
    const uint32_t* __restrict__ A, const uint32_t* __restrict__ B,
    const float* __restrict__ bias, float* __restrict__ C, int M, int N, int K) {
  __shared__ short Ah[128 * 32], Al[128 * 32], Bh[64 * 32], Bl[64 * 32];
  const int t = threadIdx.x;
  const int nTN = N >> 6;
  const int mPer = (M >> 7) >> 3;
  const int bid = blockIdx.x;
  const int xcd = bid & 7, qq = bid >> 3;
  const int m0 = (xcd * mPer + qq / nTN) << 7;
  const int n0 = (qq % nTN) << 6;
  const int w = t >> 6, l = t & 63;
  const int wrow = (w >> 1) << 6, wcol = (w & 1) << 5;
  const int lr = l & 15, lg = l >> 4;
  const int ar = t >> 1, akh = (t & 1) << 4;
  const int br = t >> 2, bkh = (t & 3) << 3;
  const int asw = (ar & 3) << 3, bsw = (br & 3) << 3;
  const uint32_t* Ap = A + (size_t)(m0 + ar) * K + akh;
  const uint32_t* Bp = B + (size_t)(n0 + br) * K + bkh;
  f32x4 acc[4][2];
#pragma unroll
  for (int i = 0; i < 4; i++)
#pragma unroll
    for (int j = 0; j < 2; j++) acc[i][j] = (f32x4){0.f, 0.f, 0.f, 0.f};
  uint4 ra0 = *(const uint4*)(Ap + 0), ra1 = *(const uint4*)(Ap + 4);
  uint4 ra2 = *(const uint4*)(Ap + 8), ra3 = *(const uint4*)(Ap + 12);
  uint4 rb0 = *(const uint4*)(Bp + 0), rb1 = *(const uint4*)(Bp + 4);
  const int NS = K >> 5;
#define STORE_G(ARR_H, ARR_L, ROW, KB, SW, U)                                   \
    {                                                                           \
      uint32_t h0 = (U.x >> 16) | (U.y & 0xffff0000u);                          \
      uint32_t h1 = (U.z >> 16) | (U.w & 0xffff0000u);                          \
      uint32_t l0 = (U.x & 0xffffu) | (U.y << 16);                              \
      uint32_t l1 = (U.z & 0xffffu) | (U.w << 16);                              \
      int idx = (ROW) * 32 + ((KB) ^ (SW));                                     \
      *(uint2*)&ARR_H[idx] = make_uint2(h0, h1);                                \
      *(uint2*)&ARR_L[idx] = make_uint2(l0, l1);                                \
    }
  for (int s = 0; s < NS; s++) {
    __syncthreads();
    STORE_G(Ah, Al, ar, akh + 0, asw, ra0)
    STORE_G(Ah, Al, ar, akh + 4, asw, ra1)
    STORE_G(Ah, Al, ar, akh + 8, asw, ra2)
    STORE_G(Ah, Al, ar, akh + 12, asw, ra3)
    STORE_G(Bh, Bl, br, bkh + 0, bsw, rb0)
    STORE_G(Bh, Bl, br, bkh + 4, bsw, rb1)
    __syncthreads();
    if (s + 1 < NS) {
      int ko = (s + 1) << 5;
      ra0 = *(const uint4*)(Ap + ko); ra1 = *(const uint4*)(Ap + ko + 4);
      ra2 = *(const uint4*)(Ap + ko + 8); ra3 = *(const uint4*)(Ap + ko + 12);
      rb0 = *(const uint4*)(Bp + ko); rb1 = *(const uint4*)(Bp + ko + 4);
    }
    short8 ahf[4], alf[4], bhf[2], blf[2];
#pragma unroll
    for (int i = 0; i < 4; i++) {
      int R = wrow + i * 16 + lr;
      int kk = (lg << 3) ^ ((R & 3) << 3);
      ahf[i] = *(const short8*)&Ah[R * 32 + kk];
      alf[i] = *(const short8*)&Al[R * 32 + kk];
    }
#pragma unroll
    for (int j = 0; j < 2; j++) {
      int Cc = wcol + j * 16 + lr;
      int kk = (lg << 3) ^ ((Cc & 3) << 3);
      bhf[j] = *(const short8*)&Bh[Cc * 32 + kk];
      blf[j] = *(const short8*)&Bl[Cc * 32 + kk];
    }
#pragma unroll
    for (int i = 0; i < 4; i++)
#pragma unroll
      for (int j = 0; j < 2; j++) {
        acc[i][j] = __builtin_amdgcn_mfma_f32_16x16x32_bf16(ahf[i], bhf[j], acc[i][j], 0, 0, 0);
        acc[i][j] = __builtin_amdgcn_mfma_f32_16x16x32_bf16(ahf[i], blf[j], acc[i][j], 0, 0, 0);
        acc[i][j] = __builtin_amdgcn_mfma_f32_16x16x32_bf16(alf[i], bhf[j], acc[i][j], 0, 0, 0);
      }
  }
#pragma unroll
  for (int i = 0; i < 4; i++)
#pragma unroll
    for (int j = 0; j < 2; j++) {
      int n = n0 + wcol + j * 16 + lr;
#pragma unroll
      for (int r = 0; r < 4; r++) {
        int m = m0 + wrow + i * 16 + lg * 4 + r;
        float v = acc[i][j][r];
        if (BIASRELU) v = fmaxf(v + bias[n], 0.f);
        C[(size_t)m * N + n] = v;
      }
    }
}

// ============================================================================
// bf16-split MFMA GEMM (3 terms), BIG tile 128x128, BK=32, 4 waves x 64x64.
// Halves LDS reads per FLOP vs the 128x64 kernel (the LDS-bound fix).
// Grid = (M/128)*(N/128), XCD m-contiguous mapping. Requires N%128==0,
// (M/128)%8==0. ~190 VGPR -> launch_bounds(256,1).
// ============================================================================
__global__ __launch_bounds__(256, 1) void gemm_bf16q_big_kernel(
    const uint32_t* __restrict__ A, const uint32_t* __restrict__ B,
    float* __restrict__ C, int M, int N, int K) {
  __shared__ short Ah[128 * 32], Al[128 * 32], Bh[128 * 32], Bl[128 * 32];
  const int t = threadIdx.x;
  const int nTN = N >> 7;
  const int mPer = (M >> 7) >> 3;
  const int bid = blockIdx.x;
  const int xcd = bid & 7, qq = bid >> 3;
  const int m0 = (xcd * mPer + qq / nTN) << 7;
  const int n0 = (qq % nTN) << 7;
  const int w = t >> 6, l = t & 63;
  const int wrow = (w & 1) << 6, wcol = (w >> 1) << 6;
  const int lr = l & 15, lg = l >> 4;
  const int ar = t >> 1, akh = (t & 1) << 4;   // A & B staging: 2 thr/row
  const int asw = (ar & 3) << 3;
  const uint32_t* Ap = A + (size_t)(m0 + ar) * K + akh;
  const uint32_t* Bp = B + (size_t)(n0 + ar) * K + akh;
  f32x4 acc[4][4];
#pragma unroll
  for (int i = 0; i < 4; i++)
#pragma unroll
    for (int j = 0; j < 4; j++) acc[i][j] = (f32x4){0.f, 0.f, 0.f, 0.f};
  uint4 ra0 = *(const uint4*)(Ap + 0), ra1 = *(const uint4*)(Ap + 4);
  uint4 ra2 = *(const uint4*)(Ap + 8), ra3 = *(const uint4*)(Ap + 12);
  uint4 rb0 = *(const uint4*)(Bp + 0), rb1 = *(const uint4*)(Bp + 4);
  uint4 rb2 = *(const uint4*)(Bp + 8), rb3 = *(const uint4*)(Bp + 12);
  const int NS = K >> 5;
  for (int s = 0; s < NS; s++) {
    __syncthreads();
    STORE_G(Ah, Al, ar, akh + 0, asw, ra0)
    STORE_G(Ah, Al, ar, akh + 4, asw, ra1)
    STORE_G(Ah, Al, ar, akh + 8, asw, ra2)
    STORE_G(Ah, Al, ar, akh + 12, asw, ra3)
    STORE_G(Bh, Bl, ar, akh + 0, asw, rb0)
    STORE_G(Bh, Bl, ar, akh + 4, asw, rb1)
    STORE_G(Bh, Bl, ar, akh + 8, asw, rb2)
    STORE_G(Bh, Bl, ar, akh + 12, asw, rb3)
    __syncthreads();
    if (s + 1 < NS) {
      int ko = (s + 1) << 5;
      ra0 = *(const uint4*)(Ap + ko); ra1 = *(const uint4*)(Ap + ko + 4);
      ra2 = *(const uint4*)(Ap + ko + 8); ra3 = *(const uint4*)(Ap + ko + 12);
      rb0 = *(const uint4*)(Bp + ko); rb1 = *(const uint4*)(Bp + ko + 4);
      rb2 = *(const uint4*)(Bp + ko + 8); rb3 = *(const uint4*)(Bp + ko + 12);
    }
    short8 ahf[4], alf[4], bhf[4], blf[4];
#pragma unroll
    for (int i = 0; i < 4; i++) {
      int R = wrow + i * 16 + lr;
      int kk = (lg << 3) ^ ((R & 3) << 3);
      ahf[i] = *(const short8*)&Ah[R * 32 + kk];
      alf[i] = *(const short8*)&Al[R * 32 + kk];
    }
#pragma unroll
    for (int j = 0; j < 4; j++) {
      int Cc = wcol + j * 16 + lr;
      int kk = (lg << 3) ^ ((Cc & 3) << 3);
      bhf[j] = *(const short8*)&Bh[Cc * 32 + kk];
      blf[j] = *(const short8*)&Bl[Cc * 32 + kk];
    }
#pragma unroll
    for (int i = 0; i < 4; i++)
#pragma unroll
      for (int j = 0; j < 4; j++) {
        acc[i][j] = __builtin_amdgcn_mfma_f32_16x16x32_bf16(ahf[i], bhf[j], acc[i][j], 0, 0, 0);
        acc[i][j] = __builtin_amdgcn_mfma_f32_16x16x32_bf16(ahf[i], blf[j], acc[i][j], 0, 0, 0);
        acc[i][j] = __builtin_amdgcn_mfma_f32_16x16x32_bf16(alf[i], bhf[j], acc[i][j], 0, 0, 0);
      }
  }
#undef STORE_G
#pragma unroll
  for (int i = 0; i < 4; i++)
#pragma unroll
    for (int j = 0; j < 4; j++) {
      int n = n0 + wcol + j * 16 + lr;
#pragma unroll
      for (int r = 0; r < 4; r++) {
        int m = m0 + wrow + i * 16 + lg * 4 + r;
        C[(size_t)m * N + n] = acc[i][j][r];
      }
    }
}

// ============================================================================
// heads (double accumulation; sw_logits amplified 10x by TAU)
// ============================================================================
__global__ __launch_bounds__(256) void heads_kernel(
    const float* __restrict__ dpen, const float* __restrict__ dfc_w,
    const float* __restrict__ dfc_b, const float* __restrict__ sw_w,
    const float* __restrict__ sw_b, float* __restrict__ out_dom,
    float* __restrict__ swbuf) {
  int t = blockIdx.x * 256 + threadIdx.x;
  int b = t >> 2, j = t & 3;
  const float* row = dpen + (size_t)b * 384;
  const float* wr = (j < 2) ? (dfc_w + j * 384) : (sw_w + (j - 2) * 384);
  double s = 0.0;
  for (int k = 0; k < 384; k++) s += (double)row[k] * (double)wr[k];
  s += (double)((j < 2) ? dfc_b[j] : sw_b[j - 2]);
  if (j < 2) out_dom[b * 2 + j] = (float)s;
  else swbuf[b * 2 + (j - 2)] = (float)s;
}

// ============================================================================
// gumbel-softmax + categorical partition choice (threefry partitionable).
// ============================================================================
__global__ __launch_bounds__(256) void partition_kernel(
    const float* __restrict__ swbuf, float* __restrict__ out_pid,
    int* __restrict__ pidxI, float* __restrict__ ysum,
    uint32_t k1a, uint32_t k1b, uint32_t k2a, uint32_t k2b) {
  int b = blockIdx.x * 256 + threadIdx.x;
  if (b >= 4096) return;
  uint32_t j0 = (uint32_t)(2 * b), j1 = (uint32_t)(2 * b + 1);
  float f0 = u01_from_bits(tf_bits32(k1a, k1b, j0));
  float f1 = u01_from_bits(tf_bits32(k1a, k1b, j1));
  const float MINV = 1e-10f;
  float u0 = fmaxf(MINV, f0 * (1.0f - MINV) + MINV);
  float u1 = fmaxf(MINV, f1 * (1.0f - MINV) + MINV);
  double g0 = -log(-log((double)u0));
  double g1 = -log(-log((double)u1));
  double s0 = (double)swbuf[2 * b], s1 = (double)swbuf[2 * b + 1];
  double x0 = (s0 + g0) / 0.1;
  double x1 = (s1 + g1) / 0.1;
  double mx = fmax(x0, x1);
  double e0 = exp(x0 - mx), e1 = exp(x1 - mx);
  double es = e0 + e1;
  double y0 = e0 / es, y1 = e1 / es;
  float h0 = u01_from_bits(tf_bits32(k2a, k2b, j0));
  float h1 = u01_from_bits(tf_bits32(k2a, k2b, j1));
  const float TINY = 1.17549435e-38f;
  float v0 = fmaxf(TINY, h0 * (1.0f - TINY) + TINY);
  float v1 = fmaxf(TINY, h1 * (1.0f - TINY) + TINY);
  double gg0 = -log(-log((double)v0));
  double gg1 = -log(-log((double)v1));
  double l0 = log(y0 + 1e-20) + gg0;
  double l1 = log(y1 + 1e-20) + gg1;
  int p = (l1 > l0) ? 1 : 0;
  out_pid[b] = (float)p;
  pidxI[b] = p;
  ysum[b] = (float)(y0 + y1);
}

// ============================================================================
// final head
// ============================================================================
__global__ __launch_bounds__(256) void final_kernel(
    const float* __restrict__ h, const float* __restrict__ p2w,
    const float* __restrict__ p2b, const int* __restrict__ pidxI,
    const float* __restrict__ ysum, float* __restrict__ out0) {
  int t = blockIdx.x * 256 + threadIdx.x;
  if (t >= 40960) return;
  int b = t / 10, c = t % 10;
  int p = pidxI[b];
  const float* hr = h + (size_t)b * 384 + p * 192;
  const float* wr = p2w + ((size_t)p * 10 + c) * 192;
  float s = 0.f;
  for (int o = 0; o < 192; o++) s += hr[o] * wr[o];
  s += p2b[p * 10 + c];
  out0[t] = s * ysum[b];
}

// ============================================================================
// Launch orchestration. All big matmuls on MFMA (3-term bf16 split).
// ~235 MB workspace (proven layout).
// ============================================================================
extern "C" void kernel_launch(void* const* d_in, const int* in_sizes, int n_in,
                              void* d_out, int out_size, void* d_ws, size_t ws_size,
                              hipStream_t stream) {
  const float* input   = (const float*)d_in[0];
  const float* conv1_w = (const float*)d_in[1];
  const float* bn1_g   = (const float*)d_in[3];
  const float* bn1_b   = (const float*)d_in[4];
  const float* conv2_w = (const float*)d_in[5];
  const float* bn2_g   = (const float*)d_in[7];
  const float* bn2_b   = (const float*)d_in[8];
  const float* conv3_w = (const float*)d_in[9];
  const float* bn3_g   = (const float*)d_in[11];
  const float* bn3_b   = (const float*)d_in[12];
  const float* pre_w   = (const float*)d_in[13];
  const float* bnp_g   = (const float*)d_in[15];
  const float* bnp_b   = (const float*)d_in[16];
  const float* disc_w  = (const float*)d_in[17];
  const float* bnd_g   = (const float*)d_in[19];
  const float* bnd_b   = (const float*)d_in[20];
  const float* dfc_w   = (const float*)d_in[21];
  const float* dfc_b   = (const float*)d_in[22];
  const float* sw_w    = (const float*)d_in[23];
  const float* sw_b    = (const float*)d_in[24];
  const float* p1_w    = (const float*)d_in[25];
  const float* p1_b    = (const float*)d_in[26];
  const float* p2_w    = (const float*)d_in[27];
  const float* p2_b    = (const float*)d_in[28];

  float* W = (float*)d_ws;
  float* pool1  = W + 0;           // [4096][32][16][16], raw -> packed in place
  uint32_t* pool1q = (uint32_t*)pool1;
  float* pool2  = W + 33554432;    // [4096][64][8][8], raw -> packed in place
  uint32_t* pool2q = (uint32_t*)pool2;
  float* act3   = W + 0;           // [4096][128][8][8], alias pool1 (dead)
  uint32_t* Acvt = (uint32_t*)(W + 0);          // act3 packed in place
  uint32_t* Bcvt = (uint32_t*)(W + 33554432);   // pre_w packed (pool2q dead then)
  uint32_t* discq = (uint32_t*)(W + 41943040);  // disc_w packed (dead region)
  uint32_t* p1q   = (uint32_t*)(W + 42336256);  // p1_w packed
  float* featp  = W + 50331648;    // [4096][1024], raw -> packed in place
  uint32_t* featq = (uint32_t*)featp;
  short* wh3    = (short*)(W + 50331648);       // conv3 w hi (dead until pre-FC)
  short* wl3    = (short*)(W + 50368512);
  short* wh2    = (short*)(W + 50405376);       // conv2 w hi
  short* wl2    = (short*)(W + 50414592);
  float* dpen   = W + 54525952;
  float* hbuf   = W + 56098816;
  float* swbuf  = W + 57671680;
  float* ysum   = W + 57679872;
  int*   pidxI  = (int*)(W + 57683968);
  float* part   = W + 57688064;
  double* sums  = (double*)(W + 58736640);
  float* scale  = W + 58769408;
  float* shift  = W + 58770432;

  float* out_cls = (float*)d_out;
  float* out_dom = out_cls + 40960;
  float* out_pid = out_cls + 49152;

  uint32_t k1a, k1b, k2a, k2b;
  threefry2x32(0u, 42u, 0u, 0u, k1a, k1b);
  threefry2x32(0u, 42u, 0u, 1u, k2a, k2b);

  // --- conv1 fused + BN + pack ---
  conv1_fused_kernel<<<dim3(4096), dim3(256), 0, stream>>>(input, conv1_w, pool1, part);
  reduce_partials_kernel<<<dim3(64), dim3(256), 0, stream>>>(part, 4096, 64, sums);
  bn_finalize_kernel<<<dim3(1), dim3(64), 0, stream>>>(sums, 1, 0, bn1_g, bn1_b, scale, shift, 32, 1.0 / (4096.0 * 1024.0));
  bn_relu_pack_vec4_kernel<8, 31><<<dim3(32768), dim3(256), 0, stream>>>(pool1, scale, shift, 8388608);

  // --- conv2 via MFMA (fused pool) + BN + pack ---
  prep_w2_kernel<<<dim3(72), dim3(256), 0, stream>>>(conv2_w, wh2, wl2);
  conv2_mfma_kernel<<<dim3(4096), dim3(256), 0, stream>>>(pool1q, wh2, wl2, pool2, part);
  reduce_partials_kernel<<<dim3(128), dim3(256), 0, stream>>>(part, 4096, 128, sums);
  bn_finalize_kernel<<<dim3(1), dim3(64), 0, stream>>>(sums, 1, 0, bn2_g, bn2_b, scale, shift, 64, 1.0 / (4096.0 * 256.0));
  bn_relu_pack_vec4_kernel<6, 63><<<dim3(16384), dim3(256), 0, stream>>>(pool2, scale, shift, 4194304);

  // --- conv3 via MFMA + BN + pack ---
  prep_w3_kernel<<<dim3(288), dim3(256), 0, stream>>>(conv3_w, wh3, wl3);
  conv3_mfma_kernel<<<dim3(4096), dim3(256), 0, stream>>>(pool2q, wh3, wl3, act3, part);
  reduce_partials_kernel<<<dim3(256), dim3(256), 0, stream>>>(part, 4096, 256, sums);
  bn_finalize_kernel<<<dim3(1), dim3(128), 0, stream>>>(sums, 1, 0, bn3_g, bn3_b, scale, shift, 128, 1.0 / (4096.0 * 64.0));
  bn_relu_pack_vec4_kernel<6, 127><<<dim3(32768), dim3(256), 0, stream>>>(act3, scale, shift, 8388608);

  // --- pre FC 8192->1024 via MFMA (big tile) + BN + ReLU + pack ---
  cvt_bf16q_kernel<<<dim3(8192), dim3(256), 0, stream>>>(pre_w, Bcvt, 2097152);
  gemm_bf16q_big_kernel<<<dim3(256), dim3(256), 0, stream>>>(Acvt, Bcvt, featp, 4096, 1024, 8192);
  col_stats_kernel<<<dim3(16, 8), dim3(1024), 0, stream>>>(featp, 4096, 1024, 8, sums);
  bn_finalize_kernel<<<dim3(4), dim3(256), 0, stream>>>(sums, 8, 2048, bnp_g, bnp_b, scale, shift, 1024, 1.0 / 4096.0);
  bn_relu_pack_cols4_kernel<<<dim3(4096), dim3(256), 0, stream>>>(featp, scale, shift, 1048576, 256);

  // --- disc FC 1024->384 via MFMA + BN + ReLU (fp32 out for heads) ---
  cvt_bf16q_kernel<<<dim3(384), dim3(256), 0, stream>>>(disc_w, discq, 98304);
  cvt_bf16q_kernel<<<dim3(384), dim3(256), 0, stream>>>(p1_w, p1q, 98304);
  gemm_bf16q_kernel<0><<<dim3(192), dim3(256), 0, stream>>>(featq, discq, (const float*)nullptr, dpen, 4096, 384, 1024);
  col_stats_kernel<<<dim3(6, 8), dim3(1024), 0, stream>>>(dpen, 4096, 384, 8, sums);
  bn_finalize_kernel<<<dim3(2), dim3(256), 0, stream>>>(sums, 8, 768, bnd_g, bnd_b, scale, shift, 384, 1.0 / 4096.0);
  bn_relu_cols4_kernel<<<dim3(1536), dim3(256), 0, stream>>>(dpen, scale, shift, 393216, 96);

  // --- heads + partition sampling ---
  heads_kernel<<<dim3(64), dim3(256), 0, stream>>>(dpen, dfc_w, dfc_b, sw_w, sw_b, out_dom, swbuf);
  partition_kernel<<<dim3(16), dim3(256), 0, stream>>>(swbuf, out_pid, pidxI, ysum, k1a, k1b, k2a, k2b);

  // --- experts: p1 via MFMA (bias+relu epilogue), then gather + p2 ---
  gemm_bf16q_kernel<1><<<dim3(192), dim3(256), 0, stream>>>(featq, p1q, p1_b, hbuf, 4096, 384, 1024);
  final_kernel<<<dim3(160), dim3(256), 0, stream>>>(hbuf, p2_w, p2_b, pidxI, ysum, out_cls);
}

// Round 13
// 927.583 us; speedup vs baseline: 1.1300x; 1.1300x over previous
//
#include <hip/hip_runtime.h>
#include <cstdint>
#include <cstddef>

typedef __attribute__((ext_vector_type(8))) short short8;    // 8 bf16 (4 VGPR)
typedef __attribute__((ext_vector_type(4))) float f32x4;     // MFMA acc

// ============================================================================
// Threefry2x32 (matches jax._src.prng.threefry2x32).
// ============================================================================
__host__ __device__ inline void threefry2x32(uint32_t k0, uint32_t k1,
                                             uint32_t x0, uint32_t x1,
                                             uint32_t& o0, uint32_t& o1) {
  uint32_t ks2 = k0 ^ k1 ^ 0x1BD11BDAu;
  uint32_t v0 = x0 + k0, v1 = x1 + k1;
#define TF_R(r) { v0 += v1; v1 = (v1 << (r)) | (v1 >> (32 - (r))); v1 ^= v0; }
  TF_R(13) TF_R(15) TF_R(26) TF_R(6)
  v0 += k1; v1 += ks2 + 1u;
  TF_R(17) TF_R(29) TF_R(16) TF_R(24)
  v0 += ks2; v1 += k0 + 2u;
  TF_R(13) TF_R(15) TF_R(26) TF_R(6)
  v0 += k0; v1 += k1 + 3u;
  TF_R(17) TF_R(29) TF_R(16) TF_R(24)
  v0 += k1; v1 += ks2 + 4u;
  TF_R(13) TF_R(15) TF_R(26) TF_R(6)
  v0 += ks2; v1 += k0 + 5u;
#undef TF_R
  o0 = v0; o1 = v1;
}

__device__ __forceinline__ uint32_t tf_bits32(uint32_t k0, uint32_t k1, uint32_t j) {
  uint32_t o0, o1;
  threefry2x32(k0, k1, 0u, j, o0, o1);
  return o0 ^ o1;
}

__device__ __forceinline__ float u01_from_bits(uint32_t bits) {
  return __uint_as_float((bits >> 9) | 0x3f800000u) - 1.0f;  // [0,1)
}

__device__ __forceinline__ float waveSum(float v) {
#pragma unroll
  for (int off = 32; off > 0; off >>= 1) v += __shfl_down(v, off, 64);
  return v;
}

// ============================================================================
// conv1 fused: conv(3->32) + BN partials (unpooled) + RAW 2x2 maxpool store.
// ============================================================================
__global__ __launch_bounds__(256) void conv1_fused_kernel(
    const float* __restrict__ in, const float* __restrict__ w,
    float* __restrict__ outraw, float* __restrict__ partials) {
  __shared__ float ins[3 * 34 * 34];
  __shared__ float red[4][64];
  const int b = blockIdx.x, t = threadIdx.x;
  for (int i = t; i < 3 * 34 * 34; i += 256) {
    int ci = i / 1156, r = i % 1156, iy = r / 34, ix = r % 34;
    int y = iy - 1, x = ix - 1;
    float v = 0.f;
    if ((unsigned)y < 32u && (unsigned)x < 32u)
      v = in[(((size_t)b * 3 + ci) * 32 + y) * 32 + x];
    ins[i] = v;
  }
  __syncthreads();
  const int py = t >> 4, px = t & 15, wv = t >> 6, ln = t & 63;
  float win[3][4][4];
#pragma unroll
  for (int ci = 0; ci < 3; ci++)
#pragma unroll
    for (int r = 0; r < 4; r++)
#pragma unroll
      for (int c = 0; c < 4; c++)
        win[ci][r][c] = ins[ci * 1156 + (2 * py + r) * 34 + (2 * px + c)];
#pragma unroll 1
  for (int co = 0; co < 32; co++) {
    float acc00 = 0.f, acc01 = 0.f, acc10 = 0.f, acc11 = 0.f;
#pragma unroll
    for (int ci = 0; ci < 3; ci++) {
      const float* wp = w + (co * 3 + ci) * 9;  // wave-uniform -> s_load
#pragma unroll
      for (int dy = 0; dy < 3; dy++)
#pragma unroll
        for (int dx = 0; dx < 3; dx++) {
          float wvv = wp[dy * 3 + dx];
          acc00 += win[ci][dy][dx] * wvv;
          acc01 += win[ci][dy][dx + 1] * wvv;
          acc10 += win[ci][dy + 1][dx] * wvv;
          acc11 += win[ci][dy + 1][dx + 1] * wvv;
        }
    }
    float sm = acc00 + acc01 + acc10 + acc11;
    float sq = acc00 * acc00 + acc01 * acc01 + acc10 * acc10 + acc11 * acc11;
    float s = waveSum(sm), q = waveSum(sq);
    if (ln == 0) { red[wv][2 * co] = s; red[wv][2 * co + 1] = q; }
    float m = fmaxf(fmaxf(acc00, acc01), fmaxf(acc10, acc11));  // RAW max
    outraw[(((size_t)b * 32 + co) * 16 + py) * 16 + px] = m;
  }
  __syncthreads();
  for (int i = t; i < 64; i += 256)
    partials[(size_t)b * 64 + i] = red[0][i] + red[1][i] + red[2][i] + red[3][i];
}

// ============================================================================
// bf16-split helpers
// ============================================================================
__device__ __forceinline__ uint32_t pack_bf16q(float x) {
  uint32_t u = __float_as_uint(x);
  uint32_t hi = (u + 0x7fffu + ((u >> 16) & 1u)) & 0xffff0000u;
  float r = x - __uint_as_float(hi);
  uint32_t v = __float_as_uint(r);
  uint32_t lo = (v + 0x7fffu + ((v >> 16) & 1u)) >> 16;
  return hi | lo;
}

__global__ void cvt_bf16q_kernel(const float* X, uint32_t* Y, int n4) {
  int i = blockIdx.x * blockDim.x + threadIdx.x;
  if (i >= n4) return;
  float4 x = ((const float4*)X)[i];
  uint4 o;
  o.x = pack_bf16q(x.x); o.y = pack_bf16q(x.y);
  o.z = pack_bf16q(x.z); o.w = pack_bf16q(x.w);
  ((uint4*)Y)[i] = o;
}

// conv2 weight prepack: w [64][32][9] fp32 -> wh/wl [9][64][32] bf16 planes.
__global__ void prep_w2_kernel(const float* __restrict__ w, short* __restrict__ wh,
                               short* __restrict__ wl) {
  int idx = blockIdx.x * 256 + threadIdx.x;
  if (idx >= 64 * 32 * 9) return;
  int tp = idx % 9, rem = idx / 9;
  int ci = rem % 32, co = rem / 32;
  uint32_t pq = pack_bf16q(w[idx]);
  size_t o = ((size_t)tp * 64 + co) * 32 + ci;
  wh[o] = (short)(pq >> 16);
  wl[o] = (short)(pq & 0xffffu);
}

// conv3 weight prepack: w [128][64][9] fp32 -> wh/wl [9][128][64] bf16 planes.
__global__ void prep_w3_kernel(const float* __restrict__ w, short* __restrict__ wh,
                               short* __restrict__ wl) {
  int idx = blockIdx.x * 256 + threadIdx.x;
  if (idx >= 128 * 64 * 9) return;
  int tp = idx % 9, rem = idx / 9;
  int ci = rem % 64, co = rem / 64;
  uint32_t pq = pack_bf16q(w[idx]);
  size_t o = ((size_t)tp * 128 + co) * 64 + ci;
  wh[o] = (short)(pq >> 16);
  wl[o] = (short)(pq & 0xffffu);
}

// ============================================================================
// conv2 via MFMA implicit GEMM (bf16-split, 3 terms).
// ============================================================================
__global__ __launch_bounds__(256) void conv2_mfma_kernel(
    const uint32_t* __restrict__ inq, const short* __restrict__ wh,
    const short* __restrict__ wl, float* __restrict__ outpool,
    float* __restrict__ partials) {
  __shared__ short Xh[324 * 32], Xl[324 * 32];
  __shared__ float red[4][128];
  const int b = blockIdx.x, t = threadIdx.x;
  for (int i = t; i < 324 * 16; i += 256) {
    int row = i >> 4;
    int py = row / 18, pxx = row % 18;
    if (py == 0 || py == 17 || pxx == 0 || pxx == 17) {
      ((uint32_t*)Xh)[i] = 0u;
      ((uint32_t*)Xl)[i] = 0u;
    }
  }
  for (int i = t; i < 4096; i += 256) {
    int p = i >> 8, px = i & 255;
    int y = px >> 4, x = px & 15;
    uint32_t ua = inq[((size_t)b * 32 + 2 * p) * 256 + px];
    uint32_t ub = inq[((size_t)b * 32 + 2 * p + 1) * 256 + px];
    uint32_t h = (ua >> 16) | (ub & 0xffff0000u);
    uint32_t l = (ua & 0xffffu) | (ub << 16);
    int row = (y + 1) * 18 + (x + 1);
    int ci2 = (2 * p) ^ ((row & 3) << 3);  // swizzled, stays even
    ((uint32_t*)Xh)[(row * 32 + ci2) >> 1] = h;
    ((uint32_t*)Xl)[(row * 32 + ci2) >> 1] = l;
  }
  __syncthreads();
  const int w = t >> 6, l = t & 63;
  const int lr = l & 15, lg = l >> 4;
  f32x4 acc[4][4];  // [co block][px block]
#pragma unroll
  for (int i = 0; i < 4; i++)
#pragma unroll
    for (int j = 0; j < 4; j++) acc[i][j] = (f32x4){0.f, 0.f, 0.f, 0.f};
#pragma unroll 1
  for (int tap = 0; tap < 9; tap++) {
    const int dy = tap / 3, dx = tap % 3;
    short8 awh[4], awl[4];
#pragma unroll
    for (int i = 0; i < 4; i++) {
      size_t off = ((size_t)tap * 64 + i * 16 + lr) * 32 + lg * 8;
      awh[i] = *(const short8*)(wh + off);
      awl[i] = *(const short8*)(wl + off);
    }
    short8 bxh[4], bxl[4];
#pragma unroll
    for (int j = 0; j < 4; j++) {
      int y = w * 4 + j, x = lr;
      int row = (y + dy) * 18 + (x + dx);
      int ci = (lg * 8) ^ ((row & 3) << 3);
      bxh[j] = *(const short8*)&Xh[row * 32 + ci];
      bxl[j] = *(const short8*)&Xl[row * 32 + ci];
    }
#pragma unroll
    for (int i = 0; i < 4; i++)
#pragma unroll
      for (int j = 0; j < 4; j++) {
        acc[i][j] = __builtin_amdgcn_mfma_f32_16x16x32_bf16(awh[i], bxh[j], acc[i][j], 0, 0, 0);
        acc[i][j] = __builtin_amdgcn_mfma_f32_16x16x32_bf16(awh[i], bxl[j], acc[i][j], 0, 0, 0);
        acc[i][j] = __builtin_amdgcn_mfma_f32_16x16x32_bf16(awl[i], bxh[j], acc[i][j], 0, 0, 0);
      }
  }
#pragma unroll
  for (int i = 0; i < 4; i++)
#pragma unroll
    for (int r = 0; r < 4; r++) {
      int co = i * 16 + lg * 4 + r;
      float v0 = acc[i][0][r], v1 = acc[i][1][r], v2 = acc[i][2][r], v3 = acc[i][3][r];
      float s = v0 + v1 + v2 + v3;
      float q = v0 * v0 + v1 * v1 + v2 * v2 + v3 * v3;
#pragma unroll
      for (int off = 1; off <= 8; off <<= 1) {
        s += __shfl_xor(s, off, 64);
        q += __shfl_xor(q, off, 64);
      }
      if (lr == 0) { red[w][2 * co] = s; red[w][2 * co + 1] = q; }
      float h0 = fmaxf(v0, __shfl_xor(v0, 1, 64));
      float h1 = fmaxf(v1, __shfl_xor(v1, 1, 64));
      float h2 = fmaxf(v2, __shfl_xor(v2, 1, 64));
      float h3 = fmaxf(v3, __shfl_xor(v3, 1, 64));
      float pm0 = fmaxf(h0, h1);
      float pm1 = fmaxf(h2, h3);
      if ((lr & 1) == 0) {
        size_t base = ((size_t)b * 64 + co) * 64 + (w * 2) * 8 + (lr >> 1);
        outpool[base] = pm0;
        outpool[base + 8] = pm1;
      }
    }
  __syncthreads();
  for (int i = t; i < 128; i += 256)
    partials[(size_t)b * 128 + i] = red[0][i] + red[1][i] + red[2][i] + red[3][i];
}

// ============================================================================
// conv3 via MFMA implicit GEMM (bf16-split, 3 terms).
// ============================================================================
__global__ __launch_bounds__(256) void conv3_mfma_kernel(
    const uint32_t* __restrict__ inq, const short* __restrict__ wh,
    const short* __restrict__ wl, float* __restrict__ outraw,
    float* __restrict__ partials) {
  __shared__ short Xh[100 * 64], Xl[100 * 64];
  __shared__ float red[256];
  const int b = blockIdx.x, t = threadIdx.x;
  for (int i = t; i < 100 * 32; i += 256) {
    int row = i >> 5;
    int py = row / 10, pxx = row % 10;
    if (py == 0 || py == 9 || pxx == 0 || pxx == 9) {
      ((uint32_t*)Xh)[i] = 0u;
      ((uint32_t*)Xl)[i] = 0u;
    }
  }
  for (int i = t; i < 2048; i += 256) {
    int p = i >> 6, px = i & 63;
    int y = px >> 3, x = px & 7;
    uint32_t ua = inq[((size_t)b * 64 + 2 * p) * 64 + px];
    uint32_t ub = inq[((size_t)b * 64 + 2 * p + 1) * 64 + px];
    uint32_t h = (ua >> 16) | (ub & 0xffff0000u);
    uint32_t l = (ua & 0xffffu) | (ub << 16);
    int row = (y + 1) * 10 + (x + 1);
    int ci2 = (2 * p) ^ ((row & 7) << 3);
    ((uint32_t*)Xh)[(row * 64 + ci2) >> 1] = h;
    ((uint32_t*)Xl)[(row * 64 + ci2) >> 1] = l;
  }
  __syncthreads();
  const int w = t >> 6, l = t & 63;
  const int lr = l & 15, lg = l >> 4;
  const int co_base = w * 32;
  f32x4 acc[2][4];
#pragma unroll
  for (int i = 0; i < 2; i++)
#pragma unroll
    for (int j = 0; j < 4; j++) acc[i][j] = (f32x4){0.f, 0.f, 0.f, 0.f};
#pragma unroll 1
  for (int tap = 0; tap < 9; tap++) {
    const int dy = tap / 3, dx = tap % 3;
#pragma unroll
    for (int sl = 0; sl < 2; sl++) {
      short8 awh[2], awl[2];
#pragma unroll
      for (int i = 0; i < 2; i++) {
        size_t off = ((size_t)tap * 128 + co_base + i * 16 + lr) * 64 + sl * 32 + lg * 8;
        awh[i] = *(const short8*)(wh + off);
        awl[i] = *(const short8*)(wl + off);
      }
      short8 bxh[4], bxl[4];
#pragma unroll
      for (int j = 0; j < 4; j++) {
        int px = j * 16 + lr;
        int row = ((px >> 3) + dy) * 10 + (px & 7) + dx;
        int ci = (sl * 32 + lg * 8) ^ ((row & 7) << 3);
        bxh[j] = *(const short8*)&Xh[row * 64 + ci];
        bxl[j] = *(const short8*)&Xl[row * 64 + ci];
      }
#pragma unroll
      for (int i = 0; i < 2; i++)
#pragma unroll
        for (int j = 0; j < 4; j++) {
          acc[i][j] = __builtin_amdgcn_mfma_f32_16x16x32_bf16(awh[i], bxh[j], acc[i][j], 0, 0, 0);
          acc[i][j] = __builtin_amdgcn_mfma_f32_16x16x32_bf16(awh[i], bxl[j], acc[i][j], 0, 0, 0);
          acc[i][j] = __builtin_amdgcn_mfma_f32_16x16x32_bf16(awl[i], bxh[j], acc[i][j], 0, 0, 0);
        }
    }
  }
#pragma unroll
  for (int i = 0; i < 2; i++)
#pragma unroll
    for (int r = 0; r < 4; r++) {
      int co = co_base + i * 16 + lg * 4 + r;
      float s = 0.f, q = 0.f;
#pragma unroll
      for (int j = 0; j < 4; j++) {
        float v = acc[i][j][r];
        outraw[((size_t)b * 128 + co) * 64 + j * 16 + lr] = v;
        s += v; q += v * v;
      }
#pragma unroll
      for (int off = 1; off <= 8; off <<= 1) {
        s += __shfl_xor(s, off, 64);
        q += __shfl_xor(q, off, 64);
      }
      if (lr == 0) { red[2 * co] = s; red[2 * co + 1] = q; }
    }
  __syncthreads();
  for (int i = t; i < 256; i += 256) partials[(size_t)b * 256 + i] = red[i];
}

// ============================================================================
// BN helpers
// ============================================================================
__global__ __launch_bounds__(256) void reduce_partials_kernel(
    const float* __restrict__ partials, int nblk, int Q, double* __restrict__ sums) {
  int q = blockIdx.x;
  double acc = 0.0;
  for (int i = threadIdx.x; i < nblk; i += 256) acc += (double)partials[(size_t)i * Q + q];
  __shared__ double red[256];
  red[threadIdx.x] = acc;
  __syncthreads();
  for (int s = 128; s > 0; s >>= 1) {
    if (threadIdx.x < s) red[threadIdx.x] += red[threadIdx.x + s];
    __syncthreads();
  }
  if (threadIdx.x == 0) sums[q] = red[0];
}

__global__ __launch_bounds__(1024) void col_stats_kernel(
    const float* __restrict__ X, int R, int C, int nch, double* __restrict__ sums) {
  int c0 = blockIdx.x * 64, chunk = blockIdx.y;
  int cl = threadIdx.x & 63, rg = threadIdx.x >> 6;
  int rows = R / nch, rbeg = chunk * rows, rend = rbeg + rows;
  double s = 0.0, sq = 0.0;
  for (int r = rbeg + rg; r < rend; r += 16) {
    float v = X[(size_t)r * C + c0 + cl];
    s += v; sq += (double)v * (double)v;
  }
  __shared__ double red[16][64][2];
  red[rg][cl][0] = s; red[rg][cl][1] = sq;
  __syncthreads();
  if (rg == 0) {
    for (int i = 1; i < 16; i++) { s += red[i][cl][0]; sq += red[i][cl][1]; }
    sums[(size_t)chunk * 2 * C + 2 * (c0 + cl)] = s;
    sums[(size_t)chunk * 2 * C + 2 * (c0 + cl) + 1] = sq;
  }
}

__global__ void bn_finalize_kernel(const double* __restrict__ sums, int nch, int cst2,
                                   const float* __restrict__ g, const float* __restrict__ b,
                                   float* __restrict__ scale, float* __restrict__ shift,
                                   int C, double invN) {
  int c = blockIdx.x * blockDim.x + threadIdx.x;
  if (c >= C) return;
  double s = 0.0, sq = 0.0;
  for (int ch = 0; ch < nch; ch++) {
    s += sums[(size_t)ch * cst2 + 2 * c];
    sq += sums[(size_t)ch * cst2 + 2 * c + 1];
  }
  double m = s * invN;
  double v = sq * invN - m * m;
  double sc = (double)g[c] / sqrt(v + 1e-5);
  scale[c] = (float)sc;
  shift[c] = (float)((double)b[c] - m * sc);
}

// BN+ReLU+bf16q-pack fused, NCHW layout, in place (fp32 -> packed u32).
template <int LOGHW, int CMASK>
__global__ void bn_relu_pack_vec4_kernel(float* __restrict__ X,
                                         const float* __restrict__ scale,
                                         const float* __restrict__ shift, int n4) {
  int i = blockIdx.x * blockDim.x + threadIdx.x;
  if (i >= n4) return;
  int c = ((i << 2) >> LOGHW) & CMASK;
  float4 v = ((float4*)X)[i];
  float sc = scale[c], sh = shift[c];
  uint4 o;
  o.x = pack_bf16q(fmaxf(v.x * sc + sh, 0.f));
  o.y = pack_bf16q(fmaxf(v.y * sc + sh, 0.f));
  o.z = pack_bf16q(fmaxf(v.z * sc + sh, 0.f));
  o.w = pack_bf16q(fmaxf(v.w * sc + sh, 0.f));
  ((uint4*)X)[i] = o;
}

// BN+ReLU+pack for [R][C] row-major, in place. C4 = C/4.
__global__ void bn_relu_pack_cols4_kernel(float* __restrict__ X,
                                          const float* __restrict__ scale,
                                          const float* __restrict__ shift,
                                          int n4, int C4) {
  int i = blockIdx.x * blockDim.x + threadIdx.x;
  if (i >= n4) return;
  int c4 = i % C4;
  float4 v = ((float4*)X)[i];
  float4 sc = ((const float4*)scale)[c4];
  float4 sh = ((const float4*)shift)[c4];
  uint4 o;
  o.x = pack_bf16q(fmaxf(v.x * sc.x + sh.x, 0.f));
  o.y = pack_bf16q(fmaxf(v.y * sc.y + sh.y, 0.f));
  o.z = pack_bf16q(fmaxf(v.z * sc.z + sh.z, 0.f));
  o.w = pack_bf16q(fmaxf(v.w * sc.w + sh.w, 0.f));
  ((uint4*)X)[i] = o;
}

// BN+ReLU (fp32 out) for [R][C] row-major, in place. C4 = C/4.
__global__ void bn_relu_cols4_kernel(float* __restrict__ X, const float* __restrict__ scale,
                                     const float* __restrict__ shift, int n4, int C4) {
  int i = blockIdx.x * blockDim.x + threadIdx.x;
  if (i >= n4) return;
  int c4 = i % C4;
  float4 v = ((float4*)X)[i];
  float4 sc = ((const float4*)scale)[c4];
  float4 sh = ((const float4*)shift)[c4];
  v.x = fmaxf(v.x * sc.x + sh.x, 0.f);
  v.y = fmaxf(v.y * sc.y + sh.y, 0.f);
  v.z = fmaxf(v.z * sc.z + sh.z, 0.f);
  v.w = fmaxf(v.w * sc.w + sh.w, 0.f);
  ((float4*)X)[i] = v;
}

// elementwise add: X += Y (float4)
__global__ void add_vec4_kernel(float* __restrict__ X, const float* __restrict__ Y, int n4) {
  int i = blockIdx.x * blockDim.x + threadIdx.x;
  if (i >= n4) return;
  float4 a = ((float4*)X)[i];
  float4 b = ((const float4*)Y)[i];
  a.x += b.x; a.y += b.y; a.z += b.z; a.w += b.w;
  ((float4*)X)[i] = a;
}

// full-rank row swizzle: distinct k-block for every row in a 16-row group
__device__ __forceinline__ int swz16(int row) {
  return ((row & 3) ^ ((row >> 2) & 3)) << 3;
}

// ============================================================================
// bf16-split MFMA GEMM (3 terms), 128x64 tile, BK=32. For N%64 shapes.
// ============================================================================
template <int BIASRELU>
__global__ __launch_bounds__(256) void gemm_bf16q_kernel(
    const uint32_t* __restrict__ A, const uint32_t* __restrict__ B,
    const float* __restrict__ bias, float* __restrict__ C, int M, int N, int K) {
  __shared__ short Ah[128 * 32], Al[128 * 32], Bh[64 * 32], Bl[64 * 32];
  const int t = threadIdx.x;
  const int nTN = N >> 6;
  const int mPer = (M >> 7) >> 3;
  const int bid = blockIdx.x;
  const int xcd = bid & 7, qq = bid >> 3;
  const int m0 = (xcd * mPer + qq / nTN) << 7;
  const int n0 = (qq % nTN) << 6;
  const int w = t >> 6, l = t & 63;
  const int wrow = (w >> 1) << 6, wcol = (w & 1) << 5;
  const int lr = l & 15, lg = l >> 4;
  const int ar = t >> 1, akh = (t & 1) << 4;
  const int br = t >> 2, bkh = (t & 3) << 3;
  const int asw = swz16(ar), bsw = swz16(br);
  const uint32_t* Ap = A + (size_t)(m0 + ar) * K + akh;
  const uint32_t* Bp = B + (size_t)(n0 + br) * K + bkh;
  f32x4 acc[4][2];
#pragma unroll
  for (int i = 0; i < 4; i++)
#pragma unroll
    for (int j = 0; j < 2; j++) acc[i][j] = (f32x4){0.f, 0.f, 0.f, 0.f};
  uint4 ra0 = *(const uint4*)(Ap + 0), ra1 = *(const uint4*)(Ap + 4);
  uint4 ra2 = *(const uint4*)(Ap + 8), ra3 = *(const uint4*)(Ap + 12);
  uint4 rb0 = *(const uint4*)(Bp + 0), rb1 = *(const uint4*)(Bp + 4);
  const int NS = K >> 5;
#define STORE_G(ARR_H, ARR_L, ROW, KB, SW, U)                                   \
    {                                                                           \
      uint32_t h0 = (U.x >> 16) | (U.y & 0xffff0000u);                          \
      uint32_t h1 = (U.z >> 16) | (U.w & 0xffff0000u);                          \
      uint32_t l0 = (U.x & 0xffffu) | (U.y << 16);                              \
      uint32_t l1 = (U.z & 0xffffu) | (U.w << 16);                              \
      int idx = (ROW) * 32 + ((KB) ^ (SW));                                     \
      *(uint2*)&ARR_H[idx] = make_uint2(h0, h1);                                \
      *(uint2*)&ARR_L[idx] = make_uint2(l0, l1);                                \
    }
  for (int s = 0; s < NS; s++) {
    __syncthreads();
    STORE_G(Ah, Al, ar, akh + 0, asw, ra0)
    STORE_G(Ah, Al, ar, akh + 4, asw, ra1)
    STORE_G(Ah, Al, ar, akh + 8, asw, ra2)
    STORE_G(Ah, Al, ar, akh + 12, asw, ra3)
    STORE_G(Bh, Bl, br, bkh + 0, bsw, rb0)
    STORE_G(Bh, Bl, br, bkh + 4, bsw, rb1)
    __syncthreads();
    if (s + 1 < NS) {
      int ko = (s + 1) << 5;
      ra0 = *(const uint4*)(Ap + ko); ra1 = *(const uint4*)(Ap + ko + 4);
      ra2 = *(const uint4*)(Ap + ko + 8); ra3 = *(const uint4*)(Ap + ko + 12);
      rb0 = *(const uint4*)(Bp + ko); rb1 = *(const uint4*)(Bp + ko + 4);
    }
    short8 ahf[4], alf[4], bhf[2], blf[2];
#pragma unroll
    for (int i = 0; i < 4; i++) {
      int R = wrow + i * 16 + lr;
      int kk = (lg << 3) ^ swz16(R);
      ahf[i] = *(const short8*)&Ah[R * 32 + kk];
      alf[i] = *(const short8*)&Al[R * 32 + kk];
    }
#pragma unroll
    for (int j = 0; j < 2; j++) {
      int Cc = wcol + j * 16 + lr;
      int kk = (lg << 3) ^ swz16(Cc);
      bhf[j] = *(const short8*)&Bh[Cc * 32 + kk];
      blf[j] = *(const short8*)&Bl[Cc * 32 + kk];
    }
#pragma unroll
    for (int i = 0; i < 4; i++)
#pragma unroll
      for (int j = 0; j < 2; j++) {
        acc[i][j] = __builtin_amdgcn_mfma_f32_16x16x32_bf16(ahf[i], bhf[j], acc[i][j], 0, 0, 0);
        acc[i][j] = __builtin_amdgcn_mfma_f32_16x16x32_bf16(ahf[i], blf[j], acc[i][j], 0, 0, 0);
        acc[i][j] = __builtin_amdgcn_mfma_f32_16x16x32_bf16(alf[i], bhf[j], acc[i][j], 0, 0, 0);
      }
  }
#pragma unroll
  for (int i = 0; i < 4; i++)
#pragma unroll
    for (int j = 0; j < 2; j++) {
      int n = n0 + wcol + j * 16 + lr;
#pragma unroll
      for (int r = 0; r < 4; r++) {
        int m = m0 + wrow + i * 16 + lg * 4 + r;
        float v = acc[i][j][r];
        if (BIASRELU) v = fmaxf(v + bias[n], 0.f);
        C[(size_t)m * N + n] = v;
      }
    }
}

// ============================================================================
// bf16-split MFMA GEMM (3 terms), BIG tile 128x128, BK=32, 4 waves x 64x64,
// SPLIT-K=2 (split s writes its own fp32 partial; merged by add_vec4).
// Grid = 2 * (M/128)*(N/128) -> 2 blocks/CU for barrier-overlap.
// ============================================================================
__global__ __launch_bounds__(256, 2) void gemm_bf16q_big_kernel(
    const uint32_t* __restrict__ A, const uint32_t* __restrict__ B,
    float* __restrict__ C0, float* __restrict__ C1, int M, int N, int K) {
  __shared__ short Ah[128 * 32], Al[128 * 32], Bh[128 * 32], Bl[128 * 32];
  const int t = threadIdx.x;
  const int nTN = N >> 7;
  const int tiles = (M >> 7) * nTN;
  const int mPer = (M >> 7) >> 3;
  const int split = blockIdx.x / tiles;
  const int bid = blockIdx.x % tiles;
  const int xcd = bid & 7, qq = bid >> 3;
  const int m0 = (xcd * mPer + qq / nTN) << 7;
  const int n0 = (qq % nTN) << 7;
  const int Kh = K >> 1;
  const int kbeg = split * Kh;
  float* Cout = split ? C1 : C0;
  const int w = t >> 6, l = t & 63;
  const int wrow = (w & 1) << 6, wcol = (w >> 1) << 6;
  const int lr = l & 15, lg = l >> 4;
  const int ar = t >> 1, akh = (t & 1) << 4;   // A & B staging: 2 thr/row
  const int asw = swz16(ar);
  const uint32_t* Ap = A + (size_t)(m0 + ar) * K + kbeg + akh;
  const uint32_t* Bp = B + (size_t)(n0 + ar) * K + kbeg + akh;
  f32x4 acc[4][4];
#pragma unroll
  for (int i = 0; i < 4; i++)
#pragma unroll
    for (int j = 0; j < 4; j++) acc[i][j] = (f32x4){0.f, 0.f, 0.f, 0.f};
  uint4 ra0 = *(const uint4*)(Ap + 0), ra1 = *(const uint4*)(Ap + 4);
  uint4 ra2 = *(const uint4*)(Ap + 8), ra3 = *(const uint4*)(Ap + 12);
  uint4 rb0 = *(const uint4*)(Bp + 0), rb1 = *(const uint4*)(Bp + 4);
  uint4 rb2 = *(const uint4*)(Bp + 8), rb3 = *(const uint4*)(Bp + 12);
  const int NS = Kh >> 5;
  for (int s = 0; s < NS; s++) {
    __syncthreads();
    STORE_G(Ah, Al, ar, akh + 0, asw, ra0)
    STORE_G(Ah, Al, ar, akh + 4, asw, ra1)
    STORE_G(Ah, Al, ar, akh + 8, asw, ra2)
    STORE_G(Ah, Al, ar, akh + 12, asw, ra3)
    STORE_G(Bh, Bl, ar, akh + 0, asw, rb0)
    STORE_G(Bh, Bl, ar, akh + 4, asw, rb1)
    STORE_G(Bh, Bl, ar, akh + 8, asw, rb2)
    STORE_G(Bh, Bl, ar, akh + 12, asw, rb3)
    __syncthreads();
    if (s + 1 < NS) {
      int ko = (s + 1) << 5;
      ra0 = *(const uint4*)(Ap + ko); ra1 = *(const uint4*)(Ap + ko + 4);
      ra2 = *(const uint4*)(Ap + ko + 8); ra3 = *(const uint4*)(Ap + ko + 12);
      rb0 = *(const uint4*)(Bp + ko); rb1 = *(const uint4*)(Bp + ko + 4);
      rb2 = *(const uint4*)(Bp + ko + 8); rb3 = *(const uint4*)(Bp + ko + 12);
    }
    short8 ahf[4], alf[4], bhf[4], blf[4];
#pragma unroll
    for (int i = 0; i < 4; i++) {
      int R = wrow + i * 16 + lr;
      int kk = (lg << 3) ^ swz16(R);
      ahf[i] = *(const short8*)&Ah[R * 32 + kk];
      alf[i] = *(const short8*)&Al[R * 32 + kk];
    }
#pragma unroll
    for (int j = 0; j < 4; j++) {
      int Cc = wcol + j * 16 + lr;
      int kk = (lg << 3) ^ swz16(Cc);
      bhf[j] = *(const short8*)&Bh[Cc * 32 + kk];
      blf[j] = *(const short8*)&Bl[Cc * 32 + kk];
    }
#pragma unroll
    for (int i = 0; i < 4; i++)
#pragma unroll
      for (int j = 0; j < 4; j++) {
        acc[i][j] = __builtin_amdgcn_mfma_f32_16x16x32_bf16(ahf[i], bhf[j], acc[i][j], 0, 0, 0);
        acc[i][j] = __builtin_amdgcn_mfma_f32_16x16x32_bf16(ahf[i], blf[j], acc[i][j], 0, 0, 0);
        acc[i][j] = __builtin_amdgcn_mfma_f32_16x16x32_bf16(alf[i], bhf[j], acc[i][j], 0, 0, 0);
      }
  }
#undef STORE_G
#pragma unroll
  for (int i = 0; i < 4; i++)
#pragma unroll
    for (int j = 0; j < 4; j++) {
      int n = n0 + wcol + j * 16 + lr;
#pragma unroll
      for (int r = 0; r < 4; r++) {
        int m = m0 + wrow + i * 16 + lg * 4 + r;
        Cout[(size_t)m * N + n] = acc[i][j][r];
      }
    }
}

// ============================================================================
// heads (double accumulation; sw_logits amplified 10x by TAU)
// ============================================================================
__global__ __launch_bounds__(256) void heads_kernel(
    const float* __restrict__ dpen, const float* __restrict__ dfc_w,
    const float* __restrict__ dfc_b, const float* __restrict__ sw_w,
    const float* __restrict__ sw_b, float* __restrict__ out_dom,
    float* __restrict__ swbuf) {
  int t = blockIdx.x * 256 + threadIdx.x;
  int b = t >> 2, j = t & 3;
  const float* row = dpen + (size_t)b * 384;
  const float* wr = (j < 2) ? (dfc_w + j * 384) : (sw_w + (j - 2) * 384);
  double s = 0.0;
  for (int k = 0; k < 384; k++) s += (double)row[k] * (double)wr[k];
  s += (double)((j < 2) ? dfc_b[j] : sw_b[j - 2]);
  if (j < 2) out_dom[b * 2 + j] = (float)s;
  else swbuf[b * 2 + (j - 2)] = (float)s;
}

// ============================================================================
// gumbel-softmax + categorical partition choice (threefry partitionable).
// ============================================================================
__global__ __launch_bounds__(256) void partition_kernel(
    const float* __restrict__ swbuf, float* __restrict__ out_pid,
    int* __restrict__ pidxI, float* __restrict__ ysum,
    uint32_t k1a, uint32_t k1b, uint32_t k2a, uint32_t k2b) {
  int b = blockIdx.x * 256 + threadIdx.x;
  if (b >= 4096) return;
  uint32_t j0 = (uint32_t)(2 * b), j1 = (uint32_t)(2 * b + 1);
  float f0 = u01_from_bits(tf_bits32(k1a, k1b, j0));
  float f1 = u01_from_bits(tf_bits32(k1a, k1b, j1));
  const float MINV = 1e-10f;
  float u0 = fmaxf(MINV, f0 * (1.0f - MINV) + MINV);
  float u1 = fmaxf(MINV, f1 * (1.0f - MINV) + MINV);
  double g0 = -log(-log((double)u0));
  double g1 = -log(-log((double)u1));
  double s0 = (double)swbuf[2 * b], s1 = (double)swbuf[2 * b + 1];
  double x0 = (s0 + g0) / 0.1;
  double x1 = (s1 + g1) / 0.1;
  double mx = fmax(x0, x1);
  double e0 = exp(x0 - mx), e1 = exp(x1 - mx);
  double es = e0 + e1;
  double y0 = e0 / es, y1 = e1 / es;
  float h0 = u01_from_bits(tf_bits32(k2a, k2b, j0));
  float h1 = u01_from_bits(tf_bits32(k2a, k2b, j1));
  const float TINY = 1.17549435e-38f;
  float v0 = fmaxf(TINY, h0 * (1.0f - TINY) + TINY);
  float v1 = fmaxf(TINY, h1 * (1.0f - TINY) + TINY);
  double gg0 = -log(-log((double)v0));
  double gg1 = -log(-log((double)v1));
  double l0 = log(y0 + 1e-20) + gg0;
  double l1 = log(y1 + 1e-20) + gg1;
  int p = (l1 > l0) ? 1 : 0;
  out_pid[b] = (float)p;
  pidxI[b] = p;
  ysum[b] = (float)(y0 + y1);
}

// ============================================================================
// final head
// ============================================================================
__global__ __launch_bounds__(256) void final_kernel(
    const float* __restrict__ h, const float* __restrict__ p2w,
    const float* __restrict__ p2b, const int* __restrict__ pidxI,
    const float* __restrict__ ysum, float* __restrict__ out0) {
  int t = blockIdx.x * 256 + threadIdx.x;
  if (t >= 40960) return;
  int b = t / 10, c = t % 10;
  int p = pidxI[b];
  const float* hr = h + (size_t)b * 384 + p * 192;
  const float* wr = p2w + ((size_t)p * 10 + c) * 192;
  float s = 0.f;
  for (int o = 0; o < 192; o++) s += hr[o] * wr[o];
  s += p2b[p * 10 + c];
  out0[t] = s * ysum[b];
}

// ============================================================================
// Launch orchestration. All big matmuls on MFMA (3-term bf16 split).
// Workspace audit (floats):
//   Acvt   0          .. 33554432   (act3 packed in place)
//   Bcvt   33554432   .. 41943040   (pre_w packed: 8,388,608 u32!)
//   discq  41943040   .. 42336256
//   p1q    42336256   .. 42729472
//   csplit 42729472   .. 46923776   (split-K partial; dead pool2q tail)
//   featp  50331648   .. 54525952
//   ... rest as before; total ~235 MB (proven).
// ============================================================================
extern "C" void kernel_launch(void* const* d_in, const int* in_sizes, int n_in,
                              void* d_out, int out_size, void* d_ws, size_t ws_size,
                              hipStream_t stream) {
  const float* input   = (const float*)d_in[0];
  const float* conv1_w = (const float*)d_in[1];
  const float* bn1_g   = (const float*)d_in[3];
  const float* bn1_b   = (const float*)d_in[4];
  const float* conv2_w = (const float*)d_in[5];
  const float* bn2_g   = (const float*)d_in[7];
  const float* bn2_b   = (const float*)d_in[8];
  const float* conv3_w = (const float*)d_in[9];
  const float* bn3_g   = (const float*)d_in[11];
  const float* bn3_b   = (const float*)d_in[12];
  const float* pre_w   = (const float*)d_in[13];
  const float* bnp_g   = (const float*)d_in[15];
  const float* bnp_b   = (const float*)d_in[16];
  const float* disc_w  = (const float*)d_in[17];
  const float* bnd_g   = (const float*)d_in[19];
  const float* bnd_b   = (const float*)d_in[20];
  const float* dfc_w   = (const float*)d_in[21];
  const float* dfc_b   = (const float*)d_in[22];
  const float* sw_w    = (const float*)d_in[23];
  const float* sw_b    = (const float*)d_in[24];
  const float* p1_w    = (const float*)d_in[25];
  const float* p1_b    = (const float*)d_in[26];
  const float* p2_w    = (const float*)d_in[27];
  const float* p2_b    = (const float*)d_in[28];

  float* W = (float*)d_ws;
  float* pool1  = W + 0;           // [4096][32][16][16], raw -> packed in place
  uint32_t* pool1q = (uint32_t*)pool1;
  float* pool2  = W + 33554432;    // [4096][64][8][8], raw -> packed in place
  uint32_t* pool2q = (uint32_t*)pool2;
  float* act3   = W + 0;           // [4096][128][8][8], alias pool1 (dead)
  uint32_t* Acvt = (uint32_t*)(W + 0);          // act3 packed in place
  uint32_t* Bcvt = (uint32_t*)(W + 33554432);   // pre_w packed: 8.4M u32 -> ends 41943040
  uint32_t* discq = (uint32_t*)(W + 41943040);  // disc_w packed
  uint32_t* p1q   = (uint32_t*)(W + 42336256);  // p1_w packed
  float* csplit = W + 42729472;    // [4096][1024] split-1 partial (truly free)
  float* featp  = W + 50331648;    // [4096][1024], raw -> packed in place
  uint32_t* featq = (uint32_t*)featp;
  short* wh3    = (short*)(W + 50331648);       // conv3 w hi (dead until pre-FC)
  short* wl3    = (short*)(W + 50368512);
  short* wh2    = (short*)(W + 50405376);       // conv2 w hi
  short* wl2    = (short*)(W + 50414592);
  float* dpen   = W + 54525952;
  float* hbuf   = W + 56098816;
  float* swbuf  = W + 57671680;
  float* ysum   = W + 57679872;
  int*   pidxI  = (int*)(W + 57683968);
  float* part   = W + 57688064;
  double* sums  = (double*)(W + 58736640);
  float* scale  = W + 58769408;
  float* shift  = W + 58770432;

  float* out_cls = (float*)d_out;
  float* out_dom = out_cls + 40960;
  float* out_pid = out_cls + 49152;

  uint32_t k1a, k1b, k2a, k2b;
  threefry2x32(0u, 42u, 0u, 0u, k1a, k1b);
  threefry2x32(0u, 42u, 0u, 1u, k2a, k2b);

  // --- conv1 fused + BN + pack ---
  conv1_fused_kernel<<<dim3(4096), dim3(256), 0, stream>>>(input, conv1_w, pool1, part);
  reduce_partials_kernel<<<dim3(64), dim3(256), 0, stream>>>(part, 4096, 64, sums);
  bn_finalize_kernel<<<dim3(1), dim3(64), 0, stream>>>(sums, 1, 0, bn1_g, bn1_b, scale, shift, 32, 1.0 / (4096.0 * 1024.0));
  bn_relu_pack_vec4_kernel<8, 31><<<dim3(32768), dim3(256), 0, stream>>>(pool1, scale, shift, 8388608);

  // --- conv2 via MFMA (fused pool) + BN + pack ---
  prep_w2_kernel<<<dim3(72), dim3(256), 0, stream>>>(conv2_w, wh2, wl2);
  conv2_mfma_kernel<<<dim3(4096), dim3(256), 0, stream>>>(pool1q, wh2, wl2, pool2, part);
  reduce_partials_kernel<<<dim3(128), dim3(256), 0, stream>>>(part, 4096, 128, sums);
  bn_finalize_kernel<<<dim3(1), dim3(64), 0, stream>>>(sums, 1, 0, bn2_g, bn2_b, scale, shift, 64, 1.0 / (4096.0 * 256.0));
  bn_relu_pack_vec4_kernel<6, 63><<<dim3(16384), dim3(256), 0, stream>>>(pool2, scale, shift, 4194304);

  // --- conv3 via MFMA + BN + pack ---
  prep_w3_kernel<<<dim3(288), dim3(256), 0, stream>>>(conv3_w, wh3, wl3);
  conv3_mfma_kernel<<<dim3(4096), dim3(256), 0, stream>>>(pool2q, wh3, wl3, act3, part);
  reduce_partials_kernel<<<dim3(256), dim3(256), 0, stream>>>(part, 4096, 256, sums);
  bn_finalize_kernel<<<dim3(1), dim3(128), 0, stream>>>(sums, 1, 0, bn3_g, bn3_b, scale, shift, 128, 1.0 / (4096.0 * 64.0));
  bn_relu_pack_vec4_kernel<6, 127><<<dim3(32768), dim3(256), 0, stream>>>(act3, scale, shift, 8388608);

  // --- pre FC 8192->1024 via MFMA (big tile, split-K=2) + merge + BN + pack ---
  cvt_bf16q_kernel<<<dim3(8192), dim3(256), 0, stream>>>(pre_w, Bcvt, 2097152);
  gemm_bf16q_big_kernel<<<dim3(512), dim3(256), 0, stream>>>(Acvt, Bcvt, featp, csplit, 4096, 1024, 8192);
  add_vec4_kernel<<<dim3(4096), dim3(256), 0, stream>>>(featp, csplit, 1048576);
  col_stats_kernel<<<dim3(16, 8), dim3(1024), 0, stream>>>(featp, 4096, 1024, 8, sums);
  bn_finalize_kernel<<<dim3(4), dim3(256), 0, stream>>>(sums, 8, 2048, bnp_g, bnp_b, scale, shift, 1024, 1.0 / 4096.0);
  bn_relu_pack_cols4_kernel<<<dim3(4096), dim3(256), 0, stream>>>(featp, scale, shift, 1048576, 256);

  // --- disc FC 1024->384 via MFMA + BN + ReLU (fp32 out for heads) ---
  cvt_bf16q_kernel<<<dim3(384), dim3(256), 0, stream>>>(disc_w, discq, 98304);
  cvt_bf16q_kernel<<<dim3(384), dim3(256), 0, stream>>>(p1_w, p1q, 98304);
  gemm_bf16q_kernel<0><<<dim3(192), dim3(256), 0, stream>>>(featq, discq, (const float*)nullptr, dpen, 4096, 384, 1024);
  col_stats_kernel<<<dim3(6, 8), dim3(1024), 0, stream>>>(dpen, 4096, 384, 8, sums);
  bn_finalize_kernel<<<dim3(2), dim3(256), 0, stream>>>(sums, 8, 768, bnd_g, bnd_b, scale, shift, 384, 1.0 / 4096.0);
  bn_relu_cols4_kernel<<<dim3(1536), dim3(256), 0, stream>>>(dpen, scale, shift, 393216, 96);

  // --- heads + partition sampling ---
  heads_kernel<<<dim3(64), dim3(256), 0, stream>>>(dpen, dfc_w, dfc_b, sw_w, sw_b, out_dom, swbuf);
  partition_kernel<<<dim3(16), dim3(256), 0, stream>>>(swbuf, out_pid, pidxI, ysum, k1a, k1b, k2a, k2b);

  // --- experts: p1 via MFMA (bias+relu epilogue), then gather + p2 ---
  gemm_bf16q_kernel<1><<<dim3(192), dim3(256), 0, stream>>>(featq, p1q, p1_b, hbuf, 4096, 384, 1024);
  final_kernel<<<dim3(160), dim3(256), 0, stream>>>(hbuf, p2_w, p2_b, pidxI, ysum, out_cls);
}

// Round 14
// 870.547 us; speedup vs baseline: 1.2040x; 1.0655x over previous
//
#include <hip/hip_runtime.h>
#include <cstdint>
#include <cstddef>

typedef __attribute__((ext_vector_type(8))) short short8;    // 8 bf16 (4 VGPR)
typedef __attribute__((ext_vector_type(4))) float f32x4;     // MFMA acc

// ============================================================================
// Threefry2x32 (matches jax._src.prng.threefry2x32).
// ============================================================================
__host__ __device__ inline void threefry2x32(uint32_t k0, uint32_t k1,
                                             uint32_t x0, uint32_t x1,
                                             uint32_t& o0, uint32_t& o1) {
  uint32_t ks2 = k0 ^ k1 ^ 0x1BD11BDAu;
  uint32_t v0 = x0 + k0, v1 = x1 + k1;
#define TF_R(r) { v0 += v1; v1 = (v1 << (r)) | (v1 >> (32 - (r))); v1 ^= v0; }
  TF_R(13) TF_R(15) TF_R(26) TF_R(6)
  v0 += k1; v1 += ks2 + 1u;
  TF_R(17) TF_R(29) TF_R(16) TF_R(24)
  v0 += ks2; v1 += k0 + 2u;
  TF_R(13) TF_R(15) TF_R(26) TF_R(6)
  v0 += k0; v1 += k1 + 3u;
  TF_R(17) TF_R(29) TF_R(16) TF_R(24)
  v0 += k1; v1 += ks2 + 4u;
  TF_R(13) TF_R(15) TF_R(26) TF_R(6)
  v0 += ks2; v1 += k0 + 5u;
#undef TF_R
  o0 = v0; o1 = v1;
}

__device__ __forceinline__ uint32_t tf_bits32(uint32_t k0, uint32_t k1, uint32_t j) {
  uint32_t o0, o1;
  threefry2x32(k0, k1, 0u, j, o0, o1);
  return o0 ^ o1;
}

__device__ __forceinline__ float u01_from_bits(uint32_t bits) {
  return __uint_as_float((bits >> 9) | 0x3f800000u) - 1.0f;  // [0,1)
}

__device__ __forceinline__ float waveSum(float v) {
#pragma unroll
  for (int off = 32; off > 0; off >>= 1) v += __shfl_down(v, off, 64);
  return v;
}

// ============================================================================
// conv1 fused: conv(3->32) + BN partials (unpooled) + RAW 2x2 maxpool store.
// ============================================================================
__global__ __launch_bounds__(256) void conv1_fused_kernel(
    const float* __restrict__ in, const float* __restrict__ w,
    float* __restrict__ outraw, float* __restrict__ partials) {
  __shared__ float ins[3 * 34 * 34];
  __shared__ float red[4][64];
  const int b = blockIdx.x, t = threadIdx.x;
  for (int i = t; i < 3 * 34 * 34; i += 256) {
    int ci = i / 1156, r = i % 1156, iy = r / 34, ix = r % 34;
    int y = iy - 1, x = ix - 1;
    float v = 0.f;
    if ((unsigned)y < 32u && (unsigned)x < 32u)
      v = in[(((size_t)b * 3 + ci) * 32 + y) * 32 + x];
    ins[i] = v;
  }
  __syncthreads();
  const int py = t >> 4, px = t & 15, wv = t >> 6, ln = t & 63;
  float win[3][4][4];
#pragma unroll
  for (int ci = 0; ci < 3; ci++)
#pragma unroll
    for (int r = 0; r < 4; r++)
#pragma unroll
      for (int c = 0; c < 4; c++)
        win[ci][r][c] = ins[ci * 1156 + (2 * py + r) * 34 + (2 * px + c)];
#pragma unroll 1
  for (int co = 0; co < 32; co++) {
    float acc00 = 0.f, acc01 = 0.f, acc10 = 0.f, acc11 = 0.f;
#pragma unroll
    for (int ci = 0; ci < 3; ci++) {
      const float* wp = w + (co * 3 + ci) * 9;  // wave-uniform -> s_load
#pragma unroll
      for (int dy = 0; dy < 3; dy++)
#pragma unroll
        for (int dx = 0; dx < 3; dx++) {
          float wvv = wp[dy * 3 + dx];
          acc00 += win[ci][dy][dx] * wvv;
          acc01 += win[ci][dy][dx + 1] * wvv;
          acc10 += win[ci][dy + 1][dx] * wvv;
          acc11 += win[ci][dy + 1][dx + 1] * wvv;
        }
    }
    float sm = acc00 + acc01 + acc10 + acc11;
    float sq = acc00 * acc00 + acc01 * acc01 + acc10 * acc10 + acc11 * acc11;
    float s = waveSum(sm), q = waveSum(sq);
    if (ln == 0) { red[wv][2 * co] = s; red[wv][2 * co + 1] = q; }
    float m = fmaxf(fmaxf(acc00, acc01), fmaxf(acc10, acc11));  // RAW max
    outraw[(((size_t)b * 32 + co) * 16 + py) * 16 + px] = m;
  }
  __syncthreads();
  for (int i = t; i < 64; i += 256)
    partials[(size_t)b * 64 + i] = red[0][i] + red[1][i] + red[2][i] + red[3][i];
}

// ============================================================================
// bf16-split helpers
// ============================================================================
__device__ __forceinline__ uint32_t pack_bf16q(float x) {
  uint32_t u = __float_as_uint(x);
  uint32_t hi = (u + 0x7fffu + ((u >> 16) & 1u)) & 0xffff0000u;
  float r = x - __uint_as_float(hi);
  uint32_t v = __float_as_uint(r);
  uint32_t lo = (v + 0x7fffu + ((v >> 16) & 1u)) >> 16;
  return hi | lo;
}

__device__ __forceinline__ uint4 pk4bn(float4 v, float sc, float sh) {
  uint4 o;
  o.x = pack_bf16q(fmaxf(v.x * sc + sh, 0.f));
  o.y = pack_bf16q(fmaxf(v.y * sc + sh, 0.f));
  o.z = pack_bf16q(fmaxf(v.z * sc + sh, 0.f));
  o.w = pack_bf16q(fmaxf(v.w * sc + sh, 0.f));
  return o;
}

__global__ void cvt_bf16q_kernel(const float* X, uint32_t* Y, int n4) {
  int i = blockIdx.x * blockDim.x + threadIdx.x;
  if (i >= n4) return;
  float4 x = ((const float4*)X)[i];
  uint4 o;
  o.x = pack_bf16q(x.x); o.y = pack_bf16q(x.y);
  o.z = pack_bf16q(x.z); o.w = pack_bf16q(x.w);
  ((uint4*)Y)[i] = o;
}

// conv2 weight prepack: w [64][32][9] fp32 -> wh/wl [9][64][32] bf16 planes.
__global__ void prep_w2_kernel(const float* __restrict__ w, short* __restrict__ wh,
                               short* __restrict__ wl) {
  int idx = blockIdx.x * 256 + threadIdx.x;
  if (idx >= 64 * 32 * 9) return;
  int tp = idx % 9, rem = idx / 9;
  int ci = rem % 32, co = rem / 32;
  uint32_t pq = pack_bf16q(w[idx]);
  size_t o = ((size_t)tp * 64 + co) * 32 + ci;
  wh[o] = (short)(pq >> 16);
  wl[o] = (short)(pq & 0xffffu);
}

// conv3 weight prepack: w [128][64][9] fp32 -> wh/wl [9][128][64] bf16 planes.
__global__ void prep_w3_kernel(const float* __restrict__ w, short* __restrict__ wh,
                               short* __restrict__ wl) {
  int idx = blockIdx.x * 256 + threadIdx.x;
  if (idx >= 128 * 64 * 9) return;
  int tp = idx % 9, rem = idx / 9;
  int ci = rem % 64, co = rem / 64;
  uint32_t pq = pack_bf16q(w[idx]);
  size_t o = ((size_t)tp * 128 + co) * 64 + ci;
  wh[o] = (short)(pq >> 16);
  wl[o] = (short)(pq & 0xffffu);
}

// ============================================================================
// conv2 via MFMA implicit GEMM (bf16-split, 3 terms).
// Input: RAW pooled conv1 [4096][32][16][16] fp32; BN1+ReLU+pack applied at
// LDS staging time (saves a full HBM round trip).
// ============================================================================
__global__ __launch_bounds__(256) void conv2_mfma_kernel(
    const float* __restrict__ in, const float* __restrict__ scale1,
    const float* __restrict__ shift1, const short* __restrict__ wh,
    const short* __restrict__ wl, float* __restrict__ outpool,
    float* __restrict__ partials) {
  __shared__ short Xh[324 * 32], Xl[324 * 32];
  __shared__ float red[4][128];
  const int b = blockIdx.x, t = threadIdx.x;
  for (int i = t; i < 324 * 16; i += 256) {
    int row = i >> 4;
    int py = row / 18, pxx = row % 18;
    if (py == 0 || py == 17 || pxx == 0 || pxx == 17) {
      ((uint32_t*)Xh)[i] = 0u;
      ((uint32_t*)Xl)[i] = 0u;
    }
  }
  for (int i = t; i < 4096; i += 256) {
    int p = i >> 8, px = i & 255;
    int y = px >> 4, x = px & 15;
    float va = in[((size_t)b * 32 + 2 * p) * 256 + px];
    float vb = in[((size_t)b * 32 + 2 * p + 1) * 256 + px];
    va = fmaxf(va * scale1[2 * p] + shift1[2 * p], 0.f);
    vb = fmaxf(vb * scale1[2 * p + 1] + shift1[2 * p + 1], 0.f);
    uint32_t ua = pack_bf16q(va), ub = pack_bf16q(vb);
    uint32_t h = (ua >> 16) | (ub & 0xffff0000u);
    uint32_t l = (ua & 0xffffu) | (ub << 16);
    int row = (y + 1) * 18 + (x + 1);
    int ci2 = (2 * p) ^ ((row & 3) << 3);  // swizzled, stays even
    ((uint32_t*)Xh)[(row * 32 + ci2) >> 1] = h;
    ((uint32_t*)Xl)[(row * 32 + ci2) >> 1] = l;
  }
  __syncthreads();
  const int w = t >> 6, l = t & 63;
  const int lr = l & 15, lg = l >> 4;
  f32x4 acc[4][4];  // [co block][px block]
#pragma unroll
  for (int i = 0; i < 4; i++)
#pragma unroll
    for (int j = 0; j < 4; j++) acc[i][j] = (f32x4){0.f, 0.f, 0.f, 0.f};
#pragma unroll 1
  for (int tap = 0; tap < 9; tap++) {
    const int dy = tap / 3, dx = tap % 3;
    short8 awh[4], awl[4];
#pragma unroll
    for (int i = 0; i < 4; i++) {
      size_t off = ((size_t)tap * 64 + i * 16 + lr) * 32 + lg * 8;
      awh[i] = *(const short8*)(wh + off);
      awl[i] = *(const short8*)(wl + off);
    }
    short8 bxh[4], bxl[4];
#pragma unroll
    for (int j = 0; j < 4; j++) {
      int y = w * 4 + j, x = lr;
      int row = (y + dy) * 18 + (x + dx);
      int ci = (lg * 8) ^ ((row & 3) << 3);
      bxh[j] = *(const short8*)&Xh[row * 32 + ci];
      bxl[j] = *(const short8*)&Xl[row * 32 + ci];
    }
#pragma unroll
    for (int i = 0; i < 4; i++)
#pragma unroll
      for (int j = 0; j < 4; j++) {
        acc[i][j] = __builtin_amdgcn_mfma_f32_16x16x32_bf16(awh[i], bxh[j], acc[i][j], 0, 0, 0);
        acc[i][j] = __builtin_amdgcn_mfma_f32_16x16x32_bf16(awh[i], bxl[j], acc[i][j], 0, 0, 0);
        acc[i][j] = __builtin_amdgcn_mfma_f32_16x16x32_bf16(awl[i], bxh[j], acc[i][j], 0, 0, 0);
      }
  }
#pragma unroll
  for (int i = 0; i < 4; i++)
#pragma unroll
    for (int r = 0; r < 4; r++) {
      int co = i * 16 + lg * 4 + r;
      float v0 = acc[i][0][r], v1 = acc[i][1][r], v2 = acc[i][2][r], v3 = acc[i][3][r];
      float s = v0 + v1 + v2 + v3;
      float q = v0 * v0 + v1 * v1 + v2 * v2 + v3 * v3;
#pragma unroll
      for (int off = 1; off <= 8; off <<= 1) {
        s += __shfl_xor(s, off, 64);
        q += __shfl_xor(q, off, 64);
      }
      if (lr == 0) { red[w][2 * co] = s; red[w][2 * co + 1] = q; }
      float h0 = fmaxf(v0, __shfl_xor(v0, 1, 64));
      float h1 = fmaxf(v1, __shfl_xor(v1, 1, 64));
      float h2 = fmaxf(v2, __shfl_xor(v2, 1, 64));
      float h3 = fmaxf(v3, __shfl_xor(v3, 1, 64));
      float pm0 = fmaxf(h0, h1);
      float pm1 = fmaxf(h2, h3);
      if ((lr & 1) == 0) {
        size_t base = ((size_t)b * 64 + co) * 64 + (w * 2) * 8 + (lr >> 1);
        outpool[base] = pm0;
        outpool[base + 8] = pm1;
      }
    }
  __syncthreads();
  for (int i = t; i < 128; i += 256)
    partials[(size_t)b * 128 + i] = red[0][i] + red[1][i] + red[2][i] + red[3][i];
}

// ============================================================================
// conv3 via MFMA implicit GEMM (bf16-split, 3 terms). BN2 applied at staging.
// ============================================================================
__global__ __launch_bounds__(256) void conv3_mfma_kernel(
    const float* __restrict__ in, const float* __restrict__ scale2,
    const float* __restrict__ shift2, const short* __restrict__ wh,
    const short* __restrict__ wl, float* __restrict__ outraw,
    float* __restrict__ partials) {
  __shared__ short Xh[100 * 64], Xl[100 * 64];
  __shared__ float red[256];
  const int b = blockIdx.x, t = threadIdx.x;
  for (int i = t; i < 100 * 32; i += 256) {
    int row = i >> 5;
    int py = row / 10, pxx = row % 10;
    if (py == 0 || py == 9 || pxx == 0 || pxx == 9) {
      ((uint32_t*)Xh)[i] = 0u;
      ((uint32_t*)Xl)[i] = 0u;
    }
  }
  for (int i = t; i < 2048; i += 256) {
    int p = i >> 6, px = i & 63;
    int y = px >> 3, x = px & 7;
    float va = in[((size_t)b * 64 + 2 * p) * 64 + px];
    float vb = in[((size_t)b * 64 + 2 * p + 1) * 64 + px];
    va = fmaxf(va * scale2[2 * p] + shift2[2 * p], 0.f);
    vb = fmaxf(vb * scale2[2 * p + 1] + shift2[2 * p + 1], 0.f);
    uint32_t ua = pack_bf16q(va), ub = pack_bf16q(vb);
    uint32_t h = (ua >> 16) | (ub & 0xffff0000u);
    uint32_t l = (ua & 0xffffu) | (ub << 16);
    int row = (y + 1) * 10 + (x + 1);
    int ci2 = (2 * p) ^ ((row & 7) << 3);
    ((uint32_t*)Xh)[(row * 64 + ci2) >> 1] = h;
    ((uint32_t*)Xl)[(row * 64 + ci2) >> 1] = l;
  }
  __syncthreads();
  const int w = t >> 6, l = t & 63;
  const int lr = l & 15, lg = l >> 4;
  const int co_base = w * 32;
  f32x4 acc[2][4];
#pragma unroll
  for (int i = 0; i < 2; i++)
#pragma unroll
    for (int j = 0; j < 4; j++) acc[i][j] = (f32x4){0.f, 0.f, 0.f, 0.f};
#pragma unroll 1
  for (int tap = 0; tap < 9; tap++) {
    const int dy = tap / 3, dx = tap % 3;
#pragma unroll
    for (int sl = 0; sl < 2; sl++) {
      short8 awh[2], awl[2];
#pragma unroll
      for (int i = 0; i < 2; i++) {
        size_t off = ((size_t)tap * 128 + co_base + i * 16 + lr) * 64 + sl * 32 + lg * 8;
        awh[i] = *(const short8*)(wh + off);
        awl[i] = *(const short8*)(wl + off);
      }
      short8 bxh[4], bxl[4];
#pragma unroll
      for (int j = 0; j < 4; j++) {
        int px = j * 16 + lr;
        int row = ((px >> 3) + dy) * 10 + (px & 7) + dx;
        int ci = (sl * 32 + lg * 8) ^ ((row & 7) << 3);
        bxh[j] = *(const short8*)&Xh[row * 64 + ci];
        bxl[j] = *(const short8*)&Xl[row * 64 + ci];
      }
#pragma unroll
      for (int i = 0; i < 2; i++)
#pragma unroll
        for (int j = 0; j < 4; j++) {
          acc[i][j] = __builtin_amdgcn_mfma_f32_16x16x32_bf16(awh[i], bxh[j], acc[i][j], 0, 0, 0);
          acc[i][j] = __builtin_amdgcn_mfma_f32_16x16x32_bf16(awh[i], bxl[j], acc[i][j], 0, 0, 0);
          acc[i][j] = __builtin_amdgcn_mfma_f32_16x16x32_bf16(awl[i], bxh[j], acc[i][j], 0, 0, 0);
        }
    }
  }
#pragma unroll
  for (int i = 0; i < 2; i++)
#pragma unroll
    for (int r = 0; r < 4; r++) {
      int co = co_base + i * 16 + lg * 4 + r;
      float s = 0.f, q = 0.f;
#pragma unroll
      for (int j = 0; j < 4; j++) {
        float v = acc[i][j][r];
        outraw[((size_t)b * 128 + co) * 64 + j * 16 + lr] = v;
        s += v; q += v * v;
      }
#pragma unroll
      for (int off = 1; off <= 8; off <<= 1) {
        s += __shfl_xor(s, off, 64);
        q += __shfl_xor(q, off, 64);
      }
      if (lr == 0) { red[2 * co] = s; red[2 * co + 1] = q; }
    }
  __syncthreads();
  for (int i = t; i < 256; i += 256) partials[(size_t)b * 256 + i] = red[i];
}

// ============================================================================
// BN helpers
// ============================================================================
__global__ __launch_bounds__(256) void reduce_partials_kernel(
    const float* __restrict__ partials, int nblk, int Q, double* __restrict__ sums) {
  int q = blockIdx.x;
  double acc = 0.0;
  for (int i = threadIdx.x; i < nblk; i += 256) acc += (double)partials[(size_t)i * Q + q];
  __shared__ double red[256];
  red[threadIdx.x] = acc;
  __syncthreads();
  for (int s = 128; s > 0; s >>= 1) {
    if (threadIdx.x < s) red[threadIdx.x] += red[threadIdx.x + s];
    __syncthreads();
  }
  if (threadIdx.x == 0) sums[q] = red[0];
}

// col stats over row-chunk, optional elementwise add of Y (split-K merge).
__global__ __launch_bounds__(1024) void col_stats_kernel(
    const float* __restrict__ X, const float* __restrict__ Y,
    int R, int C, int nch, double* __restrict__ sums) {
  int c0 = blockIdx.x * 64, chunk = blockIdx.y;
  int cl = threadIdx.x & 63, rg = threadIdx.x >> 6;
  int rows = R / nch, rbeg = chunk * rows, rend = rbeg + rows;
  double s = 0.0, sq = 0.0;
  for (int r = rbeg + rg; r < rend; r += 16) {
    size_t idx = (size_t)r * C + c0 + cl;
    float v = X[idx];
    if (Y) v += Y[idx];
    s += v; sq += (double)v * (double)v;
  }
  __shared__ double red[16][64][2];
  red[rg][cl][0] = s; red[rg][cl][1] = sq;
  __syncthreads();
  if (rg == 0) {
    for (int i = 1; i < 16; i++) { s += red[i][cl][0]; sq += red[i][cl][1]; }
    sums[(size_t)chunk * 2 * C + 2 * (c0 + cl)] = s;
    sums[(size_t)chunk * 2 * C + 2 * (c0 + cl) + 1] = sq;
  }
}

__global__ void bn_finalize_kernel(const double* __restrict__ sums, int nch, int cst2,
                                   const float* __restrict__ g, const float* __restrict__ b,
                                   float* __restrict__ scale, float* __restrict__ shift,
                                   int C, double invN) {
  int c = blockIdx.x * blockDim.x + threadIdx.x;
  if (c >= C) return;
  double s = 0.0, sq = 0.0;
  for (int ch = 0; ch < nch; ch++) {
    s += sums[(size_t)ch * cst2 + 2 * c];
    sq += sums[(size_t)ch * cst2 + 2 * c + 1];
  }
  double m = s * invN;
  double v = sq * invN - m * m;
  double sc = (double)g[c] / sqrt(v + 1e-5);
  scale[c] = (float)sc;
  shift[c] = (float)((double)b[c] - m * sc);
}

// BN+ReLU+pack for [R][C] row-major, in place, optional add of Y. C4 = C/4.
__global__ void bn_relu_pack_cols4_kernel(float* __restrict__ X,
                                          const float* __restrict__ Y,
                                          const float* __restrict__ scale,
                                          const float* __restrict__ shift,
                                          int n4, int C4) {
  int i = blockIdx.x * blockDim.x + threadIdx.x;
  if (i >= n4) return;
  int c4 = i % C4;
  float4 v = ((float4*)X)[i];
  if (Y) {
    float4 y = ((const float4*)Y)[i];
    v.x += y.x; v.y += y.y; v.z += y.z; v.w += y.w;
  }
  float4 sc = ((const float4*)scale)[c4];
  float4 sh = ((const float4*)shift)[c4];
  uint4 o;
  o.x = pack_bf16q(fmaxf(v.x * sc.x + sh.x, 0.f));
  o.y = pack_bf16q(fmaxf(v.y * sc.y + sh.y, 0.f));
  o.z = pack_bf16q(fmaxf(v.z * sc.z + sh.z, 0.f));
  o.w = pack_bf16q(fmaxf(v.w * sc.w + sh.w, 0.f));
  ((uint4*)X)[i] = o;
}

// BN+ReLU (fp32 out) for [R][C] row-major, in place. C4 = C/4.
__global__ void bn_relu_cols4_kernel(float* __restrict__ X, const float* __restrict__ scale,
                                     const float* __restrict__ shift, int n4, int C4) {
  int i = blockIdx.x * blockDim.x + threadIdx.x;
  if (i >= n4) return;
  int c4 = i % C4;
  float4 v = ((float4*)X)[i];
  float4 sc = ((const float4*)scale)[c4];
  float4 sh = ((const float4*)shift)[c4];
  v.x = fmaxf(v.x * sc.x + sh.x, 0.f);
  v.y = fmaxf(v.y * sc.y + sh.y, 0.f);
  v.z = fmaxf(v.z * sc.z + sh.z, 0.f);
  v.w = fmaxf(v.w * sc.w + sh.w, 0.f);
  ((float4*)X)[i] = v;
}

// full-rank row swizzle: distinct k-block for every row in a 16-row group
__device__ __forceinline__ int swz16(int row) {
  return ((row & 3) ^ ((row >> 2) & 3)) << 3;
}

// ============================================================================
// bf16-split MFMA GEMM (3 terms), 128x64 tile, BK=32. For N%64 shapes.
// ============================================================================
template <int BIASRELU>
__global__ __launch_bounds__(256) void gemm_bf16q_kernel(
    const uint32_t* __restrict__ A, const uint32_t* __restrict__ B,
    const float* __restrict__ bias, float* __restrict__ C, int M, int N, int K) {
  __shared__ short Ah[128 * 32], Al[128 * 32], Bh[64 * 32], Bl[64 * 32];
  const int t = threadIdx.x;
  const int nTN = N >> 6;
  const int mPer = (M >> 7) >> 3;
  const int bid = blockIdx.x;
  const int xcd = bid & 7, qq = bid >> 3;
  const int m0 = (xcd * mPer + qq / nTN) << 7;
  const int n0 = (qq % nTN) << 6;
  const int w = t >> 6, l = t & 63;
  const int wrow = (w >> 1) << 6, wcol = (w & 1) << 5;
  const int lr = l & 15, lg = l >> 4;
  const int ar = t >> 1, akh = (t & 1) << 4;
  const int br = t >> 2, bkh = (t & 3) << 3;
  const int asw = swz16(ar), bsw = swz16(br);
  const uint32_t* Ap = A + (size_t)(m0 + ar) * K + akh;
  const uint32_t* Bp = B + (size_t)(n0 + br) * K + bkh;
  f32x4 acc[4][2];
#pragma unroll
  for (int i = 0; i < 4; i++)
#pragma unroll
    for (int j = 0; j < 2; j++) acc[i][j] = (f32x4){0.f, 0.f, 0.f, 0.f};
  uint4 ra0 = *(const uint4*)(Ap + 0), ra1 = *(const uint4*)(Ap + 4);
  uint4 ra2 = *(const uint4*)(Ap + 8), ra3 = *(const uint4*)(Ap + 12);
  uint4 rb0 = *(const uint4*)(Bp + 0), rb1 = *(const uint4*)(Bp + 4);
  const int NS = K >> 5;
#define STORE_G(ARR_H, ARR_L, ROW, KB, SW, U)                                   \
    {                                                                           \
      uint32_t h0 = (U.x >> 16) | (U.y & 0xffff0000u);                          \
      uint32_t h1 = (U.z >> 16) | (U.w & 0xffff0000u);                          \
      uint32_t l0 = (U.x & 0xffffu) | (U.y << 16);                              \
      uint32_t l1 = (U.z & 0xffffu) | (U.w << 16);                              \
      int idx = (ROW) * 32 + ((KB) ^ (SW));                                     \
      *(uint2*)&ARR_H[idx] = make_uint2(h0, h1);                                \
      *(uint2*)&ARR_L[idx] = make_uint2(l0, l1);                                \
    }
  for (int s = 0; s < NS; s++) {
    __syncthreads();
    STORE_G(Ah, Al, ar, akh + 0, asw, ra0)
    STORE_G(Ah, Al, ar, akh + 4, asw, ra1)
    STORE_G(Ah, Al, ar, akh + 8, asw, ra2)
    STORE_G(Ah, Al, ar, akh + 12, asw, ra3)
    STORE_G(Bh, Bl, br, bkh + 0, bsw, rb0)
    STORE_G(Bh, Bl, br, bkh + 4, bsw, rb1)
    __syncthreads();
    if (s + 1 < NS) {
      int ko = (s + 1) << 5;
      ra0 = *(const uint4*)(Ap + ko); ra1 = *(const uint4*)(Ap + ko + 4);
      ra2 = *(const uint4*)(Ap + ko + 8); ra3 = *(const uint4*)(Ap + ko + 12);
      rb0 = *(const uint4*)(Bp + ko); rb1 = *(const uint4*)(Bp + ko + 4);
    }
    short8 ahf[4], alf[4], bhf[2], blf[2];
#pragma unroll
    for (int i = 0; i < 4; i++) {
      int R = wrow + i * 16 + lr;
      int kk = (lg << 3) ^ swz16(R);
      ahf[i] = *(const short8*)&Ah[R * 32 + kk];
      alf[i] = *(const short8*)&Al[R * 32 + kk];
    }
#pragma unroll
    for (int j = 0; j < 2; j++) {
      int Cc = wcol + j * 16 + lr;
      int kk = (lg << 3) ^ swz16(Cc);
      bhf[j] = *(const short8*)&Bh[Cc * 32 + kk];
      blf[j] = *(const short8*)&Bl[Cc * 32 + kk];
    }
#pragma unroll
    for (int i = 0; i < 4; i++)
#pragma unroll
      for (int j = 0; j < 2; j++) {
        acc[i][j] = __builtin_amdgcn_mfma_f32_16x16x32_bf16(ahf[i], bhf[j], acc[i][j], 0, 0, 0);
        acc[i][j] = __builtin_amdgcn_mfma_f32_16x16x32_bf16(ahf[i], blf[j], acc[i][j], 0, 0, 0);
        acc[i][j] = __builtin_amdgcn_mfma_f32_16x16x32_bf16(alf[i], bhf[j], acc[i][j], 0, 0, 0);
      }
  }
#pragma unroll
  for (int i = 0; i < 4; i++)
#pragma unroll
    for (int j = 0; j < 2; j++) {
      int n = n0 + wcol + j * 16 + lr;
#pragma unroll
      for (int r = 0; r < 4; r++) {
        int m = m0 + wrow + i * 16 + lg * 4 + r;
        float v = acc[i][j][r];
        if (BIASRELU) v = fmaxf(v + bias[n], 0.f);
        C[(size_t)m * N + n] = v;
      }
    }
}

// ============================================================================
// bf16-split MFMA GEMM (3 terms), BIG tile 128x128, BK=32, SPLIT-K=2.
// A is RAW fp32 act3 with BN3+ReLU applied at staging (16-float runs never
// cross a 64-wide channel). Grid = 2*(M/128)*(N/128) -> 2 blocks/CU.
// ============================================================================
__global__ __launch_bounds__(256, 2) void gemm_bf16q_big_kernel(
    const float* __restrict__ A, const uint32_t* __restrict__ B,
    const float* __restrict__ scale, const float* __restrict__ shift,
    float* __restrict__ C0, float* __restrict__ C1, int M, int N, int K) {
  __shared__ short Ah[128 * 32], Al[128 * 32], Bh[128 * 32], Bl[128 * 32];
  const int t = threadIdx.x;
  const int nTN = N >> 7;
  const int tiles = (M >> 7) * nTN;
  const int mPer = (M >> 7) >> 3;
  const int split = blockIdx.x / tiles;
  const int bid = blockIdx.x % tiles;
  const int xcd = bid & 7, qq = bid >> 3;
  const int m0 = (xcd * mPer + qq / nTN) << 7;
  const int n0 = (qq % nTN) << 7;
  const int Kh = K >> 1;
  const int kbeg = split * Kh;
  float* Cout = split ? C1 : C0;
  const int w = t >> 6, l = t & 63;
  const int wrow = (w & 1) << 6, wcol = (w >> 1) << 6;
  const int lr = l & 15, lg = l >> 4;
  const int ar = t >> 1, akh = (t & 1) << 4;   // A & B staging: 2 thr/row
  const int asw = swz16(ar);
  const float* Ap = A + (size_t)(m0 + ar) * K + kbeg + akh;
  const uint32_t* Bp = B + (size_t)(n0 + ar) * K + kbeg + akh;
  f32x4 acc[4][4];
#pragma unroll
  for (int i = 0; i < 4; i++)
#pragma unroll
    for (int j = 0; j < 4; j++) acc[i][j] = (f32x4){0.f, 0.f, 0.f, 0.f};
  float4 fa0 = *(const float4*)(Ap + 0), fa1 = *(const float4*)(Ap + 4);
  float4 fa2 = *(const float4*)(Ap + 8), fa3 = *(const float4*)(Ap + 12);
  uint4 rb0 = *(const uint4*)(Bp + 0), rb1 = *(const uint4*)(Bp + 4);
  uint4 rb2 = *(const uint4*)(Bp + 8), rb3 = *(const uint4*)(Bp + 12);
  const int NS = Kh >> 5;
  for (int s = 0; s < NS; s++) {
    // BN+ReLU+pack the A slab for this iteration (run stays in one channel)
    int ch = (kbeg + akh + (s << 5)) >> 6;
    float sc = scale[ch], sh = shift[ch];
    uint4 ua0 = pk4bn(fa0, sc, sh), ua1 = pk4bn(fa1, sc, sh);
    uint4 ua2 = pk4bn(fa2, sc, sh), ua3 = pk4bn(fa3, sc, sh);
    __syncthreads();
    STORE_G(Ah, Al, ar, akh + 0, asw, ua0)
    STORE_G(Ah, Al, ar, akh + 4, asw, ua1)
    STORE_G(Ah, Al, ar, akh + 8, asw, ua2)
    STORE_G(Ah, Al, ar, akh + 12, asw, ua3)
    STORE_G(Bh, Bl, ar, akh + 0, asw, rb0)
    STORE_G(Bh, Bl, ar, akh + 4, asw, rb1)
    STORE_G(Bh, Bl, ar, akh + 8, asw, rb2)
    STORE_G(Bh, Bl, ar, akh + 12, asw, rb3)
    __syncthreads();
    if (s + 1 < NS) {
      int ko = (s + 1) << 5;
      fa0 = *(const float4*)(Ap + ko); fa1 = *(const float4*)(Ap + ko + 4);
      fa2 = *(const float4*)(Ap + ko + 8); fa3 = *(const float4*)(Ap + ko + 12);
      rb0 = *(const uint4*)(Bp + ko); rb1 = *(const uint4*)(Bp + ko + 4);
      rb2 = *(const uint4*)(Bp + ko + 8); rb3 = *(const uint4*)(Bp + ko + 12);
    }
    short8 ahf[4], alf[4], bhf[4], blf[4];
#pragma unroll
    for (int i = 0; i < 4; i++) {
      int R = wrow + i * 16 + lr;
      int kk = (lg << 3) ^ swz16(R);
      ahf[i] = *(const short8*)&Ah[R * 32 + kk];
      alf[i] = *(const short8*)&Al[R * 32 + kk];
    }
#pragma unroll
    for (int j = 0; j < 4; j++) {
      int Cc = wcol + j * 16 + lr;
      int kk = (lg << 3) ^ swz16(Cc);
      bhf[j] = *(const short8*)&Bh[Cc * 32 + kk];
      blf[j] = *(const short8*)&Bl[Cc * 32 + kk];
    }
#pragma unroll
    for (int i = 0; i < 4; i++)
#pragma unroll
      for (int j = 0; j < 4; j++) {
        acc[i][j] = __builtin_amdgcn_mfma_f32_16x16x32_bf16(ahf[i], bhf[j], acc[i][j], 0, 0, 0);
        acc[i][j] = __builtin_amdgcn_mfma_f32_16x16x32_bf16(ahf[i], blf[j], acc[i][j], 0, 0, 0);
        acc[i][j] = __builtin_amdgcn_mfma_f32_16x16x32_bf16(alf[i], bhf[j], acc[i][j], 0, 0, 0);
      }
  }
#undef STORE_G
#pragma unroll
  for (int i = 0; i < 4; i++)
#pragma unroll
    for (int j = 0; j < 4; j++) {
      int n = n0 + wcol + j * 16 + lr;
#pragma unroll
      for (int r = 0; r < 4; r++) {
        int m = m0 + wrow + i * 16 + lg * 4 + r;
        Cout[(size_t)m * N + n] = acc[i][j][r];
      }
    }
}

// ============================================================================
// heads, wave-parallel: one wave per b; 4 j's per wave; double accumulation.
// grid 1024 blocks x 256 threads (4 waves).
// ============================================================================
__global__ __launch_bounds__(256) void heads_kernel(
    const float* __restrict__ dpen, const float* __restrict__ dfc_w,
    const float* __restrict__ dfc_b, const float* __restrict__ sw_w,
    const float* __restrict__ sw_b, float* __restrict__ out_dom,
    float* __restrict__ swbuf) {
  int wv = threadIdx.x >> 6, ln = threadIdx.x & 63;
  int b = blockIdx.x * 4 + wv;
  const float* row = dpen + (size_t)b * 384;
  double a0 = 0.0, a1 = 0.0, a2 = 0.0, a3 = 0.0;
  for (int k = ln; k < 384; k += 64) {
    double rv = (double)row[k];
    a0 += rv * (double)dfc_w[k];
    a1 += rv * (double)dfc_w[384 + k];
    a2 += rv * (double)sw_w[k];
    a3 += rv * (double)sw_w[384 + k];
  }
#pragma unroll
  for (int off = 32; off > 0; off >>= 1) {
    a0 += __shfl_down(a0, off, 64);
    a1 += __shfl_down(a1, off, 64);
    a2 += __shfl_down(a2, off, 64);
    a3 += __shfl_down(a3, off, 64);
  }
  if (ln == 0) {
    out_dom[b * 2 + 0] = (float)(a0 + (double)dfc_b[0]);
    out_dom[b * 2 + 1] = (float)(a1 + (double)dfc_b[1]);
    swbuf[b * 2 + 0] = (float)(a2 + (double)sw_b[0]);
    swbuf[b * 2 + 1] = (float)(a3 + (double)sw_b[1]);
  }
}

// ============================================================================
// gumbel-softmax + categorical partition choice (threefry partitionable).
// ============================================================================
__global__ __launch_bounds__(256) void partition_kernel(
    const float* __restrict__ swbuf, float* __restrict__ out_pid,
    int* __restrict__ pidxI, float* __restrict__ ysum,
    uint32_t k1a, uint32_t k1b, uint32_t k2a, uint32_t k2b) {
  int b = blockIdx.x * 256 + threadIdx.x;
  if (b >= 4096) return;
  uint32_t j0 = (uint32_t)(2 * b), j1 = (uint32_t)(2 * b + 1);
  float f0 = u01_from_bits(tf_bits32(k1a, k1b, j0));
  float f1 = u01_from_bits(tf_bits32(k1a, k1b, j1));
  const float MINV = 1e-10f;
  float u0 = fmaxf(MINV, f0 * (1.0f - MINV) + MINV);
  float u1 = fmaxf(MINV, f1 * (1.0f - MINV) + MINV);
  double g0 = -log(-log((double)u0));
  double g1 = -log(-log((double)u1));
  double s0 = (double)swbuf[2 * b], s1 = (double)swbuf[2 * b + 1];
  double x0 = (s0 + g0) / 0.1;
  double x1 = (s1 + g1) / 0.1;
  double mx = fmax(x0, x1);
  double e0 = exp(x0 - mx), e1 = exp(x1 - mx);
  double es = e0 + e1;
  double y0 = e0 / es, y1 = e1 / es;
  float h0 = u01_from_bits(tf_bits32(k2a, k2b, j0));
  float h1 = u01_from_bits(tf_bits32(k2a, k2b, j1));
  const float TINY = 1.17549435e-38f;
  float v0 = fmaxf(TINY, h0 * (1.0f - TINY) + TINY);
  float v1 = fmaxf(TINY, h1 * (1.0f - TINY) + TINY);
  double gg0 = -log(-log((double)v0));
  double gg1 = -log(-log((double)v1));
  double l0 = log(y0 + 1e-20) + gg0;
  double l1 = log(y1 + 1e-20) + gg1;
  int p = (l1 > l0) ? 1 : 0;
  out_pid[b] = (float)p;
  pidxI[b] = p;
  ysum[b] = (float)(y0 + y1);
}

// ============================================================================
// final head
// ============================================================================
__global__ __launch_bounds__(256) void final_kernel(
    const float* __restrict__ h, const float* __restrict__ p2w,
    const float* __restrict__ p2b, const int* __restrict__ pidxI,
    const float* __restrict__ ysum, float* __restrict__ out0) {
  int t = blockIdx.x * 256 + threadIdx.x;
  if (t >= 40960) return;
  int b = t / 10, c = t % 10;
  int p = pidxI[b];
  const float* hr = h + (size_t)b * 384 + p * 192;
  const float* wr = p2w + ((size_t)p * 10 + c) * 192;
  float s = 0.f;
  for (int o = 0; o < 192; o++) s += hr[o] * wr[o];
  s += p2b[p * 10 + c];
  out0[t] = s * ysum[b];
}

// ============================================================================
// Launch orchestration. BN+pack folded into consumer staging (no standalone
// elementwise passes over the conv activations). Workspace audit (floats):
//   pool1/act3  0        .. 33554432  (raw fp32; act3 aliases dead pool1)
//   Bcvt        33554432 .. 41943040  (pre_w packed)
//   discq       41943040 .. 42336256
//   p1q         42336256 .. 42729472
//   csplit      42729472 .. 46923776
//   featp       50331648 .. 54525952  (also wh3/wl3/wh2/wl2 before pre-FC)
//   ... rest as before; total ~235 MB (proven).
// ============================================================================
extern "C" void kernel_launch(void* const* d_in, const int* in_sizes, int n_in,
                              void* d_out, int out_size, void* d_ws, size_t ws_size,
                              hipStream_t stream) {
  const float* input   = (const float*)d_in[0];
  const float* conv1_w = (const float*)d_in[1];
  const float* bn1_g   = (const float*)d_in[3];
  const float* bn1_b   = (const float*)d_in[4];
  const float* conv2_w = (const float*)d_in[5];
  const float* bn2_g   = (const float*)d_in[7];
  const float* bn2_b   = (const float*)d_in[8];
  const float* conv3_w = (const float*)d_in[9];
  const float* bn3_g   = (const float*)d_in[11];
  const float* bn3_b   = (const float*)d_in[12];
  const float* pre_w   = (const float*)d_in[13];
  const float* bnp_g   = (const float*)d_in[15];
  const float* bnp_b   = (const float*)d_in[16];
  const float* disc_w  = (const float*)d_in[17];
  const float* bnd_g   = (const float*)d_in[19];
  const float* bnd_b   = (const float*)d_in[20];
  const float* dfc_w   = (const float*)d_in[21];
  const float* dfc_b   = (const float*)d_in[22];
  const float* sw_w    = (const float*)d_in[23];
  const float* sw_b    = (const float*)d_in[24];
  const float* p1_w    = (const float*)d_in[25];
  const float* p1_b    = (const float*)d_in[26];
  const float* p2_w    = (const float*)d_in[27];
  const float* p2_b    = (const float*)d_in[28];

  float* W = (float*)d_ws;
  float* pool1  = W + 0;           // [4096][32][16][16] raw fp32
  float* pool2  = W + 33554432;    // [4096][64][8][8] raw fp32 (first half of old region)
  float* act3   = W + 0;           // [4096][128][8][8] raw fp32, alias pool1 (dead)
  uint32_t* Bcvt = (uint32_t*)(W + 33554432);   // pre_w packed (overwrites pool2 AFTER conv3 consumed it? NO —
  // pool2 is consumed by conv3_mfma; Bcvt cvt runs after conv3 -> safe.)
  uint32_t* discq = (uint32_t*)(W + 41943040);  // disc_w packed
  uint32_t* p1q   = (uint32_t*)(W + 42336256);  // p1_w packed
  float* csplit = W + 42729472;    // [4096][1024] split-1 partial
  float* featp  = W + 50331648;    // [4096][1024], raw -> packed in place
  uint32_t* featq = (uint32_t*)featp;
  short* wh3    = (short*)(W + 50331648);       // conv3 w hi (dead until pre-FC)
  short* wl3    = (short*)(W + 50368512);
  short* wh2    = (short*)(W + 50405376);       // conv2 w hi
  short* wl2    = (short*)(W + 50414592);
  float* dpen   = W + 54525952;
  float* hbuf   = W + 56098816;
  float* swbuf  = W + 57671680;
  float* ysum   = W + 57679872;
  int*   pidxI  = (int*)(W + 57683968);
  float* part   = W + 57688064;
  double* sums  = (double*)(W + 58736640);
  float* scale  = W + 58769408;
  float* shift  = W + 58770432;

  float* out_cls = (float*)d_out;
  float* out_dom = out_cls + 40960;
  float* out_pid = out_cls + 49152;

  uint32_t k1a, k1b, k2a, k2b;
  threefry2x32(0u, 42u, 0u, 0u, k1a, k1b);
  threefry2x32(0u, 42u, 0u, 1u, k2a, k2b);

  // --- conv1 fused (raw pooled out) + BN1 stats ---
  conv1_fused_kernel<<<dim3(4096), dim3(256), 0, stream>>>(input, conv1_w, pool1, part);
  reduce_partials_kernel<<<dim3(64), dim3(256), 0, stream>>>(part, 4096, 64, sums);
  bn_finalize_kernel<<<dim3(1), dim3(64), 0, stream>>>(sums, 1, 0, bn1_g, bn1_b, scale, shift, 32, 1.0 / (4096.0 * 1024.0));

  // --- conv2 via MFMA (BN1 applied at staging; raw pooled out) + BN2 stats ---
  prep_w2_kernel<<<dim3(72), dim3(256), 0, stream>>>(conv2_w, wh2, wl2);
  conv2_mfma_kernel<<<dim3(4096), dim3(256), 0, stream>>>(pool1, scale, shift, wh2, wl2, pool2, part);
  reduce_partials_kernel<<<dim3(128), dim3(256), 0, stream>>>(part, 4096, 128, sums);
  bn_finalize_kernel<<<dim3(1), dim3(64), 0, stream>>>(sums, 1, 0, bn2_g, bn2_b, scale, shift, 64, 1.0 / (4096.0 * 256.0));

  // --- conv3 via MFMA (BN2 applied at staging; raw out) + BN3 stats ---
  prep_w3_kernel<<<dim3(288), dim3(256), 0, stream>>>(conv3_w, wh3, wl3);
  conv3_mfma_kernel<<<dim3(4096), dim3(256), 0, stream>>>(pool2, scale, shift, wh3, wl3, act3, part);
  reduce_partials_kernel<<<dim3(256), dim3(256), 0, stream>>>(part, 4096, 256, sums);
  bn_finalize_kernel<<<dim3(1), dim3(128), 0, stream>>>(sums, 1, 0, bn3_g, bn3_b, scale, shift, 128, 1.0 / (4096.0 * 64.0));

  // --- pre FC via MFMA big tile, split-K=2 (BN3 applied at A-staging) ---
  cvt_bf16q_kernel<<<dim3(8192), dim3(256), 0, stream>>>(pre_w, Bcvt, 2097152);
  gemm_bf16q_big_kernel<<<dim3(512), dim3(256), 0, stream>>>(act3, Bcvt, scale, shift, featp, csplit, 4096, 1024, 8192);
  col_stats_kernel<<<dim3(16, 8), dim3(1024), 0, stream>>>(featp, csplit, 4096, 1024, 8, sums);
  bn_finalize_kernel<<<dim3(4), dim3(256), 0, stream>>>(sums, 8, 2048, bnp_g, bnp_b, scale, shift, 1024, 1.0 / 4096.0);
  bn_relu_pack_cols4_kernel<<<dim3(4096), dim3(256), 0, stream>>>(featp, csplit, scale, shift, 1048576, 256);

  // --- disc FC 1024->384 via MFMA + BN + ReLU (fp32 out for heads) ---
  cvt_bf16q_kernel<<<dim3(384), dim3(256), 0, stream>>>(disc_w, discq, 98304);
  cvt_bf16q_kernel<<<dim3(384), dim3(256), 0, stream>>>(p1_w, p1q, 98304);
  gemm_bf16q_kernel<0><<<dim3(192), dim3(256), 0, stream>>>(featq, discq, (const float*)nullptr, dpen, 4096, 384, 1024);
  col_stats_kernel<<<dim3(6, 8), dim3(1024), 0, stream>>>(dpen, (const float*)nullptr, 4096, 384, 8, sums);
  bn_finalize_kernel<<<dim3(2), dim3(256), 0, stream>>>(sums, 8, 768, bnd_g, bnd_b, scale, shift, 384, 1.0 / 4096.0);
  bn_relu_cols4_kernel<<<dim3(1536), dim3(256), 0, stream>>>(dpen, scale, shift, 393216, 96);

  // --- heads + partition sampling ---
  heads_kernel<<<dim3(1024), dim3(256), 0, stream>>>(dpen, dfc_w, dfc_b, sw_w, sw_b, out_dom, swbuf);
  partition_kernel<<<dim3(16), dim3(256), 0, stream>>>(swbuf, out_pid, pidxI, ysum, k1a, k1b, k2a, k2b);

  // --- experts: p1 via MFMA (bias+relu epilogue), then gather + p2 ---
  gemm_bf16q_kernel<1><<<dim3(192), dim3(256), 0, stream>>>(featq, p1q, p1_b, hbuf, 4096, 384, 1024);
  final_kernel<<<dim3(160), dim3(256), 0, stream>>>(hbuf, p2_w, p2_b, pidxI, ysum, out_cls);
}

// Round 15
// 851.448 us; speedup vs baseline: 1.2311x; 1.0224x over previous
//
#include <hip/hip_runtime.h>
#include <cstdint>
#include <cstddef>

typedef __attribute__((ext_vector_type(8))) short short8;    // 8 bf16 (4 VGPR)
typedef __attribute__((ext_vector_type(4))) float f32x4;     // MFMA acc

// ============================================================================
// Threefry2x32 (matches jax._src.prng.threefry2x32).
// ============================================================================
__host__ __device__ inline void threefry2x32(uint32_t k0, uint32_t k1,
                                             uint32_t x0, uint32_t x1,
                                             uint32_t& o0, uint32_t& o1) {
  uint32_t ks2 = k0 ^ k1 ^ 0x1BD11BDAu;
  uint32_t v0 = x0 + k0, v1 = x1 + k1;
#define TF_R(r) { v0 += v1; v1 = (v1 << (r)) | (v1 >> (32 - (r))); v1 ^= v0; }
  TF_R(13) TF_R(15) TF_R(26) TF_R(6)
  v0 += k1; v1 += ks2 + 1u;
  TF_R(17) TF_R(29) TF_R(16) TF_R(24)
  v0 += ks2; v1 += k0 + 2u;
  TF_R(13) TF_R(15) TF_R(26) TF_R(6)
  v0 += k0; v1 += k1 + 3u;
  TF_R(17) TF_R(29) TF_R(16) TF_R(24)
  v0 += k1; v1 += ks2 + 4u;
  TF_R(13) TF_R(15) TF_R(26) TF_R(6)
  v0 += ks2; v1 += k0 + 5u;
#undef TF_R
  o0 = v0; o1 = v1;
}

__device__ __forceinline__ uint32_t tf_bits32(uint32_t k0, uint32_t k1, uint32_t j) {
  uint32_t o0, o1;
  threefry2x32(k0, k1, 0u, j, o0, o1);
  return o0 ^ o1;
}

__device__ __forceinline__ float u01_from_bits(uint32_t bits) {
  return __uint_as_float((bits >> 9) | 0x3f800000u) - 1.0f;  // [0,1)
}

__device__ __forceinline__ float waveSum(float v) {
#pragma unroll
  for (int off = 32; off > 0; off >>= 1) v += __shfl_down(v, off, 64);
  return v;
}

// ============================================================================
// conv1 fused: conv(3->32) + BN partials (unpooled) + RAW 2x2 maxpool store.
// ============================================================================
__global__ __launch_bounds__(256) void conv1_fused_kernel(
    const float* __restrict__ in, const float* __restrict__ w,
    float* __restrict__ outraw, float* __restrict__ partials) {
  __shared__ float ins[3 * 34 * 34];
  __shared__ float red[4][64];
  const int b = blockIdx.x, t = threadIdx.x;
  for (int i = t; i < 3 * 34 * 34; i += 256) {
    int ci = i / 1156, r = i % 1156, iy = r / 34, ix = r % 34;
    int y = iy - 1, x = ix - 1;
    float v = 0.f;
    if ((unsigned)y < 32u && (unsigned)x < 32u)
      v = in[(((size_t)b * 3 + ci) * 32 + y) * 32 + x];
    ins[i] = v;
  }
  __syncthreads();
  const int py = t >> 4, px = t & 15, wv = t >> 6, ln = t & 63;
  float win[3][4][4];
#pragma unroll
  for (int ci = 0; ci < 3; ci++)
#pragma unroll
    for (int r = 0; r < 4; r++)
#pragma unroll
      for (int c = 0; c < 4; c++)
        win[ci][r][c] = ins[ci * 1156 + (2 * py + r) * 34 + (2 * px + c)];
#pragma unroll 1
  for (int co = 0; co < 32; co++) {
    float acc00 = 0.f, acc01 = 0.f, acc10 = 0.f, acc11 = 0.f;
#pragma unroll
    for (int ci = 0; ci < 3; ci++) {
      const float* wp = w + (co * 3 + ci) * 9;  // wave-uniform -> s_load
#pragma unroll
      for (int dy = 0; dy < 3; dy++)
#pragma unroll
        for (int dx = 0; dx < 3; dx++) {
          float wvv = wp[dy * 3 + dx];
          acc00 += win[ci][dy][dx] * wvv;
          acc01 += win[ci][dy][dx + 1] * wvv;
          acc10 += win[ci][dy + 1][dx] * wvv;
          acc11 += win[ci][dy + 1][dx + 1] * wvv;
        }
    }
    float sm = acc00 + acc01 + acc10 + acc11;
    float sq = acc00 * acc00 + acc01 * acc01 + acc10 * acc10 + acc11 * acc11;
    float s = waveSum(sm), q = waveSum(sq);
    if (ln == 0) { red[wv][2 * co] = s; red[wv][2 * co + 1] = q; }
    float m = fmaxf(fmaxf(acc00, acc01), fmaxf(acc10, acc11));  // RAW max
    outraw[(((size_t)b * 32 + co) * 16 + py) * 16 + px] = m;
  }
  __syncthreads();
  for (int i = t; i < 64; i += 256)
    partials[(size_t)b * 64 + i] = red[0][i] + red[1][i] + red[2][i] + red[3][i];
}

// ============================================================================
// bf16-split helpers. Cheap RTZ split: hi = trunc(x), lo = trunc(x - hi).
// Representation err <= 2^-16|x| — same order as the dropped lo*lo term.
// ============================================================================
__device__ __forceinline__ uint32_t pack_bf16q(float x) {
  uint32_t u = __float_as_uint(x);
  uint32_t hi = u & 0xffff0000u;
  float r = x - __uint_as_float(hi);
  uint32_t lo = __float_as_uint(r) >> 16;
  return hi | lo;
}

__device__ __forceinline__ uint4 pk4bn(float4 v, float sc, float sh) {
  uint4 o;
  o.x = pack_bf16q(fmaxf(v.x * sc + sh, 0.f));
  o.y = pack_bf16q(fmaxf(v.y * sc + sh, 0.f));
  o.z = pack_bf16q(fmaxf(v.z * sc + sh, 0.f));
  o.w = pack_bf16q(fmaxf(v.w * sc + sh, 0.f));
  return o;
}

__global__ void cvt_bf16q_kernel(const float* X, uint32_t* Y, int n4) {
  int i = blockIdx.x * blockDim.x + threadIdx.x;
  if (i >= n4) return;
  float4 x = ((const float4*)X)[i];
  uint4 o;
  o.x = pack_bf16q(x.x); o.y = pack_bf16q(x.y);
  o.z = pack_bf16q(x.z); o.w = pack_bf16q(x.w);
  ((uint4*)Y)[i] = o;
}

// conv2 weight prepack: w [64][32][9] fp32 -> wh/wl [9][64][32] bf16 planes.
__global__ void prep_w2_kernel(const float* __restrict__ w, short* __restrict__ wh,
                               short* __restrict__ wl) {
  int idx = blockIdx.x * 256 + threadIdx.x;
  if (idx >= 64 * 32 * 9) return;
  int tp = idx % 9, rem = idx / 9;
  int ci = rem % 32, co = rem / 32;
  uint32_t pq = pack_bf16q(w[idx]);
  size_t o = ((size_t)tp * 64 + co) * 32 + ci;
  wh[o] = (short)(pq >> 16);
  wl[o] = (short)(pq & 0xffffu);
}

// conv3 weight prepack: w [128][64][9] fp32 -> wh/wl [9][128][64] bf16 planes.
__global__ void prep_w3_kernel(const float* __restrict__ w, short* __restrict__ wh,
                               short* __restrict__ wl) {
  int idx = blockIdx.x * 256 + threadIdx.x;
  if (idx >= 128 * 64 * 9) return;
  int tp = idx % 9, rem = idx / 9;
  int ci = rem % 64, co = rem / 64;
  uint32_t pq = pack_bf16q(w[idx]);
  size_t o = ((size_t)tp * 128 + co) * 64 + ci;
  wh[o] = (short)(pq >> 16);
  wl[o] = (short)(pq & 0xffffu);
}

// ============================================================================
// b128 LDS store of 8 consecutive k-elements (hi/lo planes), swizzled.
// Valid when KB is 8-aligned: pos(k) = k ^ SW is contiguous within the run.
// ============================================================================
#define STORE2(ARR_H, ARR_L, ROW, KB, SW, U, V)                                 \
  {                                                                             \
    uint32_t h0 = (U.x >> 16) | (U.y & 0xffff0000u);                            \
    uint32_t h1 = (U.z >> 16) | (U.w & 0xffff0000u);                            \
    uint32_t h2 = (V.x >> 16) | (V.y & 0xffff0000u);                            \
    uint32_t h3 = (V.z >> 16) | (V.w & 0xffff0000u);                            \
    uint32_t l0 = (U.x & 0xffffu) | (U.y << 16);                                \
    uint32_t l1 = (U.z & 0xffffu) | (U.w << 16);                                \
    uint32_t l2 = (V.x & 0xffffu) | (V.y << 16);                                \
    uint32_t l3 = (V.z & 0xffffu) | (V.w << 16);                                \
    int idx = (ROW) * 32 + ((KB) ^ (SW));                                       \
    *(uint4*)&ARR_H[idx] = make_uint4(h0, h1, h2, h3);                          \
    *(uint4*)&ARR_L[idx] = make_uint4(l0, l1, l2, l3);                          \
  }

// ============================================================================
// conv2 via MFMA implicit GEMM (bf16-split, 3 terms). BN1 at staging.
// ============================================================================
__global__ __launch_bounds__(256) void conv2_mfma_kernel(
    const float* __restrict__ in, const float* __restrict__ scale1,
    const float* __restrict__ shift1, const short* __restrict__ wh,
    const short* __restrict__ wl, float* __restrict__ outpool,
    float* __restrict__ partials) {
  __shared__ short Xh[324 * 32], Xl[324 * 32];
  __shared__ float red[4][128];
  const int b = blockIdx.x, t = threadIdx.x;
  for (int i = t; i < 324 * 16; i += 256) {
    int row = i >> 4;
    int py = row / 18, pxx = row % 18;
    if (py == 0 || py == 17 || pxx == 0 || pxx == 17) {
      ((uint32_t*)Xh)[i] = 0u;
      ((uint32_t*)Xl)[i] = 0u;
    }
  }
  for (int i = t; i < 4096; i += 256) {
    int p = i >> 8, px = i & 255;
    int y = px >> 4, x = px & 15;
    float va = in[((size_t)b * 32 + 2 * p) * 256 + px];
    float vb = in[((size_t)b * 32 + 2 * p + 1) * 256 + px];
    va = fmaxf(va * scale1[2 * p] + shift1[2 * p], 0.f);
    vb = fmaxf(vb * scale1[2 * p + 1] + shift1[2 * p + 1], 0.f);
    uint32_t ua = pack_bf16q(va), ub = pack_bf16q(vb);
    uint32_t h = (ua >> 16) | (ub & 0xffff0000u);
    uint32_t l = (ua & 0xffffu) | (ub << 16);
    int row = (y + 1) * 18 + (x + 1);
    int ci2 = (2 * p) ^ ((row & 3) << 3);  // swizzled, stays even
    ((uint32_t*)Xh)[(row * 32 + ci2) >> 1] = h;
    ((uint32_t*)Xl)[(row * 32 + ci2) >> 1] = l;
  }
  __syncthreads();
  const int w = t >> 6, l = t & 63;
  const int lr = l & 15, lg = l >> 4;
  f32x4 acc[4][4];  // [co block][px block]
#pragma unroll
  for (int i = 0; i < 4; i++)
#pragma unroll
    for (int j = 0; j < 4; j++) acc[i][j] = (f32x4){0.f, 0.f, 0.f, 0.f};
#pragma unroll 1
  for (int tap = 0; tap < 9; tap++) {
    const int dy = tap / 3, dx = tap % 3;
    short8 awh[4], awl[4];
#pragma unroll
    for (int i = 0; i < 4; i++) {
      size_t off = ((size_t)tap * 64 + i * 16 + lr) * 32 + lg * 8;
      awh[i] = *(const short8*)(wh + off);
      awl[i] = *(const short8*)(wl + off);
    }
    short8 bxh[4], bxl[4];
#pragma unroll
    for (int j = 0; j < 4; j++) {
      int y = w * 4 + j, x = lr;
      int row = (y + dy) * 18 + (x + dx);
      int ci = (lg * 8) ^ ((row & 3) << 3);
      bxh[j] = *(const short8*)&Xh[row * 32 + ci];
      bxl[j] = *(const short8*)&Xl[row * 32 + ci];
    }
#pragma unroll
    for (int i = 0; i < 4; i++)
#pragma unroll
      for (int j = 0; j < 4; j++) {
        acc[i][j] = __builtin_amdgcn_mfma_f32_16x16x32_bf16(awh[i], bxh[j], acc[i][j], 0, 0, 0);
        acc[i][j] = __builtin_amdgcn_mfma_f32_16x16x32_bf16(awh[i], bxl[j], acc[i][j], 0, 0, 0);
        acc[i][j] = __builtin_amdgcn_mfma_f32_16x16x32_bf16(awl[i], bxh[j], acc[i][j], 0, 0, 0);
      }
  }
#pragma unroll
  for (int i = 0; i < 4; i++)
#pragma unroll
    for (int r = 0; r < 4; r++) {
      int co = i * 16 + lg * 4 + r;
      float v0 = acc[i][0][r], v1 = acc[i][1][r], v2 = acc[i][2][r], v3 = acc[i][3][r];
      float s = v0 + v1 + v2 + v3;
      float q = v0 * v0 + v1 * v1 + v2 * v2 + v3 * v3;
#pragma unroll
      for (int off = 1; off <= 8; off <<= 1) {
        s += __shfl_xor(s, off, 64);
        q += __shfl_xor(q, off, 64);
      }
      if (lr == 0) { red[w][2 * co] = s; red[w][2 * co + 1] = q; }
      float h0 = fmaxf(v0, __shfl_xor(v0, 1, 64));
      float h1 = fmaxf(v1, __shfl_xor(v1, 1, 64));
      float h2 = fmaxf(v2, __shfl_xor(v2, 1, 64));
      float h3 = fmaxf(v3, __shfl_xor(v3, 1, 64));
      float pm0 = fmaxf(h0, h1);
      float pm1 = fmaxf(h2, h3);
      if ((lr & 1) == 0) {
        size_t base = ((size_t)b * 64 + co) * 64 + (w * 2) * 8 + (lr >> 1);
        outpool[base] = pm0;
        outpool[base + 8] = pm1;
      }
    }
  __syncthreads();
  for (int i = t; i < 128; i += 256)
    partials[(size_t)b * 128 + i] = red[0][i] + red[1][i] + red[2][i] + red[3][i];
}

// ============================================================================
// conv3 via MFMA implicit GEMM (bf16-split, 3 terms). BN2 applied at staging.
// ============================================================================
__global__ __launch_bounds__(256) void conv3_mfma_kernel(
    const float* __restrict__ in, const float* __restrict__ scale2,
    const float* __restrict__ shift2, const short* __restrict__ wh,
    const short* __restrict__ wl, float* __restrict__ outraw,
    float* __restrict__ partials) {
  __shared__ short Xh[100 * 64], Xl[100 * 64];
  __shared__ float red[256];
  const int b = blockIdx.x, t = threadIdx.x;
  for (int i = t; i < 100 * 32; i += 256) {
    int row = i >> 5;
    int py = row / 10, pxx = row % 10;
    if (py == 0 || py == 9 || pxx == 0 || pxx == 9) {
      ((uint32_t*)Xh)[i] = 0u;
      ((uint32_t*)Xl)[i] = 0u;
    }
  }
  for (int i = t; i < 2048; i += 256) {
    int p = i >> 6, px = i & 63;
    int y = px >> 3, x = px & 7;
    float va = in[((size_t)b * 64 + 2 * p) * 64 + px];
    float vb = in[((size_t)b * 64 + 2 * p + 1) * 64 + px];
    va = fmaxf(va * scale2[2 * p] + shift2[2 * p], 0.f);
    vb = fmaxf(vb * scale2[2 * p + 1] + shift2[2 * p + 1], 0.f);
    uint32_t ua = pack_bf16q(va), ub = pack_bf16q(vb);
    uint32_t h = (ua >> 16) | (ub & 0xffff0000u);
    uint32_t l = (ua & 0xffffu) | (ub << 16);
    int row = (y + 1) * 10 + (x + 1);
    int ci2 = (2 * p) ^ ((row & 7) << 3);
    ((uint32_t*)Xh)[(row * 64 + ci2) >> 1] = h;
    ((uint32_t*)Xl)[(row * 64 + ci2) >> 1] = l;
  }
  __syncthreads();
  const int w = t >> 6, l = t & 63;
  const int lr = l & 15, lg = l >> 4;
  const int co_base = w * 32;
  f32x4 acc[2][4];
#pragma unroll
  for (int i = 0; i < 2; i++)
#pragma unroll
    for (int j = 0; j < 4; j++) acc[i][j] = (f32x4){0.f, 0.f, 0.f, 0.f};
#pragma unroll 1
  for (int tap = 0; tap < 9; tap++) {
    const int dy = tap / 3, dx = tap % 3;
#pragma unroll
    for (int sl = 0; sl < 2; sl++) {
      short8 awh[2], awl[2];
#pragma unroll
      for (int i = 0; i < 2; i++) {
        size_t off = ((size_t)tap * 128 + co_base + i * 16 + lr) * 64 + sl * 32 + lg * 8;
        awh[i] = *(const short8*)(wh + off);
        awl[i] = *(const short8*)(wl + off);
      }
      short8 bxh[4], bxl[4];
#pragma unroll
      for (int j = 0; j < 4; j++) {
        int px = j * 16 + lr;
        int row = ((px >> 3) + dy) * 10 + (px & 7) + dx;
        int ci = (sl * 32 + lg * 8) ^ ((row & 7) << 3);
        bxh[j] = *(const short8*)&Xh[row * 64 + ci];
        bxl[j] = *(const short8*)&Xl[row * 64 + ci];
      }
#pragma unroll
      for (int i = 0; i < 2; i++)
#pragma unroll
        for (int j = 0; j < 4; j++) {
          acc[i][j] = __builtin_amdgcn_mfma_f32_16x16x32_bf16(awh[i], bxh[j], acc[i][j], 0, 0, 0);
          acc[i][j] = __builtin_amdgcn_mfma_f32_16x16x32_bf16(awh[i], bxl[j], acc[i][j], 0, 0, 0);
          acc[i][j] = __builtin_amdgcn_mfma_f32_16x16x32_bf16(awl[i], bxh[j], acc[i][j], 0, 0, 0);
        }
    }
  }
#pragma unroll
  for (int i = 0; i < 2; i++)
#pragma unroll
    for (int r = 0; r < 4; r++) {
      int co = co_base + i * 16 + lg * 4 + r;
      float s = 0.f, q = 0.f;
#pragma unroll
      for (int j = 0; j < 4; j++) {
        float v = acc[i][j][r];
        outraw[((size_t)b * 128 + co) * 64 + j * 16 + lr] = v;
        s += v; q += v * v;
      }
#pragma unroll
      for (int off = 1; off <= 8; off <<= 1) {
        s += __shfl_xor(s, off, 64);
        q += __shfl_xor(q, off, 64);
      }
      if (lr == 0) { red[2 * co] = s; red[2 * co + 1] = q; }
    }
  __syncthreads();
  for (int i = t; i < 256; i += 256) partials[(size_t)b * 256 + i] = red[i];
}

// ============================================================================
// BN helpers
// ============================================================================
__global__ __launch_bounds__(256) void reduce_partials_kernel(
    const float* __restrict__ partials, int nblk, int Q, double* __restrict__ sums) {
  int q = blockIdx.x;
  double acc = 0.0;
  for (int i = threadIdx.x; i < nblk; i += 256) acc += (double)partials[(size_t)i * Q + q];
  __shared__ double red[256];
  red[threadIdx.x] = acc;
  __syncthreads();
  for (int s = 128; s > 0; s >>= 1) {
    if (threadIdx.x < s) red[threadIdx.x] += red[threadIdx.x + s];
    __syncthreads();
  }
  if (threadIdx.x == 0) sums[q] = red[0];
}

// col stats over row-chunk, optional elementwise add of Y (split-K merge).
__global__ __launch_bounds__(1024) void col_stats_kernel(
    const float* __restrict__ X, const float* __restrict__ Y,
    int R, int C, int nch, double* __restrict__ sums) {
  int c0 = blockIdx.x * 64, chunk = blockIdx.y;
  int cl = threadIdx.x & 63, rg = threadIdx.x >> 6;
  int rows = R / nch, rbeg = chunk * rows, rend = rbeg + rows;
  double s = 0.0, sq = 0.0;
  for (int r = rbeg + rg; r < rend; r += 16) {
    size_t idx = (size_t)r * C + c0 + cl;
    float v = X[idx];
    if (Y) v += Y[idx];
    s += v; sq += (double)v * (double)v;
  }
  __shared__ double red[16][64][2];
  red[rg][cl][0] = s; red[rg][cl][1] = sq;
  __syncthreads();
  if (rg == 0) {
    for (int i = 1; i < 16; i++) { s += red[i][cl][0]; sq += red[i][cl][1]; }
    sums[(size_t)chunk * 2 * C + 2 * (c0 + cl)] = s;
    sums[(size_t)chunk * 2 * C + 2 * (c0 + cl) + 1] = sq;
  }
}

__global__ void bn_finalize_kernel(const double* __restrict__ sums, int nch, int cst2,
                                   const float* __restrict__ g, const float* __restrict__ b,
                                   float* __restrict__ scale, float* __restrict__ shift,
                                   int C, double invN) {
  int c = blockIdx.x * blockDim.x + threadIdx.x;
  if (c >= C) return;
  double s = 0.0, sq = 0.0;
  for (int ch = 0; ch < nch; ch++) {
    s += sums[(size_t)ch * cst2 + 2 * c];
    sq += sums[(size_t)ch * cst2 + 2 * c + 1];
  }
  double m = s * invN;
  double v = sq * invN - m * m;
  double sc = (double)g[c] / sqrt(v + 1e-5);
  scale[c] = (float)sc;
  shift[c] = (float)((double)b[c] - m * sc);
}

// BN+ReLU+pack for [R][C] row-major, in place, optional add of Y. C4 = C/4.
__global__ void bn_relu_pack_cols4_kernel(float* __restrict__ X,
                                          const float* __restrict__ Y,
                                          const float* __restrict__ scale,
                                          const float* __restrict__ shift,
                                          int n4, int C4) {
  int i = blockIdx.x * blockDim.x + threadIdx.x;
  if (i >= n4) return;
  int c4 = i % C4;
  float4 v = ((float4*)X)[i];
  if (Y) {
    float4 y = ((const float4*)Y)[i];
    v.x += y.x; v.y += y.y; v.z += y.z; v.w += y.w;
  }
  float4 sc = ((const float4*)scale)[c4];
  float4 sh = ((const float4*)shift)[c4];
  uint4 o;
  o.x = pack_bf16q(fmaxf(v.x * sc.x + sh.x, 0.f));
  o.y = pack_bf16q(fmaxf(v.y * sc.y + sh.y, 0.f));
  o.z = pack_bf16q(fmaxf(v.z * sc.z + sh.z, 0.f));
  o.w = pack_bf16q(fmaxf(v.w * sc.w + sh.w, 0.f));
  ((uint4*)X)[i] = o;
}

// BN+ReLU (fp32 out) for [R][C] row-major, in place. C4 = C/4.
__global__ void bn_relu_cols4_kernel(float* __restrict__ X, const float* __restrict__ scale,
                                     const float* __restrict__ shift, int n4, int C4) {
  int i = blockIdx.x * blockDim.x + threadIdx.x;
  if (i >= n4) return;
  int c4 = i % C4;
  float4 v = ((float4*)X)[i];
  float4 sc = ((const float4*)scale)[c4];
  float4 sh = ((const float4*)shift)[c4];
  v.x = fmaxf(v.x * sc.x + sh.x, 0.f);
  v.y = fmaxf(v.y * sc.y + sh.y, 0.f);
  v.z = fmaxf(v.z * sc.z + sh.z, 0.f);
  v.w = fmaxf(v.w * sc.w + sh.w, 0.f);
  ((float4*)X)[i] = v;
}

// full-rank row swizzle: distinct k-block for every row in a 16-row group
__device__ __forceinline__ int swz16(int row) {
  return ((row & 3) ^ ((row >> 2) & 3)) << 3;
}

// ============================================================================
// bf16-split MFMA GEMM (3 terms), 128x64 tile, BK=32. For N%64 shapes.
// ============================================================================
template <int BIASRELU>
__global__ __launch_bounds__(256) void gemm_bf16q_kernel(
    const uint32_t* __restrict__ A, const uint32_t* __restrict__ B,
    const float* __restrict__ bias, float* __restrict__ C, int M, int N, int K) {
  __shared__ short Ah[128 * 32], Al[128 * 32], Bh[64 * 32], Bl[64 * 32];
  const int t = threadIdx.x;
  const int nTN = N >> 6;
  const int mPer = (M >> 7) >> 3;
  const int bid = blockIdx.x;
  const int xcd = bid & 7, qq = bid >> 3;
  const int m0 = (xcd * mPer + qq / nTN) << 7;
  const int n0 = (qq % nTN) << 6;
  const int w = t >> 6, l = t & 63;
  const int wrow = (w >> 1) << 6, wcol = (w & 1) << 5;
  const int lr = l & 15, lg = l >> 4;
  const int ar = t >> 1, akh = (t & 1) << 4;
  const int br = t >> 2, bkh = (t & 3) << 3;
  const int asw = swz16(ar), bsw = swz16(br);
  const uint32_t* Ap = A + (size_t)(m0 + ar) * K + akh;
  const uint32_t* Bp = B + (size_t)(n0 + br) * K + bkh;
  f32x4 acc[4][2];
#pragma unroll
  for (int i = 0; i < 4; i++)
#pragma unroll
    for (int j = 0; j < 2; j++) acc[i][j] = (f32x4){0.f, 0.f, 0.f, 0.f};
  uint4 ra0 = *(const uint4*)(Ap + 0), ra1 = *(const uint4*)(Ap + 4);
  uint4 ra2 = *(const uint4*)(Ap + 8), ra3 = *(const uint4*)(Ap + 12);
  uint4 rb0 = *(const uint4*)(Bp + 0), rb1 = *(const uint4*)(Bp + 4);
  const int NS = K >> 5;
  for (int s = 0; s < NS; s++) {
    __syncthreads();
    STORE2(Ah, Al, ar, akh + 0, asw, ra0, ra1)
    STORE2(Ah, Al, ar, akh + 8, asw, ra2, ra3)
    STORE2(Bh, Bl, br, bkh, bsw, rb0, rb1)
    __syncthreads();
    if (s + 1 < NS) {
      int ko = (s + 1) << 5;
      ra0 = *(const uint4*)(Ap + ko); ra1 = *(const uint4*)(Ap + ko + 4);
      ra2 = *(const uint4*)(Ap + ko + 8); ra3 = *(const uint4*)(Ap + ko + 12);
      rb0 = *(const uint4*)(Bp + ko); rb1 = *(const uint4*)(Bp + ko + 4);
    }
    short8 ahf[4], alf[4], bhf[2], blf[2];
#pragma unroll
    for (int i = 0; i < 4; i++) {
      int R = wrow + i * 16 + lr;
      int kk = (lg << 3) ^ swz16(R);
      ahf[i] = *(const short8*)&Ah[R * 32 + kk];
      alf[i] = *(const short8*)&Al[R * 32 + kk];
    }
#pragma unroll
    for (int j = 0; j < 2; j++) {
      int Cc = wcol + j * 16 + lr;
      int kk = (lg << 3) ^ swz16(Cc);
      bhf[j] = *(const short8*)&Bh[Cc * 32 + kk];
      blf[j] = *(const short8*)&Bl[Cc * 32 + kk];
    }
#pragma unroll
    for (int i = 0; i < 4; i++)
#pragma unroll
      for (int j = 0; j < 2; j++) {
        acc[i][j] = __builtin_amdgcn_mfma_f32_16x16x32_bf16(ahf[i], bhf[j], acc[i][j], 0, 0, 0);
        acc[i][j] = __builtin_amdgcn_mfma_f32_16x16x32_bf16(ahf[i], blf[j], acc[i][j], 0, 0, 0);
        acc[i][j] = __builtin_amdgcn_mfma_f32_16x16x32_bf16(alf[i], bhf[j], acc[i][j], 0, 0, 0);
      }
  }
#pragma unroll
  for (int i = 0; i < 4; i++)
#pragma unroll
    for (int j = 0; j < 2; j++) {
      int n = n0 + wcol + j * 16 + lr;
#pragma unroll
      for (int r = 0; r < 4; r++) {
        int m = m0 + wrow + i * 16 + lg * 4 + r;
        float v = acc[i][j][r];
        if (BIASRELU) v = fmaxf(v + bias[n], 0.f);
        C[(size_t)m * N + n] = v;
      }
    }
}

// ============================================================================
// bf16-split MFMA GEMM (3 terms), BIG tile 128x128, BK=32, SPLIT-K=2.
// A is RAW fp32 act3 with BN3+ReLU applied at staging (16-float runs never
// cross a 64-wide channel). Grid = 2*(M/128)*(N/128) -> 2 blocks/CU.
// ============================================================================
__global__ __launch_bounds__(256, 2) void gemm_bf16q_big_kernel(
    const float* __restrict__ A, const uint32_t* __restrict__ B,
    const float* __restrict__ scale, const float* __restrict__ shift,
    float* __restrict__ C0, float* __restrict__ C1, int M, int N, int K) {
  __shared__ short Ah[128 * 32], Al[128 * 32], Bh[128 * 32], Bl[128 * 32];
  const int t = threadIdx.x;
  const int nTN = N >> 7;
  const int tiles = (M >> 7) * nTN;
  const int mPer = (M >> 7) >> 3;
  const int split = blockIdx.x / tiles;
  const int bid = blockIdx.x % tiles;
  const int xcd = bid & 7, qq = bid >> 3;
  const int m0 = (xcd * mPer + qq / nTN) << 7;
  const int n0 = (qq % nTN) << 7;
  const int Kh = K >> 1;
  const int kbeg = split * Kh;
  float* Cout = split ? C1 : C0;
  const int w = t >> 6, l = t & 63;
  const int wrow = (w & 1) << 6, wcol = (w >> 1) << 6;
  const int lr = l & 15, lg = l >> 4;
  const int ar = t >> 1, akh = (t & 1) << 4;   // A & B staging: 2 thr/row
  const int asw = swz16(ar);
  const float* Ap = A + (size_t)(m0 + ar) * K + kbeg + akh;
  const uint32_t* Bp = B + (size_t)(n0 + ar) * K + kbeg + akh;
  f32x4 acc[4][4];
#pragma unroll
  for (int i = 0; i < 4; i++)
#pragma unroll
    for (int j = 0; j < 4; j++) acc[i][j] = (f32x4){0.f, 0.f, 0.f, 0.f};
  float4 fa0 = *(const float4*)(Ap + 0), fa1 = *(const float4*)(Ap + 4);
  float4 fa2 = *(const float4*)(Ap + 8), fa3 = *(const float4*)(Ap + 12);
  uint4 rb0 = *(const uint4*)(Bp + 0), rb1 = *(const uint4*)(Bp + 4);
  uint4 rb2 = *(const uint4*)(Bp + 8), rb3 = *(const uint4*)(Bp + 12);
  const int NS = Kh >> 5;
  for (int s = 0; s < NS; s++) {
    // BN+ReLU+pack the A slab for this iteration (run stays in one channel)
    int ch = (kbeg + akh + (s << 5)) >> 6;
    float sc = scale[ch], sh = shift[ch];
    uint4 ua0 = pk4bn(fa0, sc, sh), ua1 = pk4bn(fa1, sc, sh);
    uint4 ua2 = pk4bn(fa2, sc, sh), ua3 = pk4bn(fa3, sc, sh);
    __syncthreads();
    STORE2(Ah, Al, ar, akh + 0, asw, ua0, ua1)
    STORE2(Ah, Al, ar, akh + 8, asw, ua2, ua3)
    STORE2(Bh, Bl, ar, akh + 0, asw, rb0, rb1)
    STORE2(Bh, Bl, ar, akh + 8, asw, rb2, rb3)
    __syncthreads();
    if (s + 1 < NS) {
      int ko = (s + 1) << 5;
      fa0 = *(const float4*)(Ap + ko); fa1 = *(const float4*)(Ap + ko + 4);
      fa2 = *(const float4*)(Ap + ko + 8); fa3 = *(const float4*)(Ap + ko + 12);
      rb0 = *(const uint4*)(Bp + ko); rb1 = *(const uint4*)(Bp + ko + 4);
      rb2 = *(const uint4*)(Bp + ko + 8); rb3 = *(const uint4*)(Bp + ko + 12);
    }
    short8 ahf[4], alf[4], bhf[4], blf[4];
#pragma unroll
    for (int i = 0; i < 4; i++) {
      int R = wrow + i * 16 + lr;
      int kk = (lg << 3) ^ swz16(R);
      ahf[i] = *(const short8*)&Ah[R * 32 + kk];
      alf[i] = *(const short8*)&Al[R * 32 + kk];
    }
#pragma unroll
    for (int j = 0; j < 4; j++) {
      int Cc = wcol + j * 16 + lr;
      int kk = (lg << 3) ^ swz16(Cc);
      bhf[j] = *(const short8*)&Bh[Cc * 32 + kk];
      blf[j] = *(const short8*)&Bl[Cc * 32 + kk];
    }
#pragma unroll
    for (int i = 0; i < 4; i++)
#pragma unroll
      for (int j = 0; j < 4; j++) {
        acc[i][j] = __builtin_amdgcn_mfma_f32_16x16x32_bf16(ahf[i], bhf[j], acc[i][j], 0, 0, 0);
        acc[i][j] = __builtin_amdgcn_mfma_f32_16x16x32_bf16(ahf[i], blf[j], acc[i][j], 0, 0, 0);
        acc[i][j] = __builtin_amdgcn_mfma_f32_16x16x32_bf16(alf[i], bhf[j], acc[i][j], 0, 0, 0);
      }
  }
#pragma unroll
  for (int i = 0; i < 4; i++)
#pragma unroll
    for (int j = 0; j < 4; j++) {
      int n = n0 + wcol + j * 16 + lr;
#pragma unroll
      for (int r = 0; r < 4; r++) {
        int m = m0 + wrow + i * 16 + lg * 4 + r;
        Cout[(size_t)m * N + n] = acc[i][j][r];
      }
    }
}

// ============================================================================
// heads, wave-parallel: one wave per b; 4 j's per wave; double accumulation.
// ============================================================================
__global__ __launch_bounds__(256) void heads_kernel(
    const float* __restrict__ dpen, const float* __restrict__ dfc_w,
    const float* __restrict__ dfc_b, const float* __restrict__ sw_w,
    const float* __restrict__ sw_b, float* __restrict__ out_dom,
    float* __restrict__ swbuf) {
  int wv = threadIdx.x >> 6, ln = threadIdx.x & 63;
  int b = blockIdx.x * 4 + wv;
  const float* row = dpen + (size_t)b * 384;
  double a0 = 0.0, a1 = 0.0, a2 = 0.0, a3 = 0.0;
  for (int k = ln; k < 384; k += 64) {
    double rv = (double)row[k];
    a0 += rv * (double)dfc_w[k];
    a1 += rv * (double)dfc_w[384 + k];
    a2 += rv * (double)sw_w[k];
    a3 += rv * (double)sw_w[384 + k];
  }
#pragma unroll
  for (int off = 32; off > 0; off >>= 1) {
    a0 += __shfl_down(a0, off, 64);
    a1 += __shfl_down(a1, off, 64);
    a2 += __shfl_down(a2, off, 64);
    a3 += __shfl_down(a3, off, 64);
  }
  if (ln == 0) {
    out_dom[b * 2 + 0] = (float)(a0 + (double)dfc_b[0]);
    out_dom[b * 2 + 1] = (float)(a1 + (double)dfc_b[1]);
    swbuf[b * 2 + 0] = (float)(a2 + (double)sw_b[0]);
    swbuf[b * 2 + 1] = (float)(a3 + (double)sw_b[1]);
  }
}

// ============================================================================
// gumbel-softmax + categorical partition choice (threefry partitionable).
// ============================================================================
__global__ __launch_bounds__(256) void partition_kernel(
    const float* __restrict__ swbuf, float* __restrict__ out_pid,
    int* __restrict__ pidxI, float* __restrict__ ysum,
    uint32_t k1a, uint32_t k1b, uint32_t k2a, uint32_t k2b) {
  int b = blockIdx.x * 256 + threadIdx.x;
  if (b >= 4096) return;
  uint32_t j0 = (uint32_t)(2 * b), j1 = (uint32_t)(2 * b + 1);
  float f0 = u01_from_bits(tf_bits32(k1a, k1b, j0));
  float f1 = u01_from_bits(tf_bits32(k1a, k1b, j1));
  const float MINV = 1e-10f;
  float u0 = fmaxf(MINV, f0 * (1.0f - MINV) + MINV);
  float u1 = fmaxf(MINV, f1 * (1.0f - MINV) + MINV);
  double g0 = -log(-log((double)u0));
  double g1 = -log(-log((double)u1));
  double s0 = (double)swbuf[2 * b], s1 = (double)swbuf[2 * b + 1];
  double x0 = (s0 + g0) / 0.1;
  double x1 = (s1 + g1) / 0.1;
  double mx = fmax(x0, x1);
  double e0 = exp(x0 - mx), e1 = exp(x1 - mx);
  double es = e0 + e1;
  double y0 = e0 / es, y1 = e1 / es;
  float h0 = u01_from_bits(tf_bits32(k2a, k2b, j0));
  float h1 = u01_from_bits(tf_bits32(k2a, k2b, j1));
  const float TINY = 1.17549435e-38f;
  float v0 = fmaxf(TINY, h0 * (1.0f - TINY) + TINY);
  float v1 = fmaxf(TINY, h1 * (1.0f - TINY) + TINY);
  double gg0 = -log(-log((double)v0));
  double gg1 = -log(-log((double)v1));
  double l0 = log(y0 + 1e-20) + gg0;
  double l1 = log(y1 + 1e-20) + gg1;
  int p = (l1 > l0) ? 1 : 0;
  out_pid[b] = (float)p;
  pidxI[b] = p;
  ysum[b] = (float)(y0 + y1);
}

// ============================================================================
// final head
// ============================================================================
__global__ __launch_bounds__(256) void final_kernel(
    const float* __restrict__ h, const float* __restrict__ p2w,
    const float* __restrict__ p2b, const int* __restrict__ pidxI,
    const float* __restrict__ ysum, float* __restrict__ out0) {
  int t = blockIdx.x * 256 + threadIdx.x;
  if (t >= 40960) return;
  int b = t / 10, c = t % 10;
  int p = pidxI[b];
  const float* hr = h + (size_t)b * 384 + p * 192;
  const float* wr = p2w + ((size_t)p * 10 + c) * 192;
  float s = 0.f;
  for (int o = 0; o < 192; o++) s += hr[o] * wr[o];
  s += p2b[p * 10 + c];
  out0[t] = s * ysum[b];
}

// ============================================================================
// Launch orchestration (structure = round 14; cheap pack + b128 LDS stores).
// ============================================================================
extern "C" void kernel_launch(void* const* d_in, const int* in_sizes, int n_in,
                              void* d_out, int out_size, void* d_ws, size_t ws_size,
                              hipStream_t stream) {
  const float* input   = (const float*)d_in[0];
  const float* conv1_w = (const float*)d_in[1];
  const float* bn1_g   = (const float*)d_in[3];
  const float* bn1_b   = (const float*)d_in[4];
  const float* conv2_w = (const float*)d_in[5];
  const float* bn2_g   = (const float*)d_in[7];
  const float* bn2_b   = (const float*)d_in[8];
  const float* conv3_w = (const float*)d_in[9];
  const float* bn3_g   = (const float*)d_in[11];
  const float* bn3_b   = (const float*)d_in[12];
  const float* pre_w   = (const float*)d_in[13];
  const float* bnp_g   = (const float*)d_in[15];
  const float* bnp_b   = (const float*)d_in[16];
  const float* disc_w  = (const float*)d_in[17];
  const float* bnd_g   = (const float*)d_in[19];
  const float* bnd_b   = (const float*)d_in[20];
  const float* dfc_w   = (const float*)d_in[21];
  const float* dfc_b   = (const float*)d_in[22];
  const float* sw_w    = (const float*)d_in[23];
  const float* sw_b    = (const float*)d_in[24];
  const float* p1_w    = (const float*)d_in[25];
  const float* p1_b    = (const float*)d_in[26];
  const float* p2_w    = (const float*)d_in[27];
  const float* p2_b    = (const float*)d_in[28];

  float* W = (float*)d_ws;
  float* pool1  = W + 0;           // [4096][32][16][16] raw fp32
  float* pool2  = W + 33554432;    // [4096][64][8][8] raw fp32
  float* act3   = W + 0;           // [4096][128][8][8] raw fp32, alias pool1
  uint32_t* Bcvt = (uint32_t*)(W + 33554432);   // pre_w packed (after conv3 consumed pool2)
  uint32_t* discq = (uint32_t*)(W + 41943040);  // disc_w packed
  uint32_t* p1q   = (uint32_t*)(W + 42336256);  // p1_w packed
  float* csplit = W + 42729472;    // [4096][1024] split-1 partial
  float* featp  = W + 50331648;    // [4096][1024], raw -> packed in place
  uint32_t* featq = (uint32_t*)featp;
  short* wh3    = (short*)(W + 50331648);       // conv3 w hi (dead until pre-FC)
  short* wl3    = (short*)(W + 50368512);
  short* wh2    = (short*)(W + 50405376);       // conv2 w hi
  short* wl2    = (short*)(W + 50414592);
  float* dpen   = W + 54525952;
  float* hbuf   = W + 56098816;
  float* swbuf  = W + 57671680;
  float* ysum   = W + 57679872;
  int*   pidxI  = (int*)(W + 57683968);
  float* part   = W + 57688064;
  double* sums  = (double*)(W + 58736640);
  float* scale  = W + 58769408;
  float* shift  = W + 58770432;

  float* out_cls = (float*)d_out;
  float* out_dom = out_cls + 40960;
  float* out_pid = out_cls + 49152;

  uint32_t k1a, k1b, k2a, k2b;
  threefry2x32(0u, 42u, 0u, 0u, k1a, k1b);
  threefry2x32(0u, 42u, 0u, 1u, k2a, k2b);

  // --- conv1 fused (raw pooled out) + BN1 stats ---
  conv1_fused_kernel<<<dim3(4096), dim3(256), 0, stream>>>(input, conv1_w, pool1, part);
  reduce_partials_kernel<<<dim3(64), dim3(256), 0, stream>>>(part, 4096, 64, sums);
  bn_finalize_kernel<<<dim3(1), dim3(64), 0, stream>>>(sums, 1, 0, bn1_g, bn1_b, scale, shift, 32, 1.0 / (4096.0 * 1024.0));

  // --- conv2 via MFMA (BN1 applied at staging; raw pooled out) + BN2 stats ---
  prep_w2_kernel<<<dim3(72), dim3(256), 0, stream>>>(conv2_w, wh2, wl2);
  conv2_mfma_kernel<<<dim3(4096), dim3(256), 0, stream>>>(pool1, scale, shift, wh2, wl2, pool2, part);
  reduce_partials_kernel<<<dim3(128), dim3(256), 0, stream>>>(part, 4096, 128, sums);
  bn_finalize_kernel<<<dim3(1), dim3(64), 0, stream>>>(sums, 1, 0, bn2_g, bn2_b, scale, shift, 64, 1.0 / (4096.0 * 256.0));

  // --- conv3 via MFMA (BN2 applied at staging; raw out) + BN3 stats ---
  prep_w3_kernel<<<dim3(288), dim3(256), 0, stream>>>(conv3_w, wh3, wl3);
  conv3_mfma_kernel<<<dim3(4096), dim3(256), 0, stream>>>(pool2, scale, shift, wh3, wl3, act3, part);
  reduce_partials_kernel<<<dim3(256), dim3(256), 0, stream>>>(part, 4096, 256, sums);
  bn_finalize_kernel<<<dim3(1), dim3(128), 0, stream>>>(sums, 1, 0, bn3_g, bn3_b, scale, shift, 128, 1.0 / (4096.0 * 64.0));

  // --- pre FC via MFMA big tile, split-K=2 (BN3 applied at A-staging) ---
  cvt_bf16q_kernel<<<dim3(8192), dim3(256), 0, stream>>>(pre_w, Bcvt, 2097152);
  gemm_bf16q_big_kernel<<<dim3(512), dim3(256), 0, stream>>>(act3, Bcvt, scale, shift, featp, csplit, 4096, 1024, 8192);
  col_stats_kernel<<<dim3(16, 8), dim3(1024), 0, stream>>>(featp, csplit, 4096, 1024, 8, sums);
  bn_finalize_kernel<<<dim3(4), dim3(256), 0, stream>>>(sums, 8, 2048, bnp_g, bnp_b, scale, shift, 1024, 1.0 / 4096.0);
  bn_relu_pack_cols4_kernel<<<dim3(4096), dim3(256), 0, stream>>>(featp, csplit, scale, shift, 1048576, 256);

  // --- disc FC 1024->384 via MFMA + BN + ReLU (fp32 out for heads) ---
  cvt_bf16q_kernel<<<dim3(384), dim3(256), 0, stream>>>(disc_w, discq, 98304);
  cvt_bf16q_kernel<<<dim3(384), dim3(256), 0, stream>>>(p1_w, p1q, 98304);
  gemm_bf16q_kernel<0><<<dim3(192), dim3(256), 0, stream>>>(featq, discq, (const float*)nullptr, dpen, 4096, 384, 1024);
  col_stats_kernel<<<dim3(6, 8), dim3(1024), 0, stream>>>(dpen, (const float*)nullptr, 4096, 384, 8, sums);
  bn_finalize_kernel<<<dim3(2), dim3(256), 0, stream>>>(sums, 8, 768, bnd_g, bnd_b, scale, shift, 384, 1.0 / 4096.0);
  bn_relu_cols4_kernel<<<dim3(1536), dim3(256), 0, stream>>>(dpen, scale, shift, 393216, 96);

  // --- heads + partition sampling ---
  heads_kernel<<<dim3(1024), dim3(256), 0, stream>>>(dpen, dfc_w, dfc_b, sw_w, sw_b, out_dom, swbuf);
  partition_kernel<<<dim3(16), dim3(256), 0, stream>>>(swbuf, out_pid, pidxI, ysum, k1a, k1b, k2a, k2b);

  // --- experts: p1 via MFMA (bias+relu epilogue), then gather + p2 ---
  gemm_bf16q_kernel<1><<<dim3(192), dim3(256), 0, stream>>>(featq, p1q, p1_b, hbuf, 4096, 384, 1024);
  final_kernel<<<dim3(160), dim3(256), 0, stream>>>(hbuf, p2_w, p2_b, pidxI, ysum, out_cls);
}

// Round 16
// 826.215 us; speedup vs baseline: 1.2687x; 1.0305x over previous
//
#include <hip/hip_runtime.h>
#include <cstdint>
#include <cstddef>

typedef __attribute__((ext_vector_type(8))) short short8;    // 8 bf16 (4 VGPR)
typedef __attribute__((ext_vector_type(4))) float f32x4;     // MFMA acc

// ============================================================================
// Threefry2x32 (matches jax._src.prng.threefry2x32).
// ============================================================================
__host__ __device__ inline void threefry2x32(uint32_t k0, uint32_t k1,
                                             uint32_t x0, uint32_t x1,
                                             uint32_t& o0, uint32_t& o1) {
  uint32_t ks2 = k0 ^ k1 ^ 0x1BD11BDAu;
  uint32_t v0 = x0 + k0, v1 = x1 + k1;
#define TF_R(r) { v0 += v1; v1 = (v1 << (r)) | (v1 >> (32 - (r))); v1 ^= v0; }
  TF_R(13) TF_R(15) TF_R(26) TF_R(6)
  v0 += k1; v1 += ks2 + 1u;
  TF_R(17) TF_R(29) TF_R(16) TF_R(24)
  v0 += ks2; v1 += k0 + 2u;
  TF_R(13) TF_R(15) TF_R(26) TF_R(6)
  v0 += k0; v1 += k1 + 3u;
  TF_R(17) TF_R(29) TF_R(16) TF_R(24)
  v0 += k1; v1 += ks2 + 4u;
  TF_R(13) TF_R(15) TF_R(26) TF_R(6)
  v0 += ks2; v1 += k0 + 5u;
#undef TF_R
  o0 = v0; o1 = v1;
}

__device__ __forceinline__ uint32_t tf_bits32(uint32_t k0, uint32_t k1, uint32_t j) {
  uint32_t o0, o1;
  threefry2x32(k0, k1, 0u, j, o0, o1);
  return o0 ^ o1;
}

__device__ __forceinline__ float u01_from_bits(uint32_t bits) {
  return __uint_as_float((bits >> 9) | 0x3f800000u) - 1.0f;  // [0,1)
}

__device__ __forceinline__ float waveSum(float v) {
#pragma unroll
  for (int off = 32; off > 0; off >>= 1) v += __shfl_down(v, off, 64);
  return v;
}

// ============================================================================
// conv1 fused: conv(3->32) + BN partials (unpooled) + RAW 2x2 maxpool store.
// ============================================================================
__global__ __launch_bounds__(256) void conv1_fused_kernel(
    const float* __restrict__ in, const float* __restrict__ w,
    float* __restrict__ outraw, float* __restrict__ partials) {
  __shared__ float ins[3 * 34 * 34];
  __shared__ float red[4][64];
  const int b = blockIdx.x, t = threadIdx.x;
  for (int i = t; i < 3 * 34 * 34; i += 256) {
    int ci = i / 1156, r = i % 1156, iy = r / 34, ix = r % 34;
    int y = iy - 1, x = ix - 1;
    float v = 0.f;
    if ((unsigned)y < 32u && (unsigned)x < 32u)
      v = in[(((size_t)b * 3 + ci) * 32 + y) * 32 + x];
    ins[i] = v;
  }
  __syncthreads();
  const int py = t >> 4, px = t & 15, wv = t >> 6, ln = t & 63;
  float win[3][4][4];
#pragma unroll
  for (int ci = 0; ci < 3; ci++)
#pragma unroll
    for (int r = 0; r < 4; r++)
#pragma unroll
      for (int c = 0; c < 4; c++)
        win[ci][r][c] = ins[ci * 1156 + (2 * py + r) * 34 + (2 * px + c)];
#pragma unroll 1
  for (int co = 0; co < 32; co++) {
    float acc00 = 0.f, acc01 = 0.f, acc10 = 0.f, acc11 = 0.f;
#pragma unroll
    for (int ci = 0; ci < 3; ci++) {
      const float* wp = w + (co * 3 + ci) * 9;  // wave-uniform -> s_load
#pragma unroll
      for (int dy = 0; dy < 3; dy++)
#pragma unroll
        for (int dx = 0; dx < 3; dx++) {
          float wvv = wp[dy * 3 + dx];
          acc00 += win[ci][dy][dx] * wvv;
          acc01 += win[ci][dy][dx + 1] * wvv;
          acc10 += win[ci][dy + 1][dx] * wvv;
          acc11 += win[ci][dy + 1][dx + 1] * wvv;
        }
    }
    float sm = acc00 + acc01 + acc10 + acc11;
    float sq = acc00 * acc00 + acc01 * acc01 + acc10 * acc10 + acc11 * acc11;
    float s = waveSum(sm), q = waveSum(sq);
    if (ln == 0) { red[wv][2 * co] = s; red[wv][2 * co + 1] = q; }
    float m = fmaxf(fmaxf(acc00, acc01), fmaxf(acc10, acc11));  // RAW max
    outraw[(((size_t)b * 32 + co) * 16 + py) * 16 + px] = m;
  }
  __syncthreads();
  for (int i = t; i < 64; i += 256)
    partials[(size_t)b * 64 + i] = red[0][i] + red[1][i] + red[2][i] + red[3][i];
}

// ============================================================================
// bf16-split helpers. Cheap RTZ split: hi = trunc(x), lo = trunc(x - hi).
// ============================================================================
__device__ __forceinline__ uint32_t pack_bf16q(float x) {
  uint32_t u = __float_as_uint(x);
  uint32_t hi = u & 0xffff0000u;
  float r = x - __uint_as_float(hi);
  uint32_t lo = __float_as_uint(r) >> 16;
  return hi | lo;
}

__device__ __forceinline__ uint4 pk4bn(float4 v, float sc, float sh) {
  uint4 o;
  o.x = pack_bf16q(fmaxf(v.x * sc + sh, 0.f));
  o.y = pack_bf16q(fmaxf(v.y * sc + sh, 0.f));
  o.z = pack_bf16q(fmaxf(v.z * sc + sh, 0.f));
  o.w = pack_bf16q(fmaxf(v.w * sc + sh, 0.f));
  return o;
}

__global__ void cvt_bf16q_kernel(const float* X, uint32_t* Y, int n4) {
  int i = blockIdx.x * blockDim.x + threadIdx.x;
  if (i >= n4) return;
  float4 x = ((const float4*)X)[i];
  uint4 o;
  o.x = pack_bf16q(x.x); o.y = pack_bf16q(x.y);
  o.z = pack_bf16q(x.z); o.w = pack_bf16q(x.w);
  ((uint4*)Y)[i] = o;
}

// conv2 weight prepack: w [64][32][9] fp32 -> wh/wl [9][64][32] bf16 planes.
__global__ void prep_w2_kernel(const float* __restrict__ w, short* __restrict__ wh,
                               short* __restrict__ wl) {
  int idx = blockIdx.x * 256 + threadIdx.x;
  if (idx >= 64 * 32 * 9) return;
  int tp = idx % 9, rem = idx / 9;
  int ci = rem % 32, co = rem / 32;
  uint32_t pq = pack_bf16q(w[idx]);
  size_t o = ((size_t)tp * 64 + co) * 32 + ci;
  wh[o] = (short)(pq >> 16);
  wl[o] = (short)(pq & 0xffffu);
}

// conv3 weight prepack: w [128][64][9] fp32 -> wh/wl [9][128][64] bf16 planes.
__global__ void prep_w3_kernel(const float* __restrict__ w, short* __restrict__ wh,
                               short* __restrict__ wl) {
  int idx = blockIdx.x * 256 + threadIdx.x;
  if (idx >= 128 * 64 * 9) return;
  int tp = idx % 9, rem = idx / 9;
  int ci = rem % 64, co = rem / 64;
  uint32_t pq = pack_bf16q(w[idx]);
  size_t o = ((size_t)tp * 128 + co) * 64 + ci;
  wh[o] = (short)(pq >> 16);
  wl[o] = (short)(pq & 0xffffu);
}

// ============================================================================
// b128 LDS store of 8 consecutive k-elements (hi/lo planes), swizzled.
// ============================================================================
#define STORE2(ARR_H, ARR_L, ROW, KB, SW, U, V)                                 \
  {                                                                             \
    uint32_t h0 = (U.x >> 16) | (U.y & 0xffff0000u);                            \
    uint32_t h1 = (U.z >> 16) | (U.w & 0xffff0000u);                            \
    uint32_t h2 = (V.x >> 16) | (V.y & 0xffff0000u);                            \
    uint32_t h3 = (V.z >> 16) | (V.w & 0xffff0000u);                            \
    uint32_t l0 = (U.x & 0xffffu) | (U.y << 16);                                \
    uint32_t l1 = (U.z & 0xffffu) | (U.w << 16);                                \
    uint32_t l2 = (V.x & 0xffffu) | (V.y << 16);                                \
    uint32_t l3 = (V.z & 0xffffu) | (V.w << 16);                                \
    int idx = (ROW) * 32 + ((KB) ^ (SW));                                       \
    *(uint4*)&ARR_H[idx] = make_uint4(h0, h1, h2, h3);                          \
    *(uint4*)&ARR_L[idx] = make_uint4(l0, l1, l2, l3);                          \
  }

// ============================================================================
// conv2 via MFMA implicit GEMM (bf16-split, 3 terms). BN1 at staging.
// ============================================================================
__global__ __launch_bounds__(256) void conv2_mfma_kernel(
    const float* __restrict__ in, const float* __restrict__ scale1,
    const float* __restrict__ shift1, const short* __restrict__ wh,
    const short* __restrict__ wl, float* __restrict__ outpool,
    float* __restrict__ partials) {
  __shared__ short Xh[324 * 32], Xl[324 * 32];
  __shared__ float red[4][128];
  const int b = blockIdx.x, t = threadIdx.x;
  for (int i = t; i < 324 * 16; i += 256) {
    int row = i >> 4;
    int py = row / 18, pxx = row % 18;
    if (py == 0 || py == 17 || pxx == 0 || pxx == 17) {
      ((uint32_t*)Xh)[i] = 0u;
      ((uint32_t*)Xl)[i] = 0u;
    }
  }
  for (int i = t; i < 4096; i += 256) {
    int p = i >> 8, px = i & 255;
    int y = px >> 4, x = px & 15;
    float va = in[((size_t)b * 32 + 2 * p) * 256 + px];
    float vb = in[((size_t)b * 32 + 2 * p + 1) * 256 + px];
    va = fmaxf(va * scale1[2 * p] + shift1[2 * p], 0.f);
    vb = fmaxf(vb * scale1[2 * p + 1] + shift1[2 * p + 1], 0.f);
    uint32_t ua = pack_bf16q(va), ub = pack_bf16q(vb);
    uint32_t h = (ua >> 16) | (ub & 0xffff0000u);
    uint32_t l = (ua & 0xffffu) | (ub << 16);
    int row = (y + 1) * 18 + (x + 1);
    int ci2 = (2 * p) ^ ((row & 3) << 3);  // swizzled, stays even
    ((uint32_t*)Xh)[(row * 32 + ci2) >> 1] = h;
    ((uint32_t*)Xl)[(row * 32 + ci2) >> 1] = l;
  }
  __syncthreads();
  const int w = t >> 6, l = t & 63;
  const int lr = l & 15, lg = l >> 4;
  f32x4 acc[4][4];  // [co block][px block]
#pragma unroll
  for (int i = 0; i < 4; i++)
#pragma unroll
    for (int j = 0; j < 4; j++) acc[i][j] = (f32x4){0.f, 0.f, 0.f, 0.f};
#pragma unroll 1
  for (int tap = 0; tap < 9; tap++) {
    const int dy = tap / 3, dx = tap % 3;
    short8 awh[4], awl[4];
#pragma unroll
    for (int i = 0; i < 4; i++) {
      size_t off = ((size_t)tap * 64 + i * 16 + lr) * 32 + lg * 8;
      awh[i] = *(const short8*)(wh + off);
      awl[i] = *(const short8*)(wl + off);
    }
    short8 bxh[4], bxl[4];
#pragma unroll
    for (int j = 0; j < 4; j++) {
      int y = w * 4 + j, x = lr;
      int row = (y + dy) * 18 + (x + dx);
      int ci = (lg * 8) ^ ((row & 3) << 3);
      bxh[j] = *(const short8*)&Xh[row * 32 + ci];
      bxl[j] = *(const short8*)&Xl[row * 32 + ci];
    }
#pragma unroll
    for (int i = 0; i < 4; i++)
#pragma unroll
      for (int j = 0; j < 4; j++) {
        acc[i][j] = __builtin_amdgcn_mfma_f32_16x16x32_bf16(awh[i], bxh[j], acc[i][j], 0, 0, 0);
        acc[i][j] = __builtin_amdgcn_mfma_f32_16x16x32_bf16(awh[i], bxl[j], acc[i][j], 0, 0, 0);
        acc[i][j] = __builtin_amdgcn_mfma_f32_16x16x32_bf16(awl[i], bxh[j], acc[i][j], 0, 0, 0);
      }
  }
#pragma unroll
  for (int i = 0; i < 4; i++)
#pragma unroll
    for (int r = 0; r < 4; r++) {
      int co = i * 16 + lg * 4 + r;
      float v0 = acc[i][0][r], v1 = acc[i][1][r], v2 = acc[i][2][r], v3 = acc[i][3][r];
      float s = v0 + v1 + v2 + v3;
      float q = v0 * v0 + v1 * v1 + v2 * v2 + v3 * v3;
#pragma unroll
      for (int off = 1; off <= 8; off <<= 1) {
        s += __shfl_xor(s, off, 64);
        q += __shfl_xor(q, off, 64);
      }
      if (lr == 0) { red[w][2 * co] = s; red[w][2 * co + 1] = q; }
      float h0 = fmaxf(v0, __shfl_xor(v0, 1, 64));
      float h1 = fmaxf(v1, __shfl_xor(v1, 1, 64));
      float h2 = fmaxf(v2, __shfl_xor(v2, 1, 64));
      float h3 = fmaxf(v3, __shfl_xor(v3, 1, 64));
      float pm0 = fmaxf(h0, h1);
      float pm1 = fmaxf(h2, h3);
      if ((lr & 1) == 0) {
        size_t base = ((size_t)b * 64 + co) * 64 + (w * 2) * 8 + (lr >> 1);
        outpool[base] = pm0;
        outpool[base + 8] = pm1;
      }
    }
  __syncthreads();
  for (int i = t; i < 128; i += 256)
    partials[(size_t)b * 128 + i] = red[0][i] + red[1][i] + red[2][i] + red[3][i];
}

// ============================================================================
// conv3 via MFMA implicit GEMM (bf16-split, 3 terms). BN2 applied at staging.
// ============================================================================
__global__ __launch_bounds__(256) void conv3_mfma_kernel(
    const float* __restrict__ in, const float* __restrict__ scale2,
    const float* __restrict__ shift2, const short* __restrict__ wh,
    const short* __restrict__ wl, float* __restrict__ outraw,
    float* __restrict__ partials) {
  __shared__ short Xh[100 * 64], Xl[100 * 64];
  __shared__ float red[256];
  const int b = blockIdx.x, t = threadIdx.x;
  for (int i = t; i < 100 * 32; i += 256) {
    int row = i >> 5;
    int py = row / 10, pxx = row % 10;
    if (py == 0 || py == 9 || pxx == 0 || pxx == 9) {
      ((uint32_t*)Xh)[i] = 0u;
      ((uint32_t*)Xl)[i] = 0u;
    }
  }
  for (int i = t; i < 2048; i += 256) {
    int p = i >> 6, px = i & 63;
    int y = px >> 3, x = px & 7;
    float va = in[((size_t)b * 64 + 2 * p) * 64 + px];
    float vb = in[((size_t)b * 64 + 2 * p + 1) * 64 + px];
    va = fmaxf(va * scale2[2 * p] + shift2[2 * p], 0.f);
    vb = fmaxf(vb * scale2[2 * p + 1] + shift2[2 * p + 1], 0.f);
    uint32_t ua = pack_bf16q(va), ub = pack_bf16q(vb);
    uint32_t h = (ua >> 16) | (ub & 0xffff0000u);
    uint32_t l = (ua & 0xffffu) | (ub << 16);
    int row = (y + 1) * 10 + (x + 1);
    int ci2 = (2 * p) ^ ((row & 7) << 3);
    ((uint32_t*)Xh)[(row * 64 + ci2) >> 1] = h;
    ((uint32_t*)Xl)[(row * 64 + ci2) >> 1] = l;
  }
  __syncthreads();
  const int w = t >> 6, l = t & 63;
  const int lr = l & 15, lg = l >> 4;
  const int co_base = w * 32;
  f32x4 acc[2][4];
#pragma unroll
  for (int i = 0; i < 2; i++)
#pragma unroll
    for (int j = 0; j < 4; j++) acc[i][j] = (f32x4){0.f, 0.f, 0.f, 0.f};
#pragma unroll 1
  for (int tap = 0; tap < 9; tap++) {
    const int dy = tap / 3, dx = tap % 3;
#pragma unroll
    for (int sl = 0; sl < 2; sl++) {
      short8 awh[2], awl[2];
#pragma unroll
      for (int i = 0; i < 2; i++) {
        size_t off = ((size_t)tap * 128 + co_base + i * 16 + lr) * 64 + sl * 32 + lg * 8;
        awh[i] = *(const short8*)(wh + off);
        awl[i] = *(const short8*)(wl + off);
      }
      short8 bxh[4], bxl[4];
#pragma unroll
      for (int j = 0; j < 4; j++) {
        int px = j * 16 + lr;
        int row = ((px >> 3) + dy) * 10 + (px & 7) + dx;
        int ci = (sl * 32 + lg * 8) ^ ((row & 7) << 3);
        bxh[j] = *(const short8*)&Xh[row * 64 + ci];
        bxl[j] = *(const short8*)&Xl[row * 64 + ci];
      }
#pragma unroll
      for (int i = 0; i < 2; i++)
#pragma unroll
        for (int j = 0; j < 4; j++) {
          acc[i][j] = __builtin_amdgcn_mfma_f32_16x16x32_bf16(awh[i], bxh[j], acc[i][j], 0, 0, 0);
          acc[i][j] = __builtin_amdgcn_mfma_f32_16x16x32_bf16(awh[i], bxl[j], acc[i][j], 0, 0, 0);
          acc[i][j] = __builtin_amdgcn_mfma_f32_16x16x32_bf16(awl[i], bxh[j], acc[i][j], 0, 0, 0);
        }
    }
  }
#pragma unroll
  for (int i = 0; i < 2; i++)
#pragma unroll
    for (int r = 0; r < 4; r++) {
      int co = co_base + i * 16 + lg * 4 + r;
      float s = 0.f, q = 0.f;
#pragma unroll
      for (int j = 0; j < 4; j++) {
        float v = acc[i][j][r];
        outraw[((size_t)b * 128 + co) * 64 + j * 16 + lr] = v;
        s += v; q += v * v;
      }
#pragma unroll
      for (int off = 1; off <= 8; off <<= 1) {
        s += __shfl_xor(s, off, 64);
        q += __shfl_xor(q, off, 64);
      }
      if (lr == 0) { red[2 * co] = s; red[2 * co + 1] = q; }
    }
  __syncthreads();
  for (int i = t; i < 256; i += 256) partials[(size_t)b * 256 + i] = red[i];
}

// ============================================================================
// reduce partials + finalize BN in one kernel. grid = C channels.
// ============================================================================
__global__ __launch_bounds__(256) void reduce_finalize_kernel(
    const float* __restrict__ partials, int nblk, int Q,
    const float* __restrict__ g, const float* __restrict__ b,
    float* __restrict__ scale, float* __restrict__ shift, double invN) {
  int c = blockIdx.x, t = threadIdx.x;
  double s = 0.0, q = 0.0;
  for (int i = t; i < nblk; i += 256) {
    s += (double)partials[(size_t)i * Q + 2 * c];
    q += (double)partials[(size_t)i * Q + 2 * c + 1];
  }
  __shared__ double rs[256], rq[256];
  rs[t] = s; rq[t] = q;
  __syncthreads();
  for (int st = 128; st > 0; st >>= 1) {
    if (t < st) { rs[t] += rs[t + st]; rq[t] += rq[t + st]; }
    __syncthreads();
  }
  if (t == 0) {
    double m = rs[0] * invN;
    double v = rq[0] * invN - m * m;
    double sc = (double)g[c] / sqrt(v + 1e-5);
    scale[c] = (float)sc;
    shift[c] = (float)((double)b[c] - m * sc);
  }
}

// col stats over row-chunk, optional elementwise add of Y (split-K merge).
__global__ __launch_bounds__(1024) void col_stats_kernel(
    const float* __restrict__ X, const float* __restrict__ Y,
    int R, int C, int nch, double* __restrict__ sums) {
  int c0 = blockIdx.x * 64, chunk = blockIdx.y;
  int cl = threadIdx.x & 63, rg = threadIdx.x >> 6;
  int rows = R / nch, rbeg = chunk * rows, rend = rbeg + rows;
  double s = 0.0, sq = 0.0;
  for (int r = rbeg + rg; r < rend; r += 16) {
    size_t idx = (size_t)r * C + c0 + cl;
    float v = X[idx];
    if (Y) v += Y[idx];
    s += v; sq += (double)v * (double)v;
  }
  __shared__ double red[16][64][2];
  red[rg][cl][0] = s; red[rg][cl][1] = sq;
  __syncthreads();
  if (rg == 0) {
    for (int i = 1; i < 16; i++) { s += red[i][cl][0]; sq += red[i][cl][1]; }
    sums[(size_t)chunk * 2 * C + 2 * (c0 + cl)] = s;
    sums[(size_t)chunk * 2 * C + 2 * (c0 + cl) + 1] = sq;
  }
}

__global__ void bn_finalize_kernel(const double* __restrict__ sums, int nch, int cst2,
                                   const float* __restrict__ g, const float* __restrict__ b,
                                   float* __restrict__ scale, float* __restrict__ shift,
                                   int C, double invN) {
  int c = blockIdx.x * blockDim.x + threadIdx.x;
  if (c >= C) return;
  double s = 0.0, sq = 0.0;
  for (int ch = 0; ch < nch; ch++) {
    s += sums[(size_t)ch * cst2 + 2 * c];
    sq += sums[(size_t)ch * cst2 + 2 * c + 1];
  }
  double m = s * invN;
  double v = sq * invN - m * m;
  double sc = (double)g[c] / sqrt(v + 1e-5);
  scale[c] = (float)sc;
  shift[c] = (float)((double)b[c] - m * sc);
}

// BN+ReLU+pack for [R][C] row-major, in place, optional add of Y. C4 = C/4.
__global__ void bn_relu_pack_cols4_kernel(float* __restrict__ X,
                                          const float* __restrict__ Y,
                                          const float* __restrict__ scale,
                                          const float* __restrict__ shift,
                                          int n4, int C4) {
  int i = blockIdx.x * blockDim.x + threadIdx.x;
  if (i >= n4) return;
  int c4 = i % C4;
  float4 v = ((float4*)X)[i];
  if (Y) {
    float4 y = ((const float4*)Y)[i];
    v.x += y.x; v.y += y.y; v.z += y.z; v.w += y.w;
  }
  float4 sc = ((const float4*)scale)[c4];
  float4 sh = ((const float4*)shift)[c4];
  uint4 o;
  o.x = pack_bf16q(fmaxf(v.x * sc.x + sh.x, 0.f));
  o.y = pack_bf16q(fmaxf(v.y * sc.y + sh.y, 0.f));
  o.z = pack_bf16q(fmaxf(v.z * sc.z + sh.z, 0.f));
  o.w = pack_bf16q(fmaxf(v.w * sc.w + sh.w, 0.f));
  ((uint4*)X)[i] = o;
}

// BN+ReLU (fp32 out) for [R][C] row-major, in place. C4 = C/4.
__global__ void bn_relu_cols4_kernel(float* __restrict__ X, const float* __restrict__ scale,
                                     const float* __restrict__ shift, int n4, int C4) {
  int i = blockIdx.x * blockDim.x + threadIdx.x;
  if (i >= n4) return;
  int c4 = i % C4;
  float4 v = ((float4*)X)[i];
  float4 sc = ((const float4*)scale)[c4];
  float4 sh = ((const float4*)shift)[c4];
  v.x = fmaxf(v.x * sc.x + sh.x, 0.f);
  v.y = fmaxf(v.y * sc.y + sh.y, 0.f);
  v.z = fmaxf(v.z * sc.z + sh.z, 0.f);
  v.w = fmaxf(v.w * sc.w + sh.w, 0.f);
  ((float4*)X)[i] = v;
}

// full-rank row swizzle: distinct k-block for every row in a 16-row group
__device__ __forceinline__ int swz16(int row) {
  return ((row & 3) ^ ((row >> 2) & 3)) << 3;
}

// ============================================================================
// DUAL bf16-split MFMA GEMM (3 terms), 128x64 tile, BK=32.
// Grid = 2*tiles: first half computes C0 = A*B0^T (no bias), second half
// C1 = relu(A*B1^T + bias1). Runs the two independent FCs concurrently.
// ============================================================================
__global__ __launch_bounds__(256) void gemm_bf16q_dual_kernel(
    const uint32_t* __restrict__ A, const uint32_t* __restrict__ B0,
    const uint32_t* __restrict__ B1, const float* __restrict__ bias1,
    float* __restrict__ C0, float* __restrict__ C1, int M, int N, int K) {
  __shared__ short Ah[128 * 32], Al[128 * 32], Bh[64 * 32], Bl[64 * 32];
  const int t = threadIdx.x;
  const int nTN = N >> 6;
  const int tiles = (M >> 7) * nTN;
  const int half = (blockIdx.x >= tiles) ? 1 : 0;
  const uint32_t* B = half ? B1 : B0;
  float* C = half ? C1 : C0;
  const int bid = blockIdx.x - half * tiles;
  const int mPer = (M >> 7) >> 3;
  const int xcd = bid & 7, qq = bid >> 3;
  const int m0 = (xcd * mPer + qq / nTN) << 7;
  const int n0 = (qq % nTN) << 6;
  const int w = t >> 6, l = t & 63;
  const int wrow = (w >> 1) << 6, wcol = (w & 1) << 5;
  const int lr = l & 15, lg = l >> 4;
  const int ar = t >> 1, akh = (t & 1) << 4;
  const int br = t >> 2, bkh = (t & 3) << 3;
  const int asw = swz16(ar), bsw = swz16(br);
  const uint32_t* Ap = A + (size_t)(m0 + ar) * K + akh;
  const uint32_t* Bp = B + (size_t)(n0 + br) * K + bkh;
  f32x4 acc[4][2];
#pragma unroll
  for (int i = 0; i < 4; i++)
#pragma unroll
    for (int j = 0; j < 2; j++) acc[i][j] = (f32x4){0.f, 0.f, 0.f, 0.f};
  uint4 ra0 = *(const uint4*)(Ap + 0), ra1 = *(const uint4*)(Ap + 4);
  uint4 ra2 = *(const uint4*)(Ap + 8), ra3 = *(const uint4*)(Ap + 12);
  uint4 rb0 = *(const uint4*)(Bp + 0), rb1 = *(const uint4*)(Bp + 4);
  const int NS = K >> 5;
  for (int s = 0; s < NS; s++) {
    __syncthreads();
    STORE2(Ah, Al, ar, akh + 0, asw, ra0, ra1)
    STORE2(Ah, Al, ar, akh + 8, asw, ra2, ra3)
    STORE2(Bh, Bl, br, bkh, bsw, rb0, rb1)
    __syncthreads();
    if (s + 1 < NS) {
      int ko = (s + 1) << 5;
      ra0 = *(const uint4*)(Ap + ko); ra1 = *(const uint4*)(Ap + ko + 4);
      ra2 = *(const uint4*)(Ap + ko + 8); ra3 = *(const uint4*)(Ap + ko + 12);
      rb0 = *(const uint4*)(Bp + ko); rb1 = *(const uint4*)(Bp + ko + 4);
    }
    short8 ahf[4], alf[4], bhf[2], blf[2];
#pragma unroll
    for (int i = 0; i < 4; i++) {
      int R = wrow + i * 16 + lr;
      int kk = (lg << 3) ^ swz16(R);
      ahf[i] = *(const short8*)&Ah[R * 32 + kk];
      alf[i] = *(const short8*)&Al[R * 32 + kk];
    }
#pragma unroll
    for (int j = 0; j < 2; j++) {
      int Cc = wcol + j * 16 + lr;
      int kk = (lg << 3) ^ swz16(Cc);
      bhf[j] = *(const short8*)&Bh[Cc * 32 + kk];
      blf[j] = *(const short8*)&Bl[Cc * 32 + kk];
    }
#pragma unroll
    for (int i = 0; i < 4; i++)
#pragma unroll
      for (int j = 0; j < 2; j++) {
        acc[i][j] = __builtin_amdgcn_mfma_f32_16x16x32_bf16(ahf[i], bhf[j], acc[i][j], 0, 0, 0);
        acc[i][j] = __builtin_amdgcn_mfma_f32_16x16x32_bf16(ahf[i], blf[j], acc[i][j], 0, 0, 0);
        acc[i][j] = __builtin_amdgcn_mfma_f32_16x16x32_bf16(alf[i], bhf[j], acc[i][j], 0, 0, 0);
      }
  }
#pragma unroll
  for (int i = 0; i < 4; i++)
#pragma unroll
    for (int j = 0; j < 2; j++) {
      int n = n0 + wcol + j * 16 + lr;
#pragma unroll
      for (int r = 0; r < 4; r++) {
        int m = m0 + wrow + i * 16 + lg * 4 + r;
        float v = acc[i][j][r];
        if (half) v = fmaxf(v + bias1[n], 0.f);
        C[(size_t)m * N + n] = v;
      }
    }
}

// ============================================================================
// bf16-split MFMA GEMM (3 terms), BIG tile 128x128, BK=32, SPLIT-K=2,
// LDS DOUBLE-BUFFERED (one barrier per K-step). A is RAW fp32 act3 with
// BN3+ReLU applied at staging. Grid = 2*(M/128)*(N/128) -> 2 blocks/CU.
// ============================================================================
__global__ __launch_bounds__(256, 2) void gemm_bf16q_big_kernel(
    const float* __restrict__ A, const uint32_t* __restrict__ B,
    const float* __restrict__ scale, const float* __restrict__ shift,
    float* __restrict__ C0, float* __restrict__ C1, int M, int N, int K) {
  __shared__ short Ah[2][128 * 32], Al[2][128 * 32], Bh[2][128 * 32], Bl[2][128 * 32];
  const int t = threadIdx.x;
  const int nTN = N >> 7;
  const int tiles = (M >> 7) * nTN;
  const int mPer = (M >> 7) >> 3;
  const int split = blockIdx.x / tiles;
  const int bid = blockIdx.x % tiles;
  const int xcd = bid & 7, qq = bid >> 3;
  const int m0 = (xcd * mPer + qq / nTN) << 7;
  const int n0 = (qq % nTN) << 7;
  const int Kh = K >> 1;
  const int kbeg = split * Kh;
  float* Cout = split ? C1 : C0;
  const int w = t >> 6, l = t & 63;
  const int wrow = (w & 1) << 6, wcol = (w >> 1) << 6;
  const int lr = l & 15, lg = l >> 4;
  const int ar = t >> 1, akh = (t & 1) << 4;   // A & B staging: 2 thr/row
  const int asw = swz16(ar);
  const float* Ap = A + (size_t)(m0 + ar) * K + kbeg + akh;
  const uint32_t* Bp = B + (size_t)(n0 + ar) * K + kbeg + akh;
  f32x4 acc[4][4];
#pragma unroll
  for (int i = 0; i < 4; i++)
#pragma unroll
    for (int j = 0; j < 4; j++) acc[i][j] = (f32x4){0.f, 0.f, 0.f, 0.f};
  const int NS = Kh >> 5;
  // prologue: stage s=0 into buf 0
  float4 fa0 = *(const float4*)(Ap + 0), fa1 = *(const float4*)(Ap + 4);
  float4 fa2 = *(const float4*)(Ap + 8), fa3 = *(const float4*)(Ap + 12);
  uint4 rb0 = *(const uint4*)(Bp + 0), rb1 = *(const uint4*)(Bp + 4);
  uint4 rb2 = *(const uint4*)(Bp + 8), rb3 = *(const uint4*)(Bp + 12);
  {
    int ch = (kbeg + akh) >> 6;
    float sc = scale[ch], sh = shift[ch];
    uint4 ua0 = pk4bn(fa0, sc, sh), ua1 = pk4bn(fa1, sc, sh);
    uint4 ua2 = pk4bn(fa2, sc, sh), ua3 = pk4bn(fa3, sc, sh);
    STORE2(Ah[0], Al[0], ar, akh + 0, asw, ua0, ua1)
    STORE2(Ah[0], Al[0], ar, akh + 8, asw, ua2, ua3)
    STORE2(Bh[0], Bl[0], ar, akh + 0, asw, rb0, rb1)
    STORE2(Bh[0], Bl[0], ar, akh + 8, asw, rb2, rb3)
  }
  if (NS > 1) {  // prefetch s=1
    fa0 = *(const float4*)(Ap + 32); fa1 = *(const float4*)(Ap + 36);
    fa2 = *(const float4*)(Ap + 40); fa3 = *(const float4*)(Ap + 44);
    rb0 = *(const uint4*)(Bp + 32); rb1 = *(const uint4*)(Bp + 36);
    rb2 = *(const uint4*)(Bp + 40); rb3 = *(const uint4*)(Bp + 44);
  }
  __syncthreads();
  int cur = 0;
  for (int s = 0; s < NS; s++) {
    short8 ahf[4], alf[4], bhf[4], blf[4];
#pragma unroll
    for (int i = 0; i < 4; i++) {
      int R = wrow + i * 16 + lr;
      int kk = (lg << 3) ^ swz16(R);
      ahf[i] = *(const short8*)&Ah[cur][R * 32 + kk];
      alf[i] = *(const short8*)&Al[cur][R * 32 + kk];
    }
#pragma unroll
    for (int j = 0; j < 4; j++) {
      int Cc = wcol + j * 16 + lr;
      int kk = (lg << 3) ^ swz16(Cc);
      bhf[j] = *(const short8*)&Bh[cur][Cc * 32 + kk];
      blf[j] = *(const short8*)&Bl[cur][Cc * 32 + kk];
    }
    if (s + 1 < NS) {  // stage s+1 into the other buffer (overlaps MFMA)
      int nxt = cur ^ 1;
      int ch = (kbeg + akh + ((s + 1) << 5)) >> 6;
      float sc = scale[ch], sh = shift[ch];
      uint4 ua0 = pk4bn(fa0, sc, sh), ua1 = pk4bn(fa1, sc, sh);
      uint4 ua2 = pk4bn(fa2, sc, sh), ua3 = pk4bn(fa3, sc, sh);
      STORE2(Ah[nxt], Al[nxt], ar, akh + 0, asw, ua0, ua1)
      STORE2(Ah[nxt], Al[nxt], ar, akh + 8, asw, ua2, ua3)
      STORE2(Bh[nxt], Bl[nxt], ar, akh + 0, asw, rb0, rb1)
      STORE2(Bh[nxt], Bl[nxt], ar, akh + 8, asw, rb2, rb3)
      if (s + 2 < NS) {  // prefetch s+2
        int ko = (s + 2) << 5;
        fa0 = *(const float4*)(Ap + ko); fa1 = *(const float4*)(Ap + ko + 4);
        fa2 = *(const float4*)(Ap + ko + 8); fa3 = *(const float4*)(Ap + ko + 12);
        rb0 = *(const uint4*)(Bp + ko); rb1 = *(const uint4*)(Bp + ko + 4);
        rb2 = *(const uint4*)(Bp + ko + 8); rb3 = *(const uint4*)(Bp + ko + 12);
      }
    }
#pragma unroll
    for (int i = 0; i < 4; i++)
#pragma unroll
      for (int j = 0; j < 4; j++) {
        acc[i][j] = __builtin_amdgcn_mfma_f32_16x16x32_bf16(ahf[i], bhf[j], acc[i][j], 0, 0, 0);
        acc[i][j] = __builtin_amdgcn_mfma_f32_16x16x32_bf16(ahf[i], blf[j], acc[i][j], 0, 0, 0);
        acc[i][j] = __builtin_amdgcn_mfma_f32_16x16x32_bf16(alf[i], bhf[j], acc[i][j], 0, 0, 0);
      }
    __syncthreads();
    cur ^= 1;
  }
#pragma unroll
  for (int i = 0; i < 4; i++)
#pragma unroll
    for (int j = 0; j < 4; j++) {
      int n = n0 + wcol + j * 16 + lr;
#pragma unroll
      for (int r = 0; r < 4; r++) {
        int m = m0 + wrow + i * 16 + lg * 4 + r;
        Cout[(size_t)m * N + n] = acc[i][j][r];
      }
    }
}

// ============================================================================
// heads, wave-parallel: one wave per b; 4 j's per wave; double accumulation.
// ============================================================================
__global__ __launch_bounds__(256) void heads_kernel(
    const float* __restrict__ dpen, const float* __restrict__ dfc_w,
    const float* __restrict__ dfc_b, const float* __restrict__ sw_w,
    const float* __restrict__ sw_b, float* __restrict__ out_dom,
    float* __restrict__ swbuf) {
  int wv = threadIdx.x >> 6, ln = threadIdx.x & 63;
  int b = blockIdx.x * 4 + wv;
  const float* row = dpen + (size_t)b * 384;
  double a0 = 0.0, a1 = 0.0, a2 = 0.0, a3 = 0.0;
  for (int k = ln; k < 384; k += 64) {
    double rv = (double)row[k];
    a0 += rv * (double)dfc_w[k];
    a1 += rv * (double)dfc_w[384 + k];
    a2 += rv * (double)sw_w[k];
    a3 += rv * (double)sw_w[384 + k];
  }
#pragma unroll
  for (int off = 32; off > 0; off >>= 1) {
    a0 += __shfl_down(a0, off, 64);
    a1 += __shfl_down(a1, off, 64);
    a2 += __shfl_down(a2, off, 64);
    a3 += __shfl_down(a3, off, 64);
  }
  if (ln == 0) {
    out_dom[b * 2 + 0] = (float)(a0 + (double)dfc_b[0]);
    out_dom[b * 2 + 1] = (float)(a1 + (double)dfc_b[1]);
    swbuf[b * 2 + 0] = (float)(a2 + (double)sw_b[0]);
    swbuf[b * 2 + 1] = (float)(a3 + (double)sw_b[1]);
  }
}

// ============================================================================
// gumbel-softmax + categorical partition choice (threefry partitionable).
// ============================================================================
__global__ __launch_bounds__(256) void partition_kernel(
    const float* __restrict__ swbuf, float* __restrict__ out_pid,
    int* __restrict__ pidxI, float* __restrict__ ysum,
    uint32_t k1a, uint32_t k1b, uint32_t k2a, uint32_t k2b) {
  int b = blockIdx.x * 256 + threadIdx.x;
  if (b >= 4096) return;
  uint32_t j0 = (uint32_t)(2 * b), j1 = (uint32_t)(2 * b + 1);
  float f0 = u01_from_bits(tf_bits32(k1a, k1b, j0));
  float f1 = u01_from_bits(tf_bits32(k1a, k1b, j1));
  const float MINV = 1e-10f;
  float u0 = fmaxf(MINV, f0 * (1.0f - MINV) + MINV);
  float u1 = fmaxf(MINV, f1 * (1.0f - MINV) + MINV);
  double g0 = -log(-log((double)u0));
  double g1 = -log(-log((double)u1));
  double s0 = (double)swbuf[2 * b], s1 = (double)swbuf[2 * b + 1];
  double x0 = (s0 + g0) / 0.1;
  double x1 = (s1 + g1) / 0.1;
  double mx = fmax(x0, x1);
  double e0 = exp(x0 - mx), e1 = exp(x1 - mx);
  double es = e0 + e1;
  double y0 = e0 / es, y1 = e1 / es;
  float h0 = u01_from_bits(tf_bits32(k2a, k2b, j0));
  float h1 = u01_from_bits(tf_bits32(k2a, k2b, j1));
  const float TINY = 1.17549435e-38f;
  float v0 = fmaxf(TINY, h0 * (1.0f - TINY) + TINY);
  float v1 = fmaxf(TINY, h1 * (1.0f - TINY) + TINY);
  double gg0 = -log(-log((double)v0));
  double gg1 = -log(-log((double)v1));
  double l0 = log(y0 + 1e-20) + gg0;
  double l1 = log(y1 + 1e-20) + gg1;
  int p = (l1 > l0) ? 1 : 0;
  out_pid[b] = (float)p;
  pidxI[b] = p;
  ysum[b] = (float)(y0 + y1);
}

// ============================================================================
// final head
// ============================================================================
__global__ __launch_bounds__(256) void final_kernel(
    const float* __restrict__ h, const float* __restrict__ p2w,
    const float* __restrict__ p2b, const int* __restrict__ pidxI,
    const float* __restrict__ ysum, float* __restrict__ out0) {
  int t = blockIdx.x * 256 + threadIdx.x;
  if (t >= 40960) return;
  int b = t / 10, c = t % 10;
  int p = pidxI[b];
  const float* hr = h + (size_t)b * 384 + p * 192;
  const float* wr = p2w + ((size_t)p * 10 + c) * 192;
  float s = 0.f;
  for (int o = 0; o < 192; o++) s += hr[o] * wr[o];
  s += p2b[p * 10 + c];
  out0[t] = s * ysum[b];
}

// ============================================================================
// Launch orchestration (dbuf big GEMM, dual FC GEMM, fused reduce+finalize).
// ============================================================================
extern "C" void kernel_launch(void* const* d_in, const int* in_sizes, int n_in,
                              void* d_out, int out_size, void* d_ws, size_t ws_size,
                              hipStream_t stream) {
  const float* input   = (const float*)d_in[0];
  const float* conv1_w = (const float*)d_in[1];
  const float* bn1_g   = (const float*)d_in[3];
  const float* bn1_b   = (const float*)d_in[4];
  const float* conv2_w = (const float*)d_in[5];
  const float* bn2_g   = (const float*)d_in[7];
  const float* bn2_b   = (const float*)d_in[8];
  const float* conv3_w = (const float*)d_in[9];
  const float* bn3_g   = (const float*)d_in[11];
  const float* bn3_b   = (const float*)d_in[12];
  const float* pre_w   = (const float*)d_in[13];
  const float* bnp_g   = (const float*)d_in[15];
  const float* bnp_b   = (const float*)d_in[16];
  const float* disc_w  = (const float*)d_in[17];
  const float* bnd_g   = (const float*)d_in[19];
  const float* bnd_b   = (const float*)d_in[20];
  const float* dfc_w   = (const float*)d_in[21];
  const float* dfc_b   = (const float*)d_in[22];
  const float* sw_w    = (const float*)d_in[23];
  const float* sw_b    = (const float*)d_in[24];
  const float* p1_w    = (const float*)d_in[25];
  const float* p1_b    = (const float*)d_in[26];
  const float* p2_w    = (const float*)d_in[27];
  const float* p2_b    = (const float*)d_in[28];

  float* W = (float*)d_ws;
  float* pool1  = W + 0;           // [4096][32][16][16] raw fp32
  float* pool2  = W + 33554432;    // [4096][64][8][8] raw fp32
  float* act3   = W + 0;           // [4096][128][8][8] raw fp32, alias pool1
  uint32_t* Bcvt = (uint32_t*)(W + 33554432);   // pre_w packed (after conv3 consumed pool2)
  uint32_t* discq = (uint32_t*)(W + 41943040);  // disc_w packed
  uint32_t* p1q   = (uint32_t*)(W + 42336256);  // p1_w packed
  float* csplit = W + 42729472;    // [4096][1024] split-1 partial
  float* featp  = W + 50331648;    // [4096][1024], raw -> packed in place
  uint32_t* featq = (uint32_t*)featp;
  short* wh3    = (short*)(W + 50331648);       // conv3 w hi (dead until pre-FC)
  short* wl3    = (short*)(W + 50368512);
  short* wh2    = (short*)(W + 50405376);       // conv2 w hi
  short* wl2    = (short*)(W + 50414592);
  float* dpen   = W + 54525952;
  float* hbuf   = W + 56098816;
  float* swbuf  = W + 57671680;
  float* ysum   = W + 57679872;
  int*   pidxI  = (int*)(W + 57683968);
  float* part   = W + 57688064;
  double* sums  = (double*)(W + 58736640);
  float* scale  = W + 58769408;
  float* shift  = W + 58770432;

  float* out_cls = (float*)d_out;
  float* out_dom = out_cls + 40960;
  float* out_pid = out_cls + 49152;

  uint32_t k1a, k1b, k2a, k2b;
  threefry2x32(0u, 42u, 0u, 0u, k1a, k1b);
  threefry2x32(0u, 42u, 0u, 1u, k2a, k2b);

  // --- conv1 fused (raw pooled out) + BN1 stats+finalize ---
  conv1_fused_kernel<<<dim3(4096), dim3(256), 0, stream>>>(input, conv1_w, pool1, part);
  reduce_finalize_kernel<<<dim3(32), dim3(256), 0, stream>>>(part, 4096, 64, bn1_g, bn1_b, scale, shift, 1.0 / (4096.0 * 1024.0));

  // --- conv2 via MFMA (BN1 at staging; raw pooled out) + BN2 stats+finalize ---
  prep_w2_kernel<<<dim3(72), dim3(256), 0, stream>>>(conv2_w, wh2, wl2);
  conv2_mfma_kernel<<<dim3(4096), dim3(256), 0, stream>>>(pool1, scale, shift, wh2, wl2, pool2, part);
  reduce_finalize_kernel<<<dim3(64), dim3(256), 0, stream>>>(part, 4096, 128, bn2_g, bn2_b, scale, shift, 1.0 / (4096.0 * 256.0));

  // --- conv3 via MFMA (BN2 at staging; raw out) + BN3 stats+finalize ---
  prep_w3_kernel<<<dim3(288), dim3(256), 0, stream>>>(conv3_w, wh3, wl3);
  conv3_mfma_kernel<<<dim3(4096), dim3(256), 0, stream>>>(pool2, scale, shift, wh3, wl3, act3, part);
  reduce_finalize_kernel<<<dim3(128), dim3(256), 0, stream>>>(part, 4096, 256, bn3_g, bn3_b, scale, shift, 1.0 / (4096.0 * 64.0));

  // --- pre FC via MFMA big tile (dbuf), split-K=2 (BN3 at A-staging) ---
  cvt_bf16q_kernel<<<dim3(8192), dim3(256), 0, stream>>>(pre_w, Bcvt, 2097152);
  gemm_bf16q_big_kernel<<<dim3(512), dim3(256), 0, stream>>>(act3, Bcvt, scale, shift, featp, csplit, 4096, 1024, 8192);
  col_stats_kernel<<<dim3(16, 8), dim3(1024), 0, stream>>>(featp, csplit, 4096, 1024, 8, sums);
  bn_finalize_kernel<<<dim3(4), dim3(256), 0, stream>>>(sums, 8, 2048, bnp_g, bnp_b, scale, shift, 1024, 1.0 / 4096.0);
  bn_relu_pack_cols4_kernel<<<dim3(4096), dim3(256), 0, stream>>>(featp, csplit, scale, shift, 1048576, 256);

  // --- disc + p1 FCs concurrently via dual MFMA GEMM ---
  cvt_bf16q_kernel<<<dim3(384), dim3(256), 0, stream>>>(disc_w, discq, 98304);
  cvt_bf16q_kernel<<<dim3(384), dim3(256), 0, stream>>>(p1_w, p1q, 98304);
  gemm_bf16q_dual_kernel<<<dim3(384), dim3(256), 0, stream>>>(featq, discq, p1q, p1_b, dpen, hbuf, 4096, 384, 1024);
  col_stats_kernel<<<dim3(6, 8), dim3(1024), 0, stream>>>(dpen, (const float*)nullptr, 4096, 384, 8, sums);
  bn_finalize_kernel<<<dim3(2), dim3(256), 0, stream>>>(sums, 8, 768, bnd_g, bnd_b, scale, shift, 384, 1.0 / 4096.0);
  bn_relu_cols4_kernel<<<dim3(1536), dim3(256), 0, stream>>>(dpen, scale, shift, 393216, 96);

  // --- heads + partition sampling ---
  heads_kernel<<<dim3(1024), dim3(256), 0, stream>>>(dpen, dfc_w, dfc_b, sw_w, sw_b, out_dom, swbuf);
  partition_kernel<<<dim3(16), dim3(256), 0, stream>>>(swbuf, out_pid, pidxI, ysum, k1a, k1b, k2a, k2b);

  // --- final: gather chosen partition + p2 ---
  final_kernel<<<dim3(160), dim3(256), 0, stream>>>(hbuf, p2_w, p2_b, pidxI, ysum, out_cls);
}